// Round 1
// baseline (4562.460 us; speedup 1.0000x reference)
//
#include <hip/hip_runtime.h>
#include <math.h>

#define BB 4
#define NN 1024
#define DD 1024
#define HH 16
#define HDIM 64
#define HD1 65
#define QSTRIDE 72
#define ROWS (BB*NN)   // 4096

// ---------------- block reduce ----------------
__device__ __forceinline__ float block_reduce_sum(float v, float* sm) {
    #pragma unroll
    for (int o = 32; o > 0; o >>= 1) v += __shfl_down(v, o);
    int lane = threadIdx.x & 63, wid = threadIdx.x >> 6;
    if (lane == 0) sm[wid] = v;
    __syncthreads();
    if (wid == 0) {
        v = (lane < (int)(blockDim.x >> 6)) ? sm[lane] : 0.f;
        #pragma unroll
        for (int o = 2; o > 0; o >>= 1) v += __shfl_down(v, o);
        if (lane == 0) sm[0] = v;
    }
    __syncthreads();
    float r = sm[0];
    __syncthreads();
    return r;
}

// ---------------- layernorm + lift ----------------
// out[row][0] = sqrt(sum s'^2 + 1); out[row][1+j] = s'
__global__ __launch_bounds__(256) void k_layernorm_lift(
        const float* __restrict__ x, const float* __restrict__ g,
        const float* __restrict__ be, float* __restrict__ out) {
    __shared__ float sm[8];
    int row = blockIdx.x;
    const float* xr = x + (size_t)row * DD;
    float* orow = out + (size_t)row * DD;
    float s = 0.f, ss = 0.f;
    for (int j = threadIdx.x; j < DD - 1; j += blockDim.x) {
        float v = xr[1 + j]; s += v; ss += v * v;
    }
    s = block_reduce_sum(s, sm);
    ss = block_reduce_sum(ss, sm);
    float mu = s / (float)(DD - 1);
    float var = ss / (float)(DD - 1) - mu * mu;
    float rstd = rsqrtf(var + 1e-5f);
    float s2 = 0.f;
    for (int j = threadIdx.x; j < DD - 1; j += blockDim.x) {
        float v = (xr[1 + j] - mu) * rstd * g[j] + be[j];
        orow[1 + j] = v; s2 += v * v;
    }
    s2 = block_reduce_sum(s2, sm);
    if (threadIdx.x == 0) orow[0] = sqrtf(s2 + 1.f);
}

// ---------------- fp32 tiled GEMM: C = A@W + bias ----------------
// A: M x K (lda=K), W: K x Nc row-major, C: row stride ldc, col offset coff.
// M % 64 == 0, K % 16 == 0 guaranteed; Nc bounds-checked.
#define BM 64
#define BN 64
#define BK 16
__global__ __launch_bounds__(256) void k_gemm(
        const float* __restrict__ A, const float* __restrict__ W,
        const float* __restrict__ bias, float* __restrict__ C,
        int M, int Nc, int K, int ldc, int coff) {
    __shared__ float As[BK][BM + 4];
    __shared__ float Ws[BK][BN + 4];
    int tid = threadIdx.x;
    int tx = tid & 15, ty = tid >> 4;
    int n0 = blockIdx.x * BN, m0 = blockIdx.y * BM;
    int ar = tid >> 2, ac = (tid & 3) * 4;   // A tile: row ar, cols ac..ac+3
    int wr = tid >> 4, wc = tid & 15;        // W tile: row wr, cols wc+16*i
    float acc[4][4] = {};
    for (int k0 = 0; k0 < K; k0 += BK) {
        float4 av = *(const float4*)(A + (size_t)(m0 + ar) * K + k0 + ac);
        As[ac + 0][ar] = av.x; As[ac + 1][ar] = av.y;
        As[ac + 2][ar] = av.z; As[ac + 3][ar] = av.w;
        const float* wrow = W + (size_t)(k0 + wr) * Nc + n0;
        #pragma unroll
        for (int ii = 0; ii < 4; ++ii) {
            int c = wc + 16 * ii;
            Ws[wr][c] = (n0 + c < Nc) ? wrow[c] : 0.f;
        }
        __syncthreads();
        #pragma unroll
        for (int kk = 0; kk < BK; ++kk) {
            float a[4], b[4];
            *(float4*)a = *(const float4*)&As[kk][ty * 4];
            *(float4*)b = *(const float4*)&Ws[kk][tx * 4];
            #pragma unroll
            for (int i = 0; i < 4; ++i)
                #pragma unroll
                for (int j = 0; j < 4; ++j) acc[i][j] += a[i] * b[j];
        }
        __syncthreads();
    }
    #pragma unroll
    for (int i = 0; i < 4; ++i) {
        int r = m0 + ty * 4 + i;
        #pragma unroll
        for (int j = 0; j < 4; ++j) {
            int c = n0 + tx * 4 + j;
            if (c < Nc) C[(size_t)r * ldc + coff + c] = acc[i][j] + bias[c];
        }
    }
}

// ---------------- split heads + lift:  (B,N,H*64) -> (B*H, N, QSTRIDE) ----------------
__global__ __launch_bounds__(256) void k_build_head(
        const float* __restrict__ src, float* __restrict__ dst) {
    int wid = threadIdx.x >> 6, lane = threadIdx.x & 63;
    int idx = blockIdx.x * 4 + wid;         // over B*N*H
    int h = idx & 15; int bn = idx >> 4;    // bn = b*N + n
    int b = bn >> 10, n = bn & 1023;
    float v = src[(size_t)bn * 1024 + h * HDIM + lane];
    float ss = v * v;
    #pragma unroll
    for (int o = 32; o > 0; o >>= 1) ss += __shfl_down(ss, o);
    ss = __shfl(ss, 0);
    float* drow = dst + (size_t)((b * HH + h) * NN + n) * QSTRIDE;
    drow[1 + lane] = v;
    if (lane == 0) drow[0] = sqrtf(ss + 1.f);
}

// ---------------- fused attention (two-pass softmax, S in LDS) ----------------
#define TQ 16
__global__ __launch_bounds__(256) void k_attn(
        const float* __restrict__ qb, const float* __restrict__ kb,
        const float* __restrict__ vb, float* __restrict__ cat) {
    __shared__ float S[TQ][1028];
    __shared__ float Qt[TQ][67];
    __shared__ float KVt[64][67];
    int bh = blockIdx.y;   // 0..63
    int qt = blockIdx.x;   // 0..63
    int tid = threadIdx.x;
    const float* qbase = qb + (size_t)bh * NN * QSTRIDE;
    const float* kbase = kb + (size_t)bh * NN * QSTRIDE;
    const float* vbase = vb + (size_t)bh * NN * QSTRIDE;
    // load Q tile; negate time component so score = dot65(Qt, K)
    for (int idx = tid; idx < TQ * HD1; idx += 256) {
        int i = idx / HD1, e = idx % HD1;
        float v = qbase[(size_t)(qt * TQ + i) * QSTRIDE + e];
        Qt[i][e] = (e == 0) ? -v : v;
    }
    int i = tid >> 4, j0 = (tid & 15) * 4;
    for (int kt = 0; kt < 16; ++kt) {
        __syncthreads();
        for (int idx = tid; idx < 64 * HD1; idx += 256) {
            int r = idx / HD1, e = idx % HD1;
            KVt[r][e] = kbase[(size_t)(kt * 64 + r) * QSTRIDE + e];
        }
        __syncthreads();
        float d0 = 0, d1 = 0, d2 = 0, d3 = 0;
        for (int e = 0; e < HD1; ++e) {
            float qv = Qt[i][e];
            d0 += qv * KVt[j0 + 0][e];
            d1 += qv * KVt[j0 + 1][e];
            d2 += qv * KVt[j0 + 2][e];
            d3 += qv * KVt[j0 + 3][e];
        }
        // scores = (2 + 2*qk)/sqrt(64)
        S[i][kt * 64 + j0 + 0] = 0.25f + 0.25f * d0;
        S[i][kt * 64 + j0 + 1] = 0.25f + 0.25f * d1;
        S[i][kt * 64 + j0 + 2] = 0.25f + 0.25f * d2;
        S[i][kt * 64 + j0 + 3] = 0.25f + 0.25f * d3;
    }
    __syncthreads();
    // softmax: 16 lanes per row
    {
        int r = tid >> 4, c0 = tid & 15;
        float mx = -1e30f;
        for (int c = c0; c < 1024; c += 16) mx = fmaxf(mx, S[r][c]);
        #pragma unroll
        for (int o = 8; o > 0; o >>= 1) mx = fmaxf(mx, __shfl_xor(mx, o, 16));
        float sum = 0.f;
        for (int c = c0; c < 1024; c += 16) {
            float e = __expf(S[r][c] - mx); S[r][c] = e; sum += e;
        }
        #pragma unroll
        for (int o = 8; o > 0; o >>= 1) sum += __shfl_xor(sum, o, 16);
        float inv = 1.f / sum;
        for (int c = c0; c < 1024; c += 16) S[r][c] *= inv;
    }
    // PV: thread (i, c0) accumulates dims e = c0 + 16*m
    int c0 = tid & 15;
    float acc[5] = {0, 0, 0, 0, 0};
    for (int kt = 0; kt < 16; ++kt) {
        __syncthreads();
        for (int idx = tid; idx < 64 * HD1; idx += 256) {
            int r = idx / HD1, e = idx % HD1;
            KVt[r][e] = vbase[(size_t)(kt * 64 + r) * QSTRIDE + e];
        }
        __syncthreads();
        for (int j = 0; j < 64; ++j) {
            float p = S[i][kt * 64 + j];
            #pragma unroll
            for (int m = 0; m < 5; ++m) {
                int e = c0 + 16 * m;
                if (e < HD1) acc[m] += p * KVt[j][e];
            }
        }
    }
    // normalize: q = mid0^2 - sum_{e>=1} mid_e^2
    float part = 0.f;
    #pragma unroll
    for (int m = 0; m < 5; ++m) {
        int e = c0 + 16 * m;
        if (e < HD1) part += (e == 0) ? acc[m] * acc[m] : -acc[m] * acc[m];
    }
    #pragma unroll
    for (int o = 8; o > 0; o >>= 1) part += __shfl_xor(part, o, 16);
    float rden = rsqrtf(fmaxf(part, 1e-8f));
    int b = bh >> 4, h = bh & 15, n = qt * TQ + i;
    float* crow = cat + (size_t)(b * NN + n) * (HH * HD1) + h * HD1;
    #pragma unroll
    for (int m = 0; m < 5; ++m) {
        int e = c0 + 16 * m;
        if (e < HD1) crow[e] = acc[m] * rden;
    }
}

// ---------------- fused lift(y) + lresnet ----------------
// y = lift(yspace); z = x + w*y; out = z / sqrt(max(z0^2 - sum zj^2, 1e-8))
__global__ __launch_bounds__(256) void k_lresnet(
        const float* __restrict__ x, const float* __restrict__ yspace, int ldy,
        const float* __restrict__ wscale, float* __restrict__ out) {
    __shared__ float sm[8];
    int row = blockIdx.x;
    const float* xr = x + (size_t)row * DD;
    const float* yr = yspace + (size_t)row * ldy;
    float w = *wscale;
    float zreg[4];
    float sy = 0.f, sz = 0.f;
    int cnt = 0;
    for (int j = threadIdx.x; j < DD - 1; j += blockDim.x) {
        float yv = yr[j];
        float zv = xr[1 + j] + w * yv;
        sy += yv * yv; sz += zv * zv;
        zreg[cnt++] = zv;
    }
    sy = block_reduce_sum(sy, sm);
    sz = block_reduce_sum(sz, sm);
    float y0 = sqrtf(sy + 1.f);
    float z0 = xr[0] + w * y0;
    float q = z0 * z0 - sz;
    float rden = rsqrtf(fmaxf(q, 1e-8f));
    cnt = 0;
    for (int j = threadIdx.x; j < DD - 1; j += blockDim.x)
        out[(size_t)row * DD + 1 + j] = zreg[cnt++] * rden;
    if (threadIdx.x == 0) out[(size_t)row * DD] = z0 * rden;
}

// ---------------- gelu (exact) + lift, in place on (4096 x 4096), space at cols 1.. ----------------
__global__ __launch_bounds__(256) void k_gelu_lift(float* __restrict__ hbuf) {
    __shared__ float sm[8];
    int row = blockIdx.x;
    float* hr = hbuf + (size_t)row * 4096;
    float s2 = 0.f;
    for (int j = threadIdx.x; j < 4095; j += blockDim.x) {
        float v = hr[1 + j];
        float gl = 0.5f * v * (1.f + erff(v * 0.70710678f));
        hr[1 + j] = gl; s2 += gl * gl;
    }
    s2 = block_reduce_sum(s2, sm);
    if (threadIdx.x == 0) hr[0] = sqrtf(s2 + 1.f);
}

// ---------------- launch ----------------
extern "C" void kernel_launch(void* const* d_in, const int* in_sizes, int n_in,
                              void* d_out, int out_size, void* d_ws, size_t ws_size,
                              hipStream_t stream) {
    const float* x   = (const float*)d_in[0];
    const float* g1  = (const float*)d_in[1];
    const float* b1  = (const float*)d_in[2];
    const float* Wq  = (const float*)d_in[3];
    const float* bq  = (const float*)d_in[4];
    const float* Wk  = (const float*)d_in[5];
    const float* bk  = (const float*)d_in[6];
    const float* Wv  = (const float*)d_in[7];
    const float* bv  = (const float*)d_in[8];
    const float* Wo  = (const float*)d_in[9];
    const float* bo  = (const float*)d_in[10];
    const float* g2  = (const float*)d_in[11];
    const float* b2  = (const float*)d_in[12];
    const float* Wfc = (const float*)d_in[13];
    const float* bfc = (const float*)d_in[14];
    const float* Wpj = (const float*)d_in[15];
    const float* bpj = (const float*)d_in[16];
    const float* w1  = (const float*)d_in[17];
    const float* w2  = (const float*)d_in[18];
    float* out = (float*)d_out;

    float* ws = (float*)d_ws;
    // element offsets
    float* lx  = ws + 0;               // 4096*1024          (also ln2)
    float* qs  = ws + 4194304;         // 4096*1024 gemm tmp
    float* qbf = ws + 8388608;         // 64*1024*72
    float* kbf = ws + 13107200;
    float* vbf = ws + 17825792;
    float* cat = ws + 22544384;        // 4096*1040
    float* ax  = ws + 26804224;        // 4096*1024
    float* x1  = ws + 30998528;        // 4096*1024
    float* hfc = ws + 4194304;         // 4096*4096 overlays qs/q/k/v (free by then)
    float* h2  = ws + 22544384;        // overlays cat (free by then)

    dim3 blk(256);

    // 1) lx = lorentz_layernorm(x)
    k_layernorm_lift<<<ROWS, blk, 0, stream>>>(x, g1, b1, lx);

    // 2) Q,K,V
    dim3 g_sq((1024 + 63) / 64, ROWS / 64);
    k_gemm<<<g_sq, blk, 0, stream>>>(lx, Wq, bq, qs, ROWS, 1024, 1024, 1024, 0);
    k_build_head<<<ROWS * HH / 4, blk, 0, stream>>>(qs, qbf);
    k_gemm<<<g_sq, blk, 0, stream>>>(lx, Wk, bk, qs, ROWS, 1024, 1024, 1024, 0);
    k_build_head<<<ROWS * HH / 4, blk, 0, stream>>>(qs, kbf);
    k_gemm<<<g_sq, blk, 0, stream>>>(lx, Wv, bv, qs, ROWS, 1024, 1024, 1024, 0);
    k_build_head<<<ROWS * HH / 4, blk, 0, stream>>>(qs, vbf);

    // 3) attention -> cat (B,N,1040)
    dim3 g_at(NN / TQ, BB * HH);
    k_attn<<<g_at, blk, 0, stream>>>(qbf, kbf, vbf, cat);

    // 4) ax_space = cat @ Wo + bo   (4096 x 1023), K=1040
    dim3 g_wo((1023 + 63) / 64, ROWS / 64);
    k_gemm<<<g_wo, blk, 0, stream>>>(cat, Wo, bo, ax, ROWS, 1023, 1040, 1024, 0);

    // 5) x1 = lresnet(x, lift(ax_space), w1)
    k_lresnet<<<ROWS, blk, 0, stream>>>(x, ax, 1024, w1, x1);

    // 6) ln2 = lorentz_layernorm(x1) (reuse lx)
    k_layernorm_lift<<<ROWS, blk, 0, stream>>>(x1, g2, b2, lx);

    // 7) hfc[:,1:] = ln2 @ Wfc + bfc  (4096 x 4095), K=1024
    dim3 g_fc((4095 + 63) / 64, ROWS / 64);
    k_gemm<<<g_fc, blk, 0, stream>>>(lx, Wfc, bfc, hfc, ROWS, 4095, 1024, 4096, 1);

    // 8) gelu + lift in place
    k_gelu_lift<<<ROWS, blk, 0, stream>>>(hfc);

    // 9) h2_space = hfc @ Wpj + bpj  (4096 x 1023), K=4096
    dim3 g_pj((1023 + 63) / 64, ROWS / 64);
    k_gemm<<<g_pj, blk, 0, stream>>>(hfc, Wpj, bpj, h2, ROWS, 1023, 4096, 1024, 0);

    // 10) out = lresnet(x1, lift(h2_space), w2)
    k_lresnet<<<ROWS, blk, 0, stream>>>(x1, h2, 1024, w2, out);
}

// Round 2
// 1818.530 us; speedup vs baseline: 2.5089x; 2.5089x over previous
//
#include <hip/hip_runtime.h>
#include <math.h>

#define BB 4
#define NN 1024
#define DD 1024
#define HH 16
#define HDIM 64
#define HD1 65
#define ROWS (BB*NN)   // 4096

typedef __attribute__((ext_vector_type(8))) short bf16x8;
typedef __attribute__((ext_vector_type(4))) float f32x4;

__device__ __forceinline__ unsigned short f2bf(float f) {
    union { float f; unsigned u; } v; v.f = f;
    unsigned r = v.u + 0x7fff + ((v.u >> 16) & 1);
    return (unsigned short)(r >> 16);
}

// ---------------- block reduce ----------------
__device__ __forceinline__ float block_reduce_sum(float v, float* sm) {
    #pragma unroll
    for (int o = 32; o > 0; o >>= 1) v += __shfl_down(v, o);
    int lane = threadIdx.x & 63, wid = threadIdx.x >> 6;
    if (lane == 0) sm[wid] = v;
    __syncthreads();
    if (wid == 0) {
        v = (lane < (int)(blockDim.x >> 6)) ? sm[lane] : 0.f;
        #pragma unroll
        for (int o = 2; o > 0; o >>= 1) v += __shfl_down(v, o);
        if (lane == 0) sm[0] = v;
    }
    __syncthreads();
    float r = sm[0];
    __syncthreads();
    return r;
}

// ---------------- layernorm + lift ----------------
__global__ __launch_bounds__(256) void k_layernorm_lift(
        const float* __restrict__ x, const float* __restrict__ g,
        const float* __restrict__ be, float* __restrict__ out) {
    __shared__ float sm[8];
    int row = blockIdx.x;
    const float* xr = x + (size_t)row * DD;
    float* orow = out + (size_t)row * DD;
    float s = 0.f, ss = 0.f;
    for (int j = threadIdx.x; j < DD - 1; j += blockDim.x) {
        float v = xr[1 + j]; s += v; ss += v * v;
    }
    s = block_reduce_sum(s, sm);
    ss = block_reduce_sum(ss, sm);
    float mu = s / (float)(DD - 1);
    float var = ss / (float)(DD - 1) - mu * mu;
    float rstd = rsqrtf(var + 1e-5f);
    float s2 = 0.f;
    for (int j = threadIdx.x; j < DD - 1; j += blockDim.x) {
        float v = (xr[1 + j] - mu) * rstd * g[j] + be[j];
        orow[1 + j] = v; s2 += v * v;
    }
    s2 = block_reduce_sum(s2, sm);
    if (threadIdx.x == 0) orow[0] = sqrtf(s2 + 1.f);
}

// ---------------- fp32 tiled GEMM: C = A@W + bias ----------------
#define BM 64
#define BN 64
#define BK 16
__global__ __launch_bounds__(256) void k_gemm(
        const float* __restrict__ A, const float* __restrict__ W,
        const float* __restrict__ bias, float* __restrict__ C,
        int M, int Nc, int K, int ldc, int coff) {
    __shared__ float As[BK][BM + 4];
    __shared__ float Ws[BK][BN + 4];
    int tid = threadIdx.x;
    int tx = tid & 15, ty = tid >> 4;
    int n0 = blockIdx.x * BN, m0 = blockIdx.y * BM;
    int ar = tid >> 2, ac = (tid & 3) * 4;
    int wr = tid >> 4, wc = tid & 15;
    float acc[4][4] = {};
    for (int k0 = 0; k0 < K; k0 += BK) {
        float4 av = *(const float4*)(A + (size_t)(m0 + ar) * K + k0 + ac);
        As[ac + 0][ar] = av.x; As[ac + 1][ar] = av.y;
        As[ac + 2][ar] = av.z; As[ac + 3][ar] = av.w;
        const float* wrow = W + (size_t)(k0 + wr) * Nc + n0;
        #pragma unroll
        for (int ii = 0; ii < 4; ++ii) {
            int c = wc + 16 * ii;
            Ws[wr][c] = (n0 + c < Nc) ? wrow[c] : 0.f;
        }
        __syncthreads();
        #pragma unroll
        for (int kk = 0; kk < BK; ++kk) {
            float a[4], b[4];
            *(float4*)a = *(const float4*)&As[kk][ty * 4];
            *(float4*)b = *(const float4*)&Ws[kk][tx * 4];
            #pragma unroll
            for (int i = 0; i < 4; ++i)
                #pragma unroll
                for (int j = 0; j < 4; ++j) acc[i][j] += a[i] * b[j];
        }
        __syncthreads();
    }
    #pragma unroll
    for (int i = 0; i < 4; ++i) {
        int r = m0 + ty * 4 + i;
        #pragma unroll
        for (int j = 0; j < 4; ++j) {
            int c = n0 + tx * 4 + j;
            if (c < Nc) C[(size_t)r * ldc + coff + c] = acc[i][j] + bias[c];
        }
    }
}

// ---------------- head builders: fp32 gemm out -> bf16 padded attention layouts ----------------
// Q/K: (bh, n, 96) bf16. elem0 = tsign*sqrt(1+|s|^2), 1..64 = space, 65..95 = 0
__global__ __launch_bounds__(256) void k_build_qk(
        const float* __restrict__ src, unsigned short* __restrict__ dst, float tsign) {
    int wid = threadIdx.x >> 6, lane = threadIdx.x & 63;
    int idx = blockIdx.x * 4 + wid;      // = bn*16 + h
    int h = idx & 15, bn = idx >> 4;
    int b = bn >> 10, n = bn & 1023;
    float v = src[(size_t)bn * 1024 + h * 64 + lane];
    float ss = v * v;
    #pragma unroll
    for (int o = 32; o > 0; o >>= 1) ss += __shfl_xor(ss, o);
    unsigned short* drow = dst + ((size_t)((b * 16 + h) * 1024 + n)) * 96;
    drow[1 + lane] = f2bf(v);
    if (lane == 0) drow[0] = f2bf(tsign * sqrtf(ss + 1.f));
    if (lane < 31) drow[65 + lane] = 0;
}

// V: transposed (bh, d=80, n=1024) bf16. d0 = time, d1..64 = space, 65..79 = 0
__global__ __launch_bounds__(256) void k_build_vt(
        const float* __restrict__ src, unsigned short* __restrict__ dst) {
    int wid = threadIdx.x >> 6, lane = threadIdx.x & 63;
    int idx = blockIdx.x * 4 + wid;
    int h = idx & 15, bn = idx >> 4;
    int b = bn >> 10, n = bn & 1023;
    float v = src[(size_t)bn * 1024 + h * 64 + lane];
    float ss = v * v;
    #pragma unroll
    for (int o = 32; o > 0; o >>= 1) ss += __shfl_xor(ss, o);
    unsigned short* base = dst + (size_t)(b * 16 + h) * 80 * 1024 + n;
    base[(size_t)(1 + lane) * 1024] = f2bf(v);
    if (lane == 0) base[0] = f2bf(sqrtf(ss + 1.f));
    if (lane >= 49) base[(size_t)(16 + lane) * 1024] = 0;  // d = 65..79
}

// ---------------- MFMA flash attention ----------------
// Block: 256 thr = 4 waves, each wave 16 queries. Grid (16 qtiles, 64 bh).
#define AKS 104   // Klds row stride (bf16 elems)
#define AVS 72    // Vlds row stride
#define APS 88    // Plds row stride
__global__ __launch_bounds__(256) void k_attn_mfma(
        const unsigned short* __restrict__ Qp,
        const unsigned short* __restrict__ Kp,
        const unsigned short* __restrict__ Vt,
        float* __restrict__ cat) {
    __shared__ __align__(16) unsigned short Klds[64 * AKS];
    __shared__ __align__(16) unsigned short Vlds[80 * AVS];
    __shared__ __align__(16) unsigned short Plds[4][16 * APS];
    int tid = threadIdx.x;
    int wave = tid >> 6, lane = tid & 63;
    int quad = lane >> 4, m = lane & 15;
    int bh = blockIdx.y, qt = blockIdx.x;

    // Q fragments (A-layout): row m of this wave's 16 queries, 3 k-chunks of 32
    const unsigned short* qptr = Qp + ((size_t)bh * 1024 + qt * 64 + wave * 16 + m) * 96;
    bf16x8 aq0 = *(const bf16x8*)(qptr + quad * 8);
    bf16x8 aq1 = *(const bf16x8*)(qptr + 32 + quad * 8);
    bf16x8 aq2 = *(const bf16x8*)(qptr + 64 + quad * 8);

    f32x4 O[5];
    #pragma unroll
    for (int i = 0; i < 5; ++i) O[i] = (f32x4){0.f, 0.f, 0.f, 0.f};
    float mrun[4] = {-1e30f, -1e30f, -1e30f, -1e30f};

    const unsigned short* kg = Kp + (size_t)bh * 1024 * 96;
    const unsigned short* vg = Vt + (size_t)bh * 80 * 1024;

    for (int kt = 0; kt < 16; ++kt) {
        __syncthreads();   // prior iter's LDS reads done
        for (int c = tid; c < 768; c += 256) {            // K tile 64x96
            int r = c / 12, col = c - r * 12;
            *(uint4*)&Klds[r * AKS + col * 8] =
                *(const uint4*)(kg + (size_t)(kt * 64 + r) * 96 + col * 8);
        }
        for (int c = tid; c < 640; c += 256) {            // V tile 80x64 (d-major)
            int r = c >> 3, col = c & 7;
            *(uint4*)&Vlds[r * AVS + col * 8] =
                *(const uint4*)(vg + (size_t)r * 1024 + kt * 64 + col * 8);
        }
        __syncthreads();

        // scores: S[16q x 64k] per wave, C-layout regs
        float p[4][4];
        float tmax[4] = {-1e30f, -1e30f, -1e30f, -1e30f};
        #pragma unroll
        for (int nt = 0; nt < 4; ++nt) {
            f32x4 acc = (f32x4){0.f, 0.f, 0.f, 0.f};
            const unsigned short* kr = &Klds[(nt * 16 + m) * AKS + quad * 8];
            acc = __builtin_amdgcn_mfma_f32_16x16x32_bf16(aq0, *(const bf16x8*)(kr),      acc, 0, 0, 0);
            acc = __builtin_amdgcn_mfma_f32_16x16x32_bf16(aq1, *(const bf16x8*)(kr + 32), acc, 0, 0, 0);
            acc = __builtin_amdgcn_mfma_f32_16x16x32_bf16(aq2, *(const bf16x8*)(kr + 64), acc, 0, 0, 0);
            #pragma unroll
            for (int r = 0; r < 4; ++r) {
                float s = 0.25f + 0.25f * acc[r];
                p[nt][r] = s;
                tmax[r] = fmaxf(tmax[r], s);
            }
        }
        // online softmax (denominator cancels in Lorentz normalization)
        #pragma unroll
        for (int r = 0; r < 4; ++r) {
            float v = tmax[r];
            v = fmaxf(v, __shfl_xor(v, 1));
            v = fmaxf(v, __shfl_xor(v, 2));
            v = fmaxf(v, __shfl_xor(v, 4));
            v = fmaxf(v, __shfl_xor(v, 8));
            float mnew = fmaxf(mrun[r], v);
            float alpha = __expf(mrun[r] - mnew);
            mrun[r] = mnew;
            #pragma unroll
            for (int vt = 0; vt < 5; ++vt) O[vt][r] *= alpha;
            #pragma unroll
            for (int nt = 0; nt < 4; ++nt) p[nt][r] = __expf(p[nt][r] - mnew);
        }
        // P: C-layout -> LDS (per-wave buffer) -> A-layout
        unsigned short* pw = &Plds[wave][0];
        #pragma unroll
        for (int nt = 0; nt < 4; ++nt)
            #pragma unroll
            for (int r = 0; r < 4; ++r)
                pw[(quad * 4 + r) * APS + nt * 16 + m] = f2bf(p[nt][r]);
        __syncthreads();
        // PV: O[16q x 80d] += P[16x64] @ V[64x80]
        #pragma unroll
        for (int kc = 0; kc < 2; ++kc) {
            bf16x8 ap = *(const bf16x8*)&Plds[wave][m * APS + kc * 32 + quad * 8];
            #pragma unroll
            for (int vt = 0; vt < 5; ++vt) {
                bf16x8 bv = *(const bf16x8*)&Vlds[(vt * 16 + m) * AVS + kc * 32 + quad * 8];
                O[vt] = __builtin_amdgcn_mfma_f32_16x16x32_bf16(ap, bv, O[vt], 0, 0, 0);
            }
        }
    }
    // epilogue: Lorentz normalize rows, write cat (B,N,16*65)
    int b = bh >> 4, h = bh & 15;
    #pragma unroll
    for (int r = 0; r < 4; ++r) {
        float part = 0.f;
        #pragma unroll
        for (int vt = 0; vt < 5; ++vt) {
            int c = vt * 16 + m;
            float o = O[vt][r];
            part += (c == 0) ? o * o : -o * o;
        }
        part += __shfl_xor(part, 1);
        part += __shfl_xor(part, 2);
        part += __shfl_xor(part, 4);
        part += __shfl_xor(part, 8);
        float rden = rsqrtf(fmaxf(part, 1e-8f));
        int n = qt * 64 + wave * 16 + quad * 4 + r;
        float* crow = cat + (size_t)(b * 1024 + n) * 1040 + h * 65;
        #pragma unroll
        for (int vt = 0; vt < 5; ++vt) {
            int c = vt * 16 + m;
            if (c < 65) crow[c] = O[vt][r] * rden;
        }
    }
}

// ---------------- fused lift(y) + lresnet ----------------
__global__ __launch_bounds__(256) void k_lresnet(
        const float* __restrict__ x, const float* __restrict__ yspace, int ldy,
        const float* __restrict__ wscale, float* __restrict__ out) {
    __shared__ float sm[8];
    int row = blockIdx.x;
    const float* xr = x + (size_t)row * DD;
    const float* yr = yspace + (size_t)row * ldy;
    float w = *wscale;
    float zreg[4];
    float sy = 0.f, sz = 0.f;
    int cnt = 0;
    for (int j = threadIdx.x; j < DD - 1; j += blockDim.x) {
        float yv = yr[j];
        float zv = xr[1 + j] + w * yv;
        sy += yv * yv; sz += zv * zv;
        zreg[cnt++] = zv;
    }
    sy = block_reduce_sum(sy, sm);
    sz = block_reduce_sum(sz, sm);
    float y0 = sqrtf(sy + 1.f);
    float z0 = xr[0] + w * y0;
    float q = z0 * z0 - sz;
    float rden = rsqrtf(fmaxf(q, 1e-8f));
    cnt = 0;
    for (int j = threadIdx.x; j < DD - 1; j += blockDim.x)
        out[(size_t)row * DD + 1 + j] = zreg[cnt++] * rden;
    if (threadIdx.x == 0) out[(size_t)row * DD] = z0 * rden;
}

// ---------------- gelu (exact) + lift ----------------
__global__ __launch_bounds__(256) void k_gelu_lift(float* __restrict__ hbuf) {
    __shared__ float sm[8];
    int row = blockIdx.x;
    float* hr = hbuf + (size_t)row * 4096;
    float s2 = 0.f;
    for (int j = threadIdx.x; j < 4095; j += blockDim.x) {
        float v = hr[1 + j];
        float gl = 0.5f * v * (1.f + erff(v * 0.70710678f));
        hr[1 + j] = gl; s2 += gl * gl;
    }
    s2 = block_reduce_sum(s2, sm);
    if (threadIdx.x == 0) hr[0] = sqrtf(s2 + 1.f);
}

// ---------------- launch ----------------
extern "C" void kernel_launch(void* const* d_in, const int* in_sizes, int n_in,
                              void* d_out, int out_size, void* d_ws, size_t ws_size,
                              hipStream_t stream) {
    const float* x   = (const float*)d_in[0];
    const float* g1  = (const float*)d_in[1];
    const float* b1  = (const float*)d_in[2];
    const float* Wq  = (const float*)d_in[3];
    const float* bq  = (const float*)d_in[4];
    const float* Wk  = (const float*)d_in[5];
    const float* bk  = (const float*)d_in[6];
    const float* Wv  = (const float*)d_in[7];
    const float* bv  = (const float*)d_in[8];
    const float* Wo  = (const float*)d_in[9];
    const float* bo  = (const float*)d_in[10];
    const float* g2  = (const float*)d_in[11];
    const float* b2  = (const float*)d_in[12];
    const float* Wfc = (const float*)d_in[13];
    const float* bfc = (const float*)d_in[14];
    const float* Wpj = (const float*)d_in[15];
    const float* bpj = (const float*)d_in[16];
    const float* w1  = (const float*)d_in[17];
    const float* w2  = (const float*)d_in[18];
    float* out = (float*)d_out;

    float* ws = (float*)d_ws;
    // float-element offsets (peak 34,144,256 floats = 136.6 MB)
    float* lx  = ws + 0;                 // 4096x1024 (reused for ln2)
    float* qs  = ws + 4194304;           // 4096x1024 fp32 gemm tmp
    unsigned short* Qp = (unsigned short*)(ws + 8388608);    // 64x1024x96 bf16
    unsigned short* Kp = (unsigned short*)(ws + 11534336);   // 64x1024x96 bf16
    unsigned short* Vt = (unsigned short*)(ws + 14680064);   // 64x80x1024 bf16
    float* cat = ws + 17301504;          // 4096x1040
    float* ax  = ws + 21561344;          // 4096x1024
    float* x1  = ws + 25755648;          // 4096x1024
    float* hfc = ws + 4194304;           // 4096x4096, overlays qs/Qp/Kp/Vt/cat (free by then)
    float* h2  = ws + 29949952;          // 4096x1024

    dim3 blk(256);

    // 1) lx = lorentz_layernorm(x)
    k_layernorm_lift<<<ROWS, blk, 0, stream>>>(x, g1, b1, lx);

    // 2) Q,K,V projections + bf16 head layouts
    dim3 g_sq(1024 / 64, ROWS / 64);
    k_gemm<<<g_sq, blk, 0, stream>>>(lx, Wq, bq, qs, ROWS, 1024, 1024, 1024, 0);
    k_build_qk<<<ROWS * HH / 4, blk, 0, stream>>>(qs, Qp, -1.f);
    k_gemm<<<g_sq, blk, 0, stream>>>(lx, Wk, bk, qs, ROWS, 1024, 1024, 1024, 0);
    k_build_qk<<<ROWS * HH / 4, blk, 0, stream>>>(qs, Kp, 1.f);
    k_gemm<<<g_sq, blk, 0, stream>>>(lx, Wv, bv, qs, ROWS, 1024, 1024, 1024, 0);
    k_build_vt<<<ROWS * HH / 4, blk, 0, stream>>>(qs, Vt);

    // 3) MFMA flash attention -> cat (B,N,1040)
    dim3 g_at(16, 64);
    k_attn_mfma<<<g_at, blk, 0, stream>>>(Qp, Kp, Vt, cat);

    // 4) ax_space = cat @ Wo + bo
    dim3 g_wo((1023 + 63) / 64, ROWS / 64);
    k_gemm<<<g_wo, blk, 0, stream>>>(cat, Wo, bo, ax, ROWS, 1023, 1040, 1024, 0);

    // 5) x1 = lresnet(x, lift(ax_space), w1)
    k_lresnet<<<ROWS, blk, 0, stream>>>(x, ax, 1024, w1, x1);

    // 6) ln2 = lorentz_layernorm(x1)
    k_layernorm_lift<<<ROWS, blk, 0, stream>>>(x1, g2, b2, lx);

    // 7) hfc[:,1:] = ln2 @ Wfc + bfc
    dim3 g_fc((4095 + 63) / 64, ROWS / 64);
    k_gemm<<<g_fc, blk, 0, stream>>>(lx, Wfc, bfc, hfc, ROWS, 4095, 1024, 4096, 1);

    // 8) gelu + lift in place
    k_gelu_lift<<<ROWS, blk, 0, stream>>>(hfc);

    // 9) h2_space = hfc @ Wpj + bpj
    dim3 g_pj((1023 + 63) / 64, ROWS / 64);
    k_gemm<<<g_pj, blk, 0, stream>>>(hfc, Wpj, bpj, h2, ROWS, 1023, 4096, 1024, 0);

    // 10) out = lresnet(x1, lift(h2_space), w2)
    k_lresnet<<<ROWS, blk, 0, stream>>>(x1, h2, 1024, w2, out);
}

// Round 3
// 565.907 us; speedup vs baseline: 8.0622x; 3.2135x over previous
//
#include <hip/hip_runtime.h>
#include <math.h>

#define BB 4
#define NN 1024
#define DD 1024
#define HH 16
#define ROWS (BB*NN)   // 4096

typedef __attribute__((ext_vector_type(8))) short bf16x8;
typedef __attribute__((ext_vector_type(4))) float f32x4;
typedef unsigned short u16;

__device__ __forceinline__ u16 f2bf(float f) {
    union { float f; unsigned u; } v; v.f = f;
    unsigned r = v.u + 0x7fff + ((v.u >> 16) & 1);
    return (u16)(r >> 16);
}
__device__ __forceinline__ float bf2f(u16 u) {
    union { unsigned u; float f; } v; v.u = ((unsigned)u) << 16; return v.f;
}

// async global->LDS, 16B per lane. LDS dest = uniform base + lane*16.
__device__ __forceinline__ void async16(const void* g, void* l) {
    __builtin_amdgcn_global_load_lds(
        (__attribute__((address_space(1))) void*)(uintptr_t)g,
        (__attribute__((address_space(3))) void*)(uintptr_t)l,
        16, 0, 0);
}

// ---------------- block reduce ----------------
__device__ __forceinline__ float block_reduce_sum(float v, float* sm) {
    #pragma unroll
    for (int o = 32; o > 0; o >>= 1) v += __shfl_down(v, o);
    int lane = threadIdx.x & 63, wid = threadIdx.x >> 6;
    if (lane == 0) sm[wid] = v;
    __syncthreads();
    if (wid == 0) {
        v = (lane < (int)(blockDim.x >> 6)) ? sm[lane] : 0.f;
        #pragma unroll
        for (int o = 2; o > 0; o >>= 1) v += __shfl_down(v, o);
        if (lane == 0) sm[0] = v;
    }
    __syncthreads();
    float r = sm[0];
    __syncthreads();
    return r;
}

// ---------------- weight transpose + bf16 convert ----------------
// W: K x N fp32 row-major -> out: Npad x Kpad bf16 (out[n][k] = W[k][n], zero pad)
__global__ __launch_bounds__(256) void k_convT(
        const float* __restrict__ W, u16* __restrict__ out,
        int K, int N, int Kpad, int Npad) {
    __shared__ float t[32][33];
    int k0 = blockIdx.x * 32, n0 = blockIdx.y * 32;
    int tx = threadIdx.x & 31, ty = threadIdx.x >> 5;   // ty 0..7
    #pragma unroll
    for (int i = 0; i < 32; i += 8) {
        int k = k0 + ty + i, n = n0 + tx;
        t[ty + i][tx] = (k < K && n < N) ? W[(size_t)k * N + n] : 0.f;
    }
    __syncthreads();
    #pragma unroll
    for (int i = 0; i < 32; i += 8) {
        int n = n0 + ty + i, k = k0 + tx;
        if (n < Npad && k < Kpad) out[(size_t)n * Kpad + k] = f2bf(t[tx][ty + i]);
    }
}

// ---------------- layernorm + lift -> bf16 ----------------
__global__ __launch_bounds__(256) void k_layernorm_lift_bf(
        const float* __restrict__ x, const float* __restrict__ g,
        const float* __restrict__ be, u16* __restrict__ out) {
    __shared__ float sm[8];
    int row = blockIdx.x;
    const float* xr = x + (size_t)row * DD;
    u16* orow = out + (size_t)row * DD;
    float s = 0.f, ss = 0.f;
    for (int j = threadIdx.x; j < DD - 1; j += blockDim.x) {
        float v = xr[1 + j]; s += v; ss += v * v;
    }
    s = block_reduce_sum(s, sm);
    ss = block_reduce_sum(ss, sm);
    float mu = s / (float)(DD - 1);
    float var = ss / (float)(DD - 1) - mu * mu;
    float rstd = rsqrtf(var + 1e-5f);
    float s2 = 0.f;
    for (int j = threadIdx.x; j < DD - 1; j += blockDim.x) {
        float v = (xr[1 + j] - mu) * rstd * g[j] + be[j];
        orow[1 + j] = f2bf(v); s2 += v * v;
    }
    s2 = block_reduce_sum(s2, sm);
    if (threadIdx.x == 0) orow[0] = f2bf(sqrtf(s2 + 1.f));
}

// ---------------- bf16 MFMA GEMM (m97 structure) ----------------
// C(MxN) = A(MxK,bf16) @ BT(NxK,bf16)^T + bias. M,N mult of 128, K mult of 64.
// Grid: (N/128, M/128), 256 threads (4 waves, 2x2 of 64x64).
__device__ __forceinline__ void cstore(float* p, float v) { *p = v; }
__device__ __forceinline__ void cstore(u16* p, float v) { *p = f2bf(v); }

template <typename OT>
__global__ __launch_bounds__(256) void k_gemm_mfma(
        const u16* __restrict__ A, const u16* __restrict__ BT,
        const float* __restrict__ bias, int nbias,
        OT* __restrict__ C, int ldc, int K) {
    __shared__ __align__(16) u16 As[128 * 64];
    __shared__ __align__(16) u16 Bs[128 * 64];
    int tid = threadIdx.x;
    int wave = tid >> 6, lane = tid & 63;
    int quad = lane >> 4, m16 = lane & 15;
    int n0 = blockIdx.x * 128, m0 = blockIdx.y * 128;
    int wm = (wave & 1) * 64, wn = (wave >> 1) * 64;

    f32x4 acc[4][4];
    #pragma unroll
    for (int t = 0; t < 4; ++t)
        #pragma unroll
        for (int u = 0; u < 4; ++u) acc[t][u] = (f32x4){0.f, 0.f, 0.f, 0.f};

    int srow = wave * 32 + (lane >> 3);      // staging row (j=0)
    int scol = (lane & 7) * 8;
    const u16* ag = A  + (size_t)(m0 + srow) * K + scol;
    const u16* bg = BT + (size_t)(n0 + srow) * K + scol;
    u16* asl = &As[(wave * 32) * 64];        // wave-uniform LDS bases
    u16* bsl = &Bs[(wave * 32) * 64];

    for (int k0 = 0; k0 < K; k0 += 64) {
        __syncthreads();
        #pragma unroll
        for (int j = 0; j < 4; ++j) {
            async16(ag + (size_t)(j * 8) * K + k0, asl + (j * 8) * 64);
            async16(bg + (size_t)(j * 8) * K + k0, bsl + (j * 8) * 64);
        }
        __syncthreads();
        #pragma unroll
        for (int kk = 0; kk < 2; ++kk) {
            bf16x8 af[4], bfr[4];
            #pragma unroll
            for (int t = 0; t < 4; ++t)
                af[t] = *(const bf16x8*)&As[(wm + t * 16 + m16) * 64 + kk * 32 + quad * 8];
            #pragma unroll
            for (int u = 0; u < 4; ++u)
                bfr[u] = *(const bf16x8*)&Bs[(wn + u * 16 + m16) * 64 + kk * 32 + quad * 8];
            #pragma unroll
            for (int t = 0; t < 4; ++t)
                #pragma unroll
                for (int u = 0; u < 4; ++u)
                    acc[t][u] = __builtin_amdgcn_mfma_f32_16x16x32_bf16(af[t], bfr[u], acc[t][u], 0, 0, 0);
        }
    }
    #pragma unroll
    for (int u = 0; u < 4; ++u) {
        int col = n0 + wn + u * 16 + m16;
        float bv = (bias != nullptr && col < nbias) ? bias[col] : 0.f;
        #pragma unroll
        for (int t = 0; t < 4; ++t) {
            #pragma unroll
            for (int r = 0; r < 4; ++r) {
                int row = m0 + wm + t * 16 + quad * 4 + r;
                cstore(C + (size_t)row * ldc + col, acc[t][u][r] + bv);
            }
        }
    }
}

// ---------------- head builders: bf16 qkv -> padded attention layouts ----------------
// Q/K: (bh, n, 96) bf16. elem0 = tsign*sqrt(1+|s|^2)
__global__ __launch_bounds__(256) void k_build_qk(
        const u16* __restrict__ qkv, int colbase, const float* __restrict__ bias,
        u16* __restrict__ dst, float tsign) {
    int wid = threadIdx.x >> 6, lane = threadIdx.x & 63;
    int idx = blockIdx.x * 4 + wid;      // = bn*16 + h
    int h = idx & 15, bn = idx >> 4;
    int b = bn >> 10, n = bn & 1023;
    float v = bf2f(qkv[(size_t)bn * 3072 + colbase + h * 64 + lane]) + bias[h * 64 + lane];
    float ss = v * v;
    #pragma unroll
    for (int o = 32; o > 0; o >>= 1) ss += __shfl_xor(ss, o);
    u16* drow = dst + ((size_t)((b * 16 + h) * 1024 + n)) * 96;
    drow[1 + lane] = f2bf(v);
    if (lane == 0) drow[0] = f2bf(tsign * sqrtf(ss + 1.f));
    if (lane < 31) drow[65 + lane] = 0;
}

// V: transposed (bh, d=80, n=1024) bf16
__global__ __launch_bounds__(256) void k_build_vt(
        const u16* __restrict__ qkv, int colbase, const float* __restrict__ bias,
        u16* __restrict__ dst) {
    int wid = threadIdx.x >> 6, lane = threadIdx.x & 63;
    int idx = blockIdx.x * 4 + wid;
    int h = idx & 15, bn = idx >> 4;
    int b = bn >> 10, n = bn & 1023;
    float v = bf2f(qkv[(size_t)bn * 3072 + colbase + h * 64 + lane]) + bias[h * 64 + lane];
    float ss = v * v;
    #pragma unroll
    for (int o = 32; o > 0; o >>= 1) ss += __shfl_xor(ss, o);
    u16* base = dst + (size_t)(b * 16 + h) * 80 * 1024 + n;
    base[(size_t)(1 + lane) * 1024] = f2bf(v);
    if (lane == 0) base[0] = f2bf(sqrtf(ss + 1.f));
    if (lane >= 49) base[(size_t)(16 + lane) * 1024] = 0;  // d = 65..79
}

// zero pad cols 1040..1087 of cat (stride 1088)
__global__ __launch_bounds__(256) void k_zero_pad(u16* __restrict__ cat) {
    int i = blockIdx.x * 256 + threadIdx.x;
    int r = i / 48, c = i - r * 48;
    cat[(size_t)r * 1088 + 1040 + c] = 0;
}

// ---------------- MFMA flash attention (bf16 out, stride 1088) ----------------
#define AKS 104
#define AVS 72
#define APS 88
__global__ __launch_bounds__(256) void k_attn_mfma(
        const u16* __restrict__ Qp, const u16* __restrict__ Kp,
        const u16* __restrict__ Vt, u16* __restrict__ cat) {
    __shared__ __align__(16) u16 Klds[64 * AKS];
    __shared__ __align__(16) u16 Vlds[80 * AVS];
    __shared__ __align__(16) u16 Plds[4][16 * APS];
    int tid = threadIdx.x;
    int wave = tid >> 6, lane = tid & 63;
    int quad = lane >> 4, m = lane & 15;
    int bh = blockIdx.y, qt = blockIdx.x;

    const u16* qptr = Qp + ((size_t)bh * 1024 + qt * 64 + wave * 16 + m) * 96;
    bf16x8 aq0 = *(const bf16x8*)(qptr + quad * 8);
    bf16x8 aq1 = *(const bf16x8*)(qptr + 32 + quad * 8);
    bf16x8 aq2 = *(const bf16x8*)(qptr + 64 + quad * 8);

    f32x4 O[5];
    #pragma unroll
    for (int i = 0; i < 5; ++i) O[i] = (f32x4){0.f, 0.f, 0.f, 0.f};
    float mrun[4] = {-1e30f, -1e30f, -1e30f, -1e30f};

    const u16* kg = Kp + (size_t)bh * 1024 * 96;
    const u16* vg = Vt + (size_t)bh * 80 * 1024;

    for (int kt = 0; kt < 16; ++kt) {
        __syncthreads();
        for (int c = tid; c < 768; c += 256) {            // K tile 64x96
            int r = c / 12, col = c - r * 12;
            *(uint4*)&Klds[r * AKS + col * 8] =
                *(const uint4*)(kg + (size_t)(kt * 64 + r) * 96 + col * 8);
        }
        for (int c = tid; c < 640; c += 256) {            // V tile 80x64 (d-major)
            int r = c >> 3, col = c & 7;
            *(uint4*)&Vlds[r * AVS + col * 8] =
                *(const uint4*)(vg + (size_t)r * 1024 + kt * 64 + col * 8);
        }
        __syncthreads();

        float p[4][4];
        float tmax[4] = {-1e30f, -1e30f, -1e30f, -1e30f};
        #pragma unroll
        for (int nt = 0; nt < 4; ++nt) {
            f32x4 acc = (f32x4){0.f, 0.f, 0.f, 0.f};
            const u16* kr = &Klds[(nt * 16 + m) * AKS + quad * 8];
            acc = __builtin_amdgcn_mfma_f32_16x16x32_bf16(aq0, *(const bf16x8*)(kr),      acc, 0, 0, 0);
            acc = __builtin_amdgcn_mfma_f32_16x16x32_bf16(aq1, *(const bf16x8*)(kr + 32), acc, 0, 0, 0);
            acc = __builtin_amdgcn_mfma_f32_16x16x32_bf16(aq2, *(const bf16x8*)(kr + 64), acc, 0, 0, 0);
            #pragma unroll
            for (int r = 0; r < 4; ++r) {
                float s = 0.25f + 0.25f * acc[r];
                p[nt][r] = s;
                tmax[r] = fmaxf(tmax[r], s);
            }
        }
        #pragma unroll
        for (int r = 0; r < 4; ++r) {
            float v = tmax[r];
            v = fmaxf(v, __shfl_xor(v, 1));
            v = fmaxf(v, __shfl_xor(v, 2));
            v = fmaxf(v, __shfl_xor(v, 4));
            v = fmaxf(v, __shfl_xor(v, 8));
            float mnew = fmaxf(mrun[r], v);
            float alpha = __expf(mrun[r] - mnew);
            mrun[r] = mnew;
            #pragma unroll
            for (int vt = 0; vt < 5; ++vt) O[vt][r] *= alpha;
            #pragma unroll
            for (int nt = 0; nt < 4; ++nt) p[nt][r] = __expf(p[nt][r] - mnew);
        }
        u16* pw = &Plds[wave][0];
        #pragma unroll
        for (int nt = 0; nt < 4; ++nt)
            #pragma unroll
            for (int r = 0; r < 4; ++r)
                pw[(quad * 4 + r) * APS + nt * 16 + m] = f2bf(p[nt][r]);
        __syncthreads();
        #pragma unroll
        for (int kc = 0; kc < 2; ++kc) {
            bf16x8 ap = *(const bf16x8*)&Plds[wave][m * APS + kc * 32 + quad * 8];
            #pragma unroll
            for (int vt = 0; vt < 5; ++vt) {
                bf16x8 bv = *(const bf16x8*)&Vlds[(vt * 16 + m) * AVS + kc * 32 + quad * 8];
                O[vt] = __builtin_amdgcn_mfma_f32_16x16x32_bf16(ap, bv, O[vt], 0, 0, 0);
            }
        }
    }
    int b = bh >> 4, h = bh & 15;
    #pragma unroll
    for (int r = 0; r < 4; ++r) {
        float part = 0.f;
        #pragma unroll
        for (int vt = 0; vt < 5; ++vt) {
            int c = vt * 16 + m;
            float o = O[vt][r];
            part += (c == 0) ? o * o : -o * o;
        }
        part += __shfl_xor(part, 1);
        part += __shfl_xor(part, 2);
        part += __shfl_xor(part, 4);
        part += __shfl_xor(part, 8);
        float rden = rsqrtf(fmaxf(part, 1e-8f));
        int n = qt * 64 + wave * 16 + quad * 4 + r;
        u16* crow = cat + (size_t)(b * 1024 + n) * 1088 + h * 65;
        #pragma unroll
        for (int vt = 0; vt < 5; ++vt) {
            int c = vt * 16 + m;
            if (c < 65) crow[c] = f2bf(O[vt][r] * rden);
        }
    }
}

// ---------------- fused lift(y) + lresnet (fp32 in/out) ----------------
__global__ __launch_bounds__(256) void k_lresnet(
        const float* __restrict__ x, const float* __restrict__ yspace, int ldy,
        const float* __restrict__ wscale, float* __restrict__ out) {
    __shared__ float sm[8];
    int row = blockIdx.x;
    const float* xr = x + (size_t)row * DD;
    const float* yr = yspace + (size_t)row * ldy;
    float w = *wscale;
    float zreg[4];
    float sy = 0.f, sz = 0.f;
    int cnt = 0;
    for (int j = threadIdx.x; j < DD - 1; j += blockDim.x) {
        float yv = yr[j];
        float zv = xr[1 + j] + w * yv;
        sy += yv * yv; sz += zv * zv;
        zreg[cnt++] = zv;
    }
    sy = block_reduce_sum(sy, sm);
    sz = block_reduce_sum(sz, sm);
    float y0 = sqrtf(sy + 1.f);
    float z0 = xr[0] + w * y0;
    float q = z0 * z0 - sz;
    float rden = rsqrtf(fmaxf(q, 1e-8f));
    cnt = 0;
    for (int j = threadIdx.x; j < DD - 1; j += blockDim.x)
        out[(size_t)row * DD + 1 + j] = zreg[cnt++] * rden;
    if (threadIdx.x == 0) out[(size_t)row * DD] = z0 * rden;
}

// ---------------- gelu (exact) + lift: bf16 in -> bf16 lifted out ----------------
__global__ __launch_bounds__(256) void k_gelu_lift(
        const u16* __restrict__ hfc, u16* __restrict__ hg) {
    __shared__ float sm[8];
    int row = blockIdx.x;
    const u16* hr = hfc + (size_t)row * 4096;
    u16* gr = hg + (size_t)row * 4096;
    float s2 = 0.f;
    for (int j = threadIdx.x; j < 4095; j += blockDim.x) {
        float v = bf2f(hr[j]);
        float gl = 0.5f * v * (1.f + erff(v * 0.70710678f));
        gr[1 + j] = f2bf(gl); s2 += gl * gl;
    }
    s2 = block_reduce_sum(s2, sm);
    if (threadIdx.x == 0) gr[0] = f2bf(sqrtf(s2 + 1.f));
}

// ---------------- launch ----------------
extern "C" void kernel_launch(void* const* d_in, const int* in_sizes, int n_in,
                              void* d_out, int out_size, void* d_ws, size_t ws_size,
                              hipStream_t stream) {
    const float* x   = (const float*)d_in[0];
    const float* g1  = (const float*)d_in[1];
    const float* b1  = (const float*)d_in[2];
    const float* Wq  = (const float*)d_in[3];
    const float* bq  = (const float*)d_in[4];
    const float* Wk  = (const float*)d_in[5];
    const float* bk  = (const float*)d_in[6];
    const float* Wv  = (const float*)d_in[7];
    const float* bv  = (const float*)d_in[8];
    const float* Wo  = (const float*)d_in[9];
    const float* bo  = (const float*)d_in[10];
    const float* g2  = (const float*)d_in[11];
    const float* b2  = (const float*)d_in[12];
    const float* Wfc = (const float*)d_in[13];
    const float* bfc = (const float*)d_in[14];
    const float* Wpj = (const float*)d_in[15];
    const float* bpj = (const float*)d_in[16];
    const float* w1  = (const float*)d_in[17];
    const float* w2  = (const float*)d_in[18];
    float* out = (float*)d_out;

    char* W = (char*)d_ws;
    // byte offsets; peak 134,348,800 B (proven-safe range)
    u16* lx_bf  = (u16*)(W + 0);            // 8 MB   (reused as ln2)
    u16* WqkvT  = (u16*)(W + 8388608);      // [3072][1024]
    u16* WoT    = (u16*)(W + 14680064);     // [1024][1088]
    u16* WfcT   = (u16*)(W + 16908288);     // [4096][1024]
    u16* WpjT   = (u16*)(W + 25296896);     // [1024][4096]
    u16* qkv_bf = (u16*)(W + 33685504);     // 4096x3072 (dead after builders)
    u16* Qp     = (u16*)(W + 58851328);     // 64x1024x96
    u16* Kp     = (u16*)(W + 71434240);
    u16* Vt     = (u16*)(W + 84017152);     // 64x80x1024
    u16* cat_bf = (u16*)(W + 94502912);     // 4096x1088
    float* ax   = (float*)(W + 33685504);   // overlay qkv_bf (dead)
    float* x1   = (float*)(W + 50462720);   // overlay qkv tail/Qp head (dead)
    u16* hfc_bf = (u16*)(W + 67239936);     // 4096x4096, overlay Qp/Kp/Vt/cat-head (dead)
    u16* hg_bf  = (u16*)(W + 100794368);    // 4096x4096
    float* h2   = (float*)(W + 33685504);   // overlay ax (dead)

    dim3 blk(256);

    // weight conversion + transpose (per call; ws is re-poisoned)
    k_convT<<<dim3(32, 32), blk, 0, stream>>>(Wq, WqkvT,                 1024, 1024, 1024, 1024);
    k_convT<<<dim3(32, 32), blk, 0, stream>>>(Wk, WqkvT + 1024 * 1024,   1024, 1024, 1024, 1024);
    k_convT<<<dim3(32, 32), blk, 0, stream>>>(Wv, WqkvT + 2048 * 1024,   1024, 1024, 1024, 1024);
    k_convT<<<dim3(34, 32), blk, 0, stream>>>(Wo, WoT,                   1040, 1023, 1088, 1024);
    k_convT<<<dim3(32, 128), blk, 0, stream>>>(Wfc, WfcT,                1024, 4095, 1024, 4096);
    k_convT<<<dim3(128, 32), blk, 0, stream>>>(Wpj, WpjT,                4096, 1023, 4096, 1024);

    // 1) lx = lorentz_layernorm(x) -> bf16
    k_layernorm_lift_bf<<<ROWS, blk, 0, stream>>>(x, g1, b1, lx_bf);

    // 2) fused QKV GEMM (bias folded into builders) + head layouts
    k_gemm_mfma<u16><<<dim3(24, 32), blk, 0, stream>>>(lx_bf, WqkvT, nullptr, 0, qkv_bf, 3072, 1024);
    k_build_qk<<<ROWS * HH / 4, blk, 0, stream>>>(qkv_bf, 0,    bq, Qp, -1.f);
    k_build_qk<<<ROWS * HH / 4, blk, 0, stream>>>(qkv_bf, 1024, bk, Kp, 1.f);
    k_build_vt<<<ROWS * HH / 4, blk, 0, stream>>>(qkv_bf, 2048, bv, Vt);

    // 3) MFMA flash attention -> cat_bf (stride 1088, pad zeroed)
    k_zero_pad<<<768, blk, 0, stream>>>(cat_bf);
    k_attn_mfma<<<dim3(16, 64), blk, 0, stream>>>(Qp, Kp, Vt, cat_bf);

    // 4) ax = cat @ Wo + bo  (fp32 out)
    k_gemm_mfma<float><<<dim3(8, 32), blk, 0, stream>>>(cat_bf, WoT, bo, 1023, ax, 1024, 1088);

    // 5) x1 = lresnet(x, lift(ax), w1)
    k_lresnet<<<ROWS, blk, 0, stream>>>(x, ax, 1024, w1, x1);

    // 6) ln2 -> bf16 (reuse lx_bf)
    k_layernorm_lift_bf<<<ROWS, blk, 0, stream>>>(x1, g2, b2, lx_bf);

    // 7) hfc = ln2 @ Wfc + bfc (bf16 out, cols 0..4094 valid)
    k_gemm_mfma<u16><<<dim3(32, 32), blk, 0, stream>>>(lx_bf, WfcT, bfc, 4095, hfc_bf, 4096, 1024);

    // 8) hg = lift(gelu(hfc)) bf16
    k_gelu_lift<<<ROWS, blk, 0, stream>>>(hfc_bf, hg_bf);

    // 9) h2 = hg @ Wpj + bpj (fp32 out)
    k_gemm_mfma<float><<<dim3(8, 32), blk, 0, stream>>>(hg_bf, WpjT, bpj, 1023, h2, 1024, 4096);

    // 10) out = lresnet(x1, lift(h2), w2)
    k_lresnet<<<ROWS, blk, 0, stream>>>(x1, h2, 1024, w2, out);
}

// Round 4
// 496.941 us; speedup vs baseline: 9.1811x; 1.1388x over previous
//
#include <hip/hip_runtime.h>
#include <math.h>

#define BB 4
#define NN 1024
#define DD 1024
#define HH 16
#define ROWS (BB*NN)   // 4096

typedef __attribute__((ext_vector_type(8))) short bf16x8;
typedef __attribute__((ext_vector_type(4))) float f32x4;
typedef unsigned short u16;

__device__ __forceinline__ u16 f2bf(float f) {
    union { float f; unsigned u; } v; v.f = f;
    unsigned r = v.u + 0x7fff + ((v.u >> 16) & 1);
    return (u16)(r >> 16);
}
__device__ __forceinline__ float bf2f(u16 u) {
    union { unsigned u; float f; } v; v.u = ((unsigned)u) << 16; return v.f;
}

// async global->LDS, 16B per lane. LDS dest = uniform base + lane*16.
__device__ __forceinline__ void async16(const void* g, void* l) {
    __builtin_amdgcn_global_load_lds(
        (__attribute__((address_space(1))) void*)(uintptr_t)g,
        (__attribute__((address_space(3))) void*)(uintptr_t)l,
        16, 0, 0);
}

// ---------------- block reduce ----------------
__device__ __forceinline__ float block_reduce_sum(float v, float* sm) {
    #pragma unroll
    for (int o = 32; o > 0; o >>= 1) v += __shfl_down(v, o);
    int lane = threadIdx.x & 63, wid = threadIdx.x >> 6;
    if (lane == 0) sm[wid] = v;
    __syncthreads();
    if (wid == 0) {
        v = (lane < (int)(blockDim.x >> 6)) ? sm[lane] : 0.f;
        #pragma unroll
        for (int o = 2; o > 0; o >>= 1) v += __shfl_down(v, o);
        if (lane == 0) sm[0] = v;
    }
    __syncthreads();
    float r = sm[0];
    __syncthreads();
    return r;
}

// ---------------- weight transpose + bf16 convert ----------------
__global__ __launch_bounds__(256) void k_convT(
        const float* __restrict__ W, u16* __restrict__ out,
        int K, int N, int Kpad, int Npad) {
    __shared__ float t[32][33];
    int k0 = blockIdx.x * 32, n0 = blockIdx.y * 32;
    int tx = threadIdx.x & 31, ty = threadIdx.x >> 5;
    #pragma unroll
    for (int i = 0; i < 32; i += 8) {
        int k = k0 + ty + i, n = n0 + tx;
        t[ty + i][tx] = (k < K && n < N) ? W[(size_t)k * N + n] : 0.f;
    }
    __syncthreads();
    #pragma unroll
    for (int i = 0; i < 32; i += 8) {
        int n = n0 + ty + i, k = k0 + tx;
        if (n < Npad && k < Kpad) out[(size_t)n * Kpad + k] = f2bf(t[tx][ty + i]);
    }
}

// ---------------- layernorm + lift -> bf16 ----------------
__global__ __launch_bounds__(256) void k_layernorm_lift_bf(
        const float* __restrict__ x, const float* __restrict__ g,
        const float* __restrict__ be, u16* __restrict__ out) {
    __shared__ float sm[8];
    int row = blockIdx.x;
    const float* xr = x + (size_t)row * DD;
    u16* orow = out + (size_t)row * DD;
    float s = 0.f, ss = 0.f;
    for (int j = threadIdx.x; j < DD - 1; j += blockDim.x) {
        float v = xr[1 + j]; s += v; ss += v * v;
    }
    s = block_reduce_sum(s, sm);
    ss = block_reduce_sum(ss, sm);
    float mu = s / (float)(DD - 1);
    float var = ss / (float)(DD - 1) - mu * mu;
    float rstd = rsqrtf(var + 1e-5f);
    float s2 = 0.f;
    for (int j = threadIdx.x; j < DD - 1; j += blockDim.x) {
        float v = (xr[1 + j] - mu) * rstd * g[j] + be[j];
        orow[1 + j] = f2bf(v); s2 += v * v;
    }
    s2 = block_reduce_sum(s2, sm);
    if (threadIdx.x == 0) orow[0] = f2bf(sqrtf(s2 + 1.f));
}

// ---------------- bf16 MFMA GEMM (m97 structure + XOR swizzle + in-launch split-K) ----------------
// C(MxN) = A(MxK)@BT(NxK)^T + bias. Tiles 128x128, BK=64.
// blockIdx.z = 0: k in [0,ksplit), out C0, +bias;  z = 1: k in [ksplit,K), out C1, no bias.
// LDS slot s of row r holds global chunk s^(r&7) (8-elem chunks) -> 8-way max read alias.
__device__ __forceinline__ void cstore(float* p, float v) { *p = v; }
__device__ __forceinline__ void cstore(u16* p, float v) { *p = f2bf(v); }

template <typename OT>
__global__ __launch_bounds__(256) void k_gemm_mfma(
        const u16* __restrict__ A, const u16* __restrict__ BT,
        const float* __restrict__ bias, int nbias,
        OT* __restrict__ C0, OT* __restrict__ C1,
        int ldc, int ldab, int ksplit, int K) {
    __shared__ __align__(16) u16 As[128 * 64];
    __shared__ __align__(16) u16 Bs[128 * 64];
    int z = blockIdx.z;
    int kbeg = z ? ksplit : 0;
    int kend = z ? K : ksplit;
    OT* C = z ? C1 : C0;
    const float* bs = z ? nullptr : bias;

    int tid = threadIdx.x;
    int wave = tid >> 6, lane = tid & 63;
    int quad = lane >> 4, m16 = lane & 15;
    int n0 = blockIdx.x * 128, m0 = blockIdx.y * 128;
    int wm = (wave & 1) * 64, wn = (wave >> 1) * 64;

    f32x4 acc[4][4];
    #pragma unroll
    for (int t = 0; t < 4; ++t)
        #pragma unroll
        for (int u = 0; u < 4; ++u) acc[t][u] = (f32x4){0.f, 0.f, 0.f, 0.f};

    int r8 = lane >> 3;                      // row within 8-row staging group
    int cc = (lane & 7) ^ r8;                // swizzled source chunk
    int srow = wave * 32 + r8;
    const u16* ag = A  + (size_t)(m0 + srow) * ldab + cc * 8;
    const u16* bg = BT + (size_t)(n0 + srow) * ldab + cc * 8;
    u16* asl = &As[(wave * 32) * 64];
    u16* bsl = &Bs[(wave * 32) * 64];

    for (int k0 = kbeg; k0 < kend; k0 += 64) {
        __syncthreads();
        #pragma unroll
        for (int j = 0; j < 4; ++j) {
            async16(ag + (size_t)(j * 8) * ldab + k0, asl + (j * 8) * 64);
            async16(bg + (size_t)(j * 8) * ldab + k0, bsl + (j * 8) * 64);
        }
        __syncthreads();
        #pragma unroll
        for (int kk = 0; kk < 2; ++kk) {
            bf16x8 af[4], bfr[4];
            #pragma unroll
            for (int t = 0; t < 4; ++t) {
                int slot = (kk * 4 + quad) ^ (m16 & 7);
                af[t] = *(const bf16x8*)&As[(wm + t * 16 + m16) * 64 + slot * 8];
            }
            #pragma unroll
            for (int u = 0; u < 4; ++u) {
                int slot = (kk * 4 + quad) ^ (m16 & 7);
                bfr[u] = *(const bf16x8*)&Bs[(wn + u * 16 + m16) * 64 + slot * 8];
            }
            #pragma unroll
            for (int t = 0; t < 4; ++t)
                #pragma unroll
                for (int u = 0; u < 4; ++u)
                    acc[t][u] = __builtin_amdgcn_mfma_f32_16x16x32_bf16(af[t], bfr[u], acc[t][u], 0, 0, 0);
        }
    }
    #pragma unroll
    for (int u = 0; u < 4; ++u) {
        int col = n0 + wn + u * 16 + m16;
        float bv = (bs != nullptr && col < nbias) ? bs[col] : 0.f;
        #pragma unroll
        for (int t = 0; t < 4; ++t) {
            #pragma unroll
            for (int r = 0; r < 4; ++r) {
                int row = m0 + wm + t * 16 + quad * 4 + r;
                cstore(C + (size_t)row * ldc + col, acc[t][u][r] + bv);
            }
        }
    }
}

// ---------------- head builders ----------------
__global__ __launch_bounds__(256) void k_build_qk(
        const u16* __restrict__ qkv, int colbase, const float* __restrict__ bias,
        u16* __restrict__ dst, float tsign) {
    int wid = threadIdx.x >> 6, lane = threadIdx.x & 63;
    int idx = blockIdx.x * 4 + wid;
    int h = idx & 15, bn = idx >> 4;
    int b = bn >> 10, n = bn & 1023;
    float v = bf2f(qkv[(size_t)bn * 3072 + colbase + h * 64 + lane]) + bias[h * 64 + lane];
    float ss = v * v;
    #pragma unroll
    for (int o = 32; o > 0; o >>= 1) ss += __shfl_xor(ss, o);
    u16* drow = dst + ((size_t)((b * 16 + h) * 1024 + n)) * 96;
    drow[1 + lane] = f2bf(v);
    if (lane == 0) drow[0] = f2bf(tsign * sqrtf(ss + 1.f));
    if (lane < 31) drow[65 + lane] = 0;
}

__global__ __launch_bounds__(256) void k_build_vt(
        const u16* __restrict__ qkv, int colbase, const float* __restrict__ bias,
        u16* __restrict__ dst) {
    int wid = threadIdx.x >> 6, lane = threadIdx.x & 63;
    int idx = blockIdx.x * 4 + wid;
    int h = idx & 15, bn = idx >> 4;
    int b = bn >> 10, n = bn & 1023;
    float v = bf2f(qkv[(size_t)bn * 3072 + colbase + h * 64 + lane]) + bias[h * 64 + lane];
    float ss = v * v;
    #pragma unroll
    for (int o = 32; o > 0; o >>= 1) ss += __shfl_xor(ss, o);
    u16* base = dst + (size_t)(b * 16 + h) * 80 * 1024 + n;
    base[(size_t)(1 + lane) * 1024] = f2bf(v);
    if (lane == 0) base[0] = f2bf(sqrtf(ss + 1.f));
    if (lane >= 49) base[(size_t)(16 + lane) * 1024] = 0;  // d = 65..79
}

__global__ __launch_bounds__(256) void k_zero_pad(u16* __restrict__ cat) {
    int i = blockIdx.x * 256 + threadIdx.x;
    int r = i / 48, c = i - r * 48;
    cat[(size_t)r * 1088 + 1040 + c] = 0;
}

// ---------------- MFMA flash attention (bf16 out, stride 1088) ----------------
#define AKS 104
#define AVS 72
#define APS 88
__global__ __launch_bounds__(256) void k_attn_mfma(
        const u16* __restrict__ Qp, const u16* __restrict__ Kp,
        const u16* __restrict__ Vt, u16* __restrict__ cat) {
    __shared__ __align__(16) u16 Klds[64 * AKS];
    __shared__ __align__(16) u16 Vlds[80 * AVS];
    __shared__ __align__(16) u16 Plds[4][16 * APS];
    int tid = threadIdx.x;
    int wave = tid >> 6, lane = tid & 63;
    int quad = lane >> 4, m = lane & 15;
    int bh = blockIdx.y, qt = blockIdx.x;

    const u16* qptr = Qp + ((size_t)bh * 1024 + qt * 64 + wave * 16 + m) * 96;
    bf16x8 aq0 = *(const bf16x8*)(qptr + quad * 8);
    bf16x8 aq1 = *(const bf16x8*)(qptr + 32 + quad * 8);
    bf16x8 aq2 = *(const bf16x8*)(qptr + 64 + quad * 8);

    f32x4 O[5];
    #pragma unroll
    for (int i = 0; i < 5; ++i) O[i] = (f32x4){0.f, 0.f, 0.f, 0.f};
    float mrun[4] = {-1e30f, -1e30f, -1e30f, -1e30f};

    const u16* kg = Kp + (size_t)bh * 1024 * 96;
    const u16* vg = Vt + (size_t)bh * 80 * 1024;

    for (int kt = 0; kt < 16; ++kt) {
        __syncthreads();
        for (int c = tid; c < 768; c += 256) {
            int r = c / 12, col = c - r * 12;
            *(uint4*)&Klds[r * AKS + col * 8] =
                *(const uint4*)(kg + (size_t)(kt * 64 + r) * 96 + col * 8);
        }
        for (int c = tid; c < 640; c += 256) {
            int r = c >> 3, col = c & 7;
            *(uint4*)&Vlds[r * AVS + col * 8] =
                *(const uint4*)(vg + (size_t)r * 1024 + kt * 64 + col * 8);
        }
        __syncthreads();

        float p[4][4];
        float tmax[4] = {-1e30f, -1e30f, -1e30f, -1e30f};
        #pragma unroll
        for (int nt = 0; nt < 4; ++nt) {
            f32x4 acc = (f32x4){0.f, 0.f, 0.f, 0.f};
            const u16* kr = &Klds[(nt * 16 + m) * AKS + quad * 8];
            acc = __builtin_amdgcn_mfma_f32_16x16x32_bf16(aq0, *(const bf16x8*)(kr),      acc, 0, 0, 0);
            acc = __builtin_amdgcn_mfma_f32_16x16x32_bf16(aq1, *(const bf16x8*)(kr + 32), acc, 0, 0, 0);
            acc = __builtin_amdgcn_mfma_f32_16x16x32_bf16(aq2, *(const bf16x8*)(kr + 64), acc, 0, 0, 0);
            #pragma unroll
            for (int r = 0; r < 4; ++r) {
                float s = 0.25f + 0.25f * acc[r];
                p[nt][r] = s;
                tmax[r] = fmaxf(tmax[r], s);
            }
        }
        #pragma unroll
        for (int r = 0; r < 4; ++r) {
            float v = tmax[r];
            v = fmaxf(v, __shfl_xor(v, 1));
            v = fmaxf(v, __shfl_xor(v, 2));
            v = fmaxf(v, __shfl_xor(v, 4));
            v = fmaxf(v, __shfl_xor(v, 8));
            float mnew = fmaxf(mrun[r], v);
            float alpha = __expf(mrun[r] - mnew);
            mrun[r] = mnew;
            #pragma unroll
            for (int vt = 0; vt < 5; ++vt) O[vt][r] *= alpha;
            #pragma unroll
            for (int nt = 0; nt < 4; ++nt) p[nt][r] = __expf(p[nt][r] - mnew);
        }
        u16* pw = &Plds[wave][0];
        #pragma unroll
        for (int nt = 0; nt < 4; ++nt)
            #pragma unroll
            for (int r = 0; r < 4; ++r)
                pw[(quad * 4 + r) * APS + nt * 16 + m] = f2bf(p[nt][r]);
        __syncthreads();
        #pragma unroll
        for (int kc = 0; kc < 2; ++kc) {
            bf16x8 ap = *(const bf16x8*)&Plds[wave][m * APS + kc * 32 + quad * 8];
            #pragma unroll
            for (int vt = 0; vt < 5; ++vt) {
                bf16x8 bv = *(const bf16x8*)&Vlds[(vt * 16 + m) * AVS + kc * 32 + quad * 8];
                O[vt] = __builtin_amdgcn_mfma_f32_16x16x32_bf16(ap, bv, O[vt], 0, 0, 0);
            }
        }
    }
    int b = bh >> 4, h = bh & 15;
    #pragma unroll
    for (int r = 0; r < 4; ++r) {
        float part = 0.f;
        #pragma unroll
        for (int vt = 0; vt < 5; ++vt) {
            int c = vt * 16 + m;
            float o = O[vt][r];
            part += (c == 0) ? o * o : -o * o;
        }
        part += __shfl_xor(part, 1);
        part += __shfl_xor(part, 2);
        part += __shfl_xor(part, 4);
        part += __shfl_xor(part, 8);
        float rden = rsqrtf(fmaxf(part, 1e-8f));
        int n = qt * 64 + wave * 16 + quad * 4 + r;
        u16* crow = cat + (size_t)(b * 1024 + n) * 1088 + h * 65;
        #pragma unroll
        for (int vt = 0; vt < 5; ++vt) {
            int c = vt * 16 + m;
            if (c < 65) crow[c] = f2bf(O[vt][r] * rden);
        }
    }
}

// ---------------- fused lift(y0+y1) + lresnet (fp32) ----------------
__global__ __launch_bounds__(256) void k_lresnet(
        const float* __restrict__ x, const float* __restrict__ y0,
        const float* __restrict__ y1, const float* __restrict__ wscale,
        float* __restrict__ out) {
    __shared__ float sm[8];
    int row = blockIdx.x;
    const float* xr = x + (size_t)row * DD;
    const float* ya = y0 + (size_t)row * 1024;
    const float* yb = y1 + (size_t)row * 1024;
    float w = *wscale;
    float zreg[4];
    float sy = 0.f, sz = 0.f;
    int cnt = 0;
    for (int j = threadIdx.x; j < DD - 1; j += blockDim.x) {
        float yv = ya[j] + yb[j];
        float zv = xr[1 + j] + w * yv;
        sy += yv * yv; sz += zv * zv;
        zreg[cnt++] = zv;
    }
    sy = block_reduce_sum(sy, sm);
    sz = block_reduce_sum(sz, sm);
    float y0t = sqrtf(sy + 1.f);
    float z0 = xr[0] + w * y0t;
    float q = z0 * z0 - sz;
    float rden = rsqrtf(fmaxf(q, 1e-8f));
    cnt = 0;
    for (int j = threadIdx.x; j < DD - 1; j += blockDim.x)
        out[(size_t)row * DD + 1 + j] = zreg[cnt++] * rden;
    if (threadIdx.x == 0) out[(size_t)row * DD] = z0 * rden;
}

// ---------------- gelu (exact) + lift: bf16 in -> bf16 lifted out ----------------
__global__ __launch_bounds__(256) void k_gelu_lift(
        const u16* __restrict__ hfc, u16* __restrict__ hg) {
    __shared__ float sm[8];
    int row = blockIdx.x;
    const u16* hr = hfc + (size_t)row * 4096;
    u16* gr = hg + (size_t)row * 4096;
    float s2 = 0.f;
    for (int j = threadIdx.x; j < 4095; j += blockDim.x) {
        float v = bf2f(hr[j]);
        float gl = 0.5f * v * (1.f + erff(v * 0.70710678f));
        gr[1 + j] = f2bf(gl); s2 += gl * gl;
    }
    s2 = block_reduce_sum(s2, sm);
    if (threadIdx.x == 0) gr[0] = f2bf(sqrtf(s2 + 1.f));
}

// ---------------- launch ----------------
extern "C" void kernel_launch(void* const* d_in, const int* in_sizes, int n_in,
                              void* d_out, int out_size, void* d_ws, size_t ws_size,
                              hipStream_t stream) {
    const float* x   = (const float*)d_in[0];
    const float* g1  = (const float*)d_in[1];
    const float* b1  = (const float*)d_in[2];
    const float* Wq  = (const float*)d_in[3];
    const float* bq  = (const float*)d_in[4];
    const float* Wk  = (const float*)d_in[5];
    const float* bk  = (const float*)d_in[6];
    const float* Wv  = (const float*)d_in[7];
    const float* bv  = (const float*)d_in[8];
    const float* Wo  = (const float*)d_in[9];
    const float* bo  = (const float*)d_in[10];
    const float* g2  = (const float*)d_in[11];
    const float* b2  = (const float*)d_in[12];
    const float* Wfc = (const float*)d_in[13];
    const float* bfc = (const float*)d_in[14];
    const float* Wpj = (const float*)d_in[15];
    const float* bpj = (const float*)d_in[16];
    const float* w1  = (const float*)d_in[17];
    const float* w2  = (const float*)d_in[18];
    float* out = (float*)d_out;

    char* W = (char*)d_ws;
    // byte offsets; peak 117,571,584 B
    u16* lx_bf  = (u16*)(W + 0);            // 8 MB (ln1, later ln2)
    u16* WqkvT  = (u16*)(W + 8388608);      // [3072][1024]
    u16* WoT    = (u16*)(W + 14680064);     // [1024][1088]
    u16* WfcT   = (u16*)(W + 16908288);     // [4096][1024]
    u16* WpjT   = (u16*)(W + 25296896);     // [1024][4096]
    u16* qkv_bf = (u16*)(W + 33685504);     // 4096x3072 (dead after builders)
    u16* Qp     = (u16*)(W + 58851328);     // 64x1024x96
    u16* Kp     = (u16*)(W + 71434240);
    u16* Vt     = (u16*)(W + 84017152);     // 64x80x1024
    u16* cat_bf = (u16*)(W + 94502912);     // 4096x1088
    float* ax0  = (float*)(W + 33685504);   // overlay qkv (dead)
    float* ax1  = (float*)(W + 50462720);   // overlay qkv/Qp-head (dead)
    float* x1   = (float*)(W + 67239936);   // overlay Qp-tail/Kp (dead)
    u16* hfc_bf = (u16*)(W + 84017152);     // 32MB, overlay Vt/cat (dead)
    u16* hg_bf  = (u16*)(W + 33685504);     // 32MB, overlay ax0/ax1 (dead)
    float* h2a  = (float*)(W + 84017152);   // overlay hfc (dead after gelu)
    float* h2b  = (float*)(W + 100794368);

    dim3 blk(256);

    // weight conversion + transpose
    k_convT<<<dim3(32, 32), blk, 0, stream>>>(Wq, WqkvT,                 1024, 1024, 1024, 1024);
    k_convT<<<dim3(32, 32), blk, 0, stream>>>(Wk, WqkvT + 1024 * 1024,   1024, 1024, 1024, 1024);
    k_convT<<<dim3(32, 32), blk, 0, stream>>>(Wv, WqkvT + 2048 * 1024,   1024, 1024, 1024, 1024);
    k_convT<<<dim3(34, 32), blk, 0, stream>>>(Wo, WoT,                   1040, 1023, 1088, 1024);
    k_convT<<<dim3(32, 128), blk, 0, stream>>>(Wfc, WfcT,                1024, 4095, 1024, 4096);
    k_convT<<<dim3(128, 32), blk, 0, stream>>>(Wpj, WpjT,                4096, 1023, 4096, 1024);

    // 1) lx = lorentz_layernorm(x) -> bf16
    k_layernorm_lift_bf<<<ROWS, blk, 0, stream>>>(x, g1, b1, lx_bf);

    // 2) fused QKV GEMM + head layouts
    k_gemm_mfma<u16><<<dim3(24, 32, 1), blk, 0, stream>>>(
        lx_bf, WqkvT, nullptr, 0, qkv_bf, qkv_bf, 3072, 1024, 1024, 1024);
    k_build_qk<<<ROWS * HH / 4, blk, 0, stream>>>(qkv_bf, 0,    bq, Qp, -1.f);
    k_build_qk<<<ROWS * HH / 4, blk, 0, stream>>>(qkv_bf, 1024, bk, Kp, 1.f);
    k_build_vt<<<ROWS * HH / 4, blk, 0, stream>>>(qkv_bf, 2048, bv, Vt);

    // 3) MFMA flash attention -> cat_bf (stride 1088)
    k_zero_pad<<<768, blk, 0, stream>>>(cat_bf);
    k_attn_mfma<<<dim3(16, 64), blk, 0, stream>>>(Qp, Kp, Vt, cat_bf);

    // 4) ax = cat @ Wo + bo, split-K (576+512) in one launch
    k_gemm_mfma<float><<<dim3(8, 32, 2), blk, 0, stream>>>(
        cat_bf, WoT, bo, 1023, ax0, ax1, 1024, 1088, 576, 1088);

    // 5) x1 = lresnet(x, lift(ax0+ax1), w1)
    k_lresnet<<<ROWS, blk, 0, stream>>>(x, ax0, ax1, w1, x1);

    // 6) ln2 -> bf16 (reuse lx_bf)
    k_layernorm_lift_bf<<<ROWS, blk, 0, stream>>>(x1, g2, b2, lx_bf);

    // 7) hfc = ln2 @ Wfc + bfc (bf16 out)
    k_gemm_mfma<u16><<<dim3(32, 32, 1), blk, 0, stream>>>(
        lx_bf, WfcT, bfc, 4095, hfc_bf, hfc_bf, 4096, 1024, 1024, 1024);

    // 8) hg = lift(gelu(hfc)) bf16
    k_gelu_lift<<<ROWS, blk, 0, stream>>>(hfc_bf, hg_bf);

    // 9) h2 = hg @ Wpj + bpj, split-K (2048+2048) in one launch
    k_gemm_mfma<float><<<dim3(8, 32, 2), blk, 0, stream>>>(
        hg_bf, WpjT, bpj, 1023, h2a, h2b, 1024, 4096, 2048, 4096);

    // 10) out = lresnet(x1, lift(h2a+h2b), w2)
    k_lresnet<<<ROWS, blk, 0, stream>>>(x1, h2a, h2b, w2, out);
}

// Round 5
// 489.399 us; speedup vs baseline: 9.3226x; 1.0154x over previous
//
#include <hip/hip_runtime.h>
#include <math.h>

#define BB 4
#define NN 1024
#define DD 1024
#define HH 16
#define ROWS (BB*NN)   // 4096

typedef __attribute__((ext_vector_type(8))) short bf16x8;
typedef __attribute__((ext_vector_type(4))) float f32x4;
typedef unsigned short u16;

__device__ __forceinline__ u16 f2bf(float f) {
    union { float f; unsigned u; } v; v.f = f;
    unsigned r = v.u + 0x7fff + ((v.u >> 16) & 1);
    return (u16)(r >> 16);
}
__device__ __forceinline__ u16 f2bf_fast(float f) {   // round-half-up, 2 VALU ops
    union { float f; unsigned u; } v; v.f = f;
    return (u16)((v.u + 0x8000u) >> 16);
}
__device__ __forceinline__ float bf2f(u16 u) {
    union { unsigned u; float f; } v; v.u = ((unsigned)u) << 16; return v.f;
}

// async global->LDS, 16B per lane. LDS dest = uniform base + lane*16.
__device__ __forceinline__ void async16(const void* g, void* l) {
    __builtin_amdgcn_global_load_lds(
        (__attribute__((address_space(1))) void*)(uintptr_t)g,
        (__attribute__((address_space(3))) void*)(uintptr_t)l,
        16, 0, 0);
}

// ---------------- block reduce ----------------
__device__ __forceinline__ float block_reduce_sum(float v, float* sm) {
    #pragma unroll
    for (int o = 32; o > 0; o >>= 1) v += __shfl_down(v, o);
    int lane = threadIdx.x & 63, wid = threadIdx.x >> 6;
    if (lane == 0) sm[wid] = v;
    __syncthreads();
    if (wid == 0) {
        v = (lane < (int)(blockDim.x >> 6)) ? sm[lane] : 0.f;
        #pragma unroll
        for (int o = 2; o > 0; o >>= 1) v += __shfl_down(v, o);
        if (lane == 0) sm[0] = v;
    }
    __syncthreads();
    float r = sm[0];
    __syncthreads();
    return r;
}

// ---------------- weight transpose + bf16 convert ----------------
__global__ __launch_bounds__(256) void k_convT(
        const float* __restrict__ W, u16* __restrict__ out,
        int K, int N, int Kpad, int Npad) {
    __shared__ float t[32][33];
    int k0 = blockIdx.x * 32, n0 = blockIdx.y * 32;
    int tx = threadIdx.x & 31, ty = threadIdx.x >> 5;
    #pragma unroll
    for (int i = 0; i < 32; i += 8) {
        int k = k0 + ty + i, n = n0 + tx;
        t[ty + i][tx] = (k < K && n < N) ? W[(size_t)k * N + n] : 0.f;
    }
    __syncthreads();
    #pragma unroll
    for (int i = 0; i < 32; i += 8) {
        int n = n0 + ty + i, k = k0 + tx;
        if (n < Npad && k < Kpad) out[(size_t)n * Kpad + k] = f2bf(t[tx][ty + i]);
    }
}

// ---------------- layernorm + lift -> bf16 ----------------
__global__ __launch_bounds__(256) void k_layernorm_lift_bf(
        const float* __restrict__ x, const float* __restrict__ g,
        const float* __restrict__ be, u16* __restrict__ out) {
    __shared__ float sm[8];
    int row = blockIdx.x;
    const float* xr = x + (size_t)row * DD;
    u16* orow = out + (size_t)row * DD;
    float s = 0.f, ss = 0.f;
    for (int j = threadIdx.x; j < DD - 1; j += blockDim.x) {
        float v = xr[1 + j]; s += v; ss += v * v;
    }
    s = block_reduce_sum(s, sm);
    ss = block_reduce_sum(ss, sm);
    float mu = s / (float)(DD - 1);
    float var = ss / (float)(DD - 1) - mu * mu;
    float rstd = rsqrtf(var + 1e-5f);
    float s2 = 0.f;
    for (int j = threadIdx.x; j < DD - 1; j += blockDim.x) {
        float v = (xr[1 + j] - mu) * rstd * g[j] + be[j];
        orow[1 + j] = f2bf(v); s2 += v * v;
    }
    s2 = block_reduce_sum(s2, sm);
    if (threadIdx.x == 0) orow[0] = f2bf(sqrtf(s2 + 1.f));
}

// ---------------- bf16 MFMA GEMM (m97 + XOR swizzle + in-launch split-K) ----------------
__device__ __forceinline__ void cstore(float* p, float v) { *p = v; }
__device__ __forceinline__ void cstore(u16* p, float v) { *p = f2bf(v); }

template <typename OT>
__global__ __launch_bounds__(256) void k_gemm_mfma(
        const u16* __restrict__ A, const u16* __restrict__ BT,
        const float* __restrict__ bias, int nbias,
        OT* __restrict__ C0, OT* __restrict__ C1,
        int ldc, int ldab, int ksplit, int K) {
    __shared__ __align__(16) u16 As[128 * 64];
    __shared__ __align__(16) u16 Bs[128 * 64];
    int z = blockIdx.z;
    int kbeg = z ? ksplit : 0;
    int kend = z ? K : ksplit;
    OT* C = z ? C1 : C0;
    const float* bs = z ? nullptr : bias;

    int tid = threadIdx.x;
    int wave = tid >> 6, lane = tid & 63;
    int quad = lane >> 4, m16 = lane & 15;
    int n0 = blockIdx.x * 128, m0 = blockIdx.y * 128;
    int wm = (wave & 1) * 64, wn = (wave >> 1) * 64;

    f32x4 acc[4][4];
    #pragma unroll
    for (int t = 0; t < 4; ++t)
        #pragma unroll
        for (int u = 0; u < 4; ++u) acc[t][u] = (f32x4){0.f, 0.f, 0.f, 0.f};

    int r8 = lane >> 3;
    int cc = (lane & 7) ^ r8;
    int srow = wave * 32 + r8;
    const u16* ag = A  + (size_t)(m0 + srow) * ldab + cc * 8;
    const u16* bg = BT + (size_t)(n0 + srow) * ldab + cc * 8;
    u16* asl = &As[(wave * 32) * 64];
    u16* bsl = &Bs[(wave * 32) * 64];

    for (int k0 = kbeg; k0 < kend; k0 += 64) {
        __syncthreads();
        #pragma unroll
        for (int j = 0; j < 4; ++j) {
            async16(ag + (size_t)(j * 8) * ldab + k0, asl + (j * 8) * 64);
            async16(bg + (size_t)(j * 8) * ldab + k0, bsl + (j * 8) * 64);
        }
        __syncthreads();
        #pragma unroll
        for (int kk = 0; kk < 2; ++kk) {
            bf16x8 af[4], bfr[4];
            #pragma unroll
            for (int t = 0; t < 4; ++t) {
                int slot = (kk * 4 + quad) ^ (m16 & 7);
                af[t] = *(const bf16x8*)&As[(wm + t * 16 + m16) * 64 + slot * 8];
            }
            #pragma unroll
            for (int u = 0; u < 4; ++u) {
                int slot = (kk * 4 + quad) ^ (m16 & 7);
                bfr[u] = *(const bf16x8*)&Bs[(wn + u * 16 + m16) * 64 + slot * 8];
            }
            #pragma unroll
            for (int t = 0; t < 4; ++t)
                #pragma unroll
                for (int u = 0; u < 4; ++u)
                    acc[t][u] = __builtin_amdgcn_mfma_f32_16x16x32_bf16(af[t], bfr[u], acc[t][u], 0, 0, 0);
        }
    }
    #pragma unroll
    for (int u = 0; u < 4; ++u) {
        int col = n0 + wn + u * 16 + m16;
        float bv = (bs != nullptr && col < nbias) ? bs[col] : 0.f;
        #pragma unroll
        for (int t = 0; t < 4; ++t) {
            #pragma unroll
            for (int r = 0; r < 4; ++r) {
                int row = m0 + wm + t * 16 + quad * 4 + r;
                cstore(C + (size_t)row * ldc + col, acc[t][u][r] + bv);
            }
        }
    }
}

// ---------------- head builders ----------------
__global__ __launch_bounds__(256) void k_build_qk(
        const u16* __restrict__ qkv, int colbase, const float* __restrict__ bias,
        u16* __restrict__ dst, float tsign) {
    int wid = threadIdx.x >> 6, lane = threadIdx.x & 63;
    int idx = blockIdx.x * 4 + wid;
    int h = idx & 15, bn = idx >> 4;
    int b = bn >> 10, n = bn & 1023;
    float v = bf2f(qkv[(size_t)bn * 3072 + colbase + h * 64 + lane]) + bias[h * 64 + lane];
    float ss = v * v;
    #pragma unroll
    for (int o = 32; o > 0; o >>= 1) ss += __shfl_xor(ss, o);
    u16* drow = dst + ((size_t)((b * 16 + h) * 1024 + n)) * 96;
    drow[1 + lane] = f2bf(v);
    if (lane == 0) drow[0] = f2bf(tsign * sqrtf(ss + 1.f));
    if (lane < 31) drow[65 + lane] = 0;
}

__global__ __launch_bounds__(256) void k_build_vt(
        const u16* __restrict__ qkv, int colbase, const float* __restrict__ bias,
        u16* __restrict__ dst) {
    int wid = threadIdx.x >> 6, lane = threadIdx.x & 63;
    int idx = blockIdx.x * 4 + wid;
    int h = idx & 15, bn = idx >> 4;
    int b = bn >> 10, n = bn & 1023;
    float v = bf2f(qkv[(size_t)bn * 3072 + colbase + h * 64 + lane]) + bias[h * 64 + lane];
    float ss = v * v;
    #pragma unroll
    for (int o = 32; o > 0; o >>= 1) ss += __shfl_xor(ss, o);
    u16* base = dst + (size_t)(b * 16 + h) * 80 * 1024 + n;
    base[(size_t)(1 + lane) * 1024] = f2bf(v);
    if (lane == 0) base[0] = f2bf(sqrtf(ss + 1.f));
    if (lane >= 49) base[(size_t)(16 + lane) * 1024] = 0;  // d = 65..79
}

__global__ __launch_bounds__(256) void k_zero_pad(u16* __restrict__ cat) {
    int i = blockIdx.x * 256 + threadIdx.x;
    int r = i / 48, c = i - r * 48;
    cat[(size_t)r * 1088 + 1040 + c] = 0;
}

// ---------------- MFMA flash attention v2 ----------------
// 128 queries/block (2 groups of 64 per wave-set), fixed softmax max (scores <= 0
// mathematically: Lorentz inner product of hyperboloid points <= -1), denominator
// cancels in Lorentz normalization. No mid-loop barrier (Plds is wave-private).
#define AKS 104
#define AVS 72
#define APS 88
#define EXPC 0.36067376f   // 0.25 * log2(e)
__global__ __launch_bounds__(256) void k_attn_mfma(
        const u16* __restrict__ Qp, const u16* __restrict__ Kp,
        const u16* __restrict__ Vt, u16* __restrict__ cat) {
    __shared__ __align__(16) u16 Klds[64 * AKS];
    __shared__ __align__(16) u16 Vlds[80 * AVS];
    __shared__ __align__(16) u16 Plds[4][16 * APS];
    int tid = threadIdx.x;
    int wave = tid >> 6, lane = tid & 63;
    int quad = lane >> 4, m = lane & 15;
    int bh = blockIdx.y, qt = blockIdx.x;   // qt over 8 tiles of 128 queries

    // Q fragments for 2 query groups
    bf16x8 aq[2][3];
    #pragma unroll
    for (int g = 0; g < 2; ++g) {
        const u16* qptr = Qp + ((size_t)bh * 1024 + qt * 128 + g * 64 + wave * 16 + m) * 96;
        aq[g][0] = *(const bf16x8*)(qptr + quad * 8);
        aq[g][1] = *(const bf16x8*)(qptr + 32 + quad * 8);
        aq[g][2] = *(const bf16x8*)(qptr + 64 + quad * 8);
    }

    f32x4 O[2][5];
    #pragma unroll
    for (int g = 0; g < 2; ++g)
        #pragma unroll
        for (int i = 0; i < 5; ++i) O[g][i] = (f32x4){0.f, 0.f, 0.f, 0.f};

    const u16* kg = Kp + (size_t)bh * 1024 * 96;
    const u16* vg = Vt + (size_t)bh * 80 * 1024;

    for (int kt = 0; kt < 16; ++kt) {
        __syncthreads();
        for (int c = tid; c < 768; c += 256) {            // K tile 64x96
            int r = c / 12, col = c - r * 12;
            *(uint4*)&Klds[r * AKS + col * 8] =
                *(const uint4*)(kg + (size_t)(kt * 64 + r) * 96 + col * 8);
        }
        for (int c = tid; c < 640; c += 256) {            // V tile 80x64 (d-major)
            int r = c >> 3, col = c & 7;
            *(uint4*)&Vlds[r * AVS + col * 8] =
                *(const uint4*)(vg + (size_t)r * 1024 + kt * 64 + col * 8);
        }
        __syncthreads();

        u16* pw = &Plds[wave][0];
        #pragma unroll
        for (int g = 0; g < 2; ++g) {
            // scores -> p = exp2(qk*EXPC + EXPC)  (== exp((2+2qk)/8), max fixed at 0)
            #pragma unroll
            for (int nt = 0; nt < 4; ++nt) {
                f32x4 acc = (f32x4){0.f, 0.f, 0.f, 0.f};
                const u16* kr = &Klds[(nt * 16 + m) * AKS + quad * 8];
                acc = __builtin_amdgcn_mfma_f32_16x16x32_bf16(aq[g][0], *(const bf16x8*)(kr),      acc, 0, 0, 0);
                acc = __builtin_amdgcn_mfma_f32_16x16x32_bf16(aq[g][1], *(const bf16x8*)(kr + 32), acc, 0, 0, 0);
                acc = __builtin_amdgcn_mfma_f32_16x16x32_bf16(aq[g][2], *(const bf16x8*)(kr + 64), acc, 0, 0, 0);
                #pragma unroll
                for (int r = 0; r < 4; ++r) {
                    float p = __builtin_amdgcn_exp2f(fmaf(acc[r], EXPC, EXPC));
                    pw[(quad * 4 + r) * APS + nt * 16 + m] = f2bf_fast(p);
                }
            }
            // PV (intra-wave LDS dependency: compiler inserts lgkmcnt wait)
            #pragma unroll
            for (int kc = 0; kc < 2; ++kc) {
                bf16x8 ap = *(const bf16x8*)&Plds[wave][m * APS + kc * 32 + quad * 8];
                #pragma unroll
                for (int vt = 0; vt < 5; ++vt) {
                    bf16x8 bv = *(const bf16x8*)&Vlds[(vt * 16 + m) * AVS + kc * 32 + quad * 8];
                    O[g][vt] = __builtin_amdgcn_mfma_f32_16x16x32_bf16(ap, bv, O[g][vt], 0, 0, 0);
                }
            }
        }
    }
    // epilogue: Lorentz normalize rows, write cat (B,N,1088-stride)
    int b = bh >> 4, h = bh & 15;
    #pragma unroll
    for (int g = 0; g < 2; ++g) {
        #pragma unroll
        for (int r = 0; r < 4; ++r) {
            float part = 0.f;
            #pragma unroll
            for (int vt = 0; vt < 5; ++vt) {
                int c = vt * 16 + m;
                float o = O[g][vt][r];
                part += (c == 0) ? o * o : -o * o;
            }
            part += __shfl_xor(part, 1);
            part += __shfl_xor(part, 2);
            part += __shfl_xor(part, 4);
            part += __shfl_xor(part, 8);
            float rden = rsqrtf(fmaxf(part, 1e-8f));
            int n = qt * 128 + g * 64 + wave * 16 + quad * 4 + r;
            u16* crow = cat + (size_t)(b * 1024 + n) * 1088 + h * 65;
            #pragma unroll
            for (int vt = 0; vt < 5; ++vt) {
                int c = vt * 16 + m;
                if (c < 65) crow[c] = f2bf(O[g][vt][r] * rden);
            }
        }
    }
}

// ---------------- fused lift(y0+y1) + lresnet (fp32) ----------------
__global__ __launch_bounds__(256) void k_lresnet(
        const float* __restrict__ x, const float* __restrict__ y0,
        const float* __restrict__ y1, const float* __restrict__ wscale,
        float* __restrict__ out) {
    __shared__ float sm[8];
    int row = blockIdx.x;
    const float* xr = x + (size_t)row * DD;
    const float* ya = y0 + (size_t)row * 1024;
    const float* yb = y1 + (size_t)row * 1024;
    float w = *wscale;
    float zreg[4];
    float sy = 0.f, sz = 0.f;
    int cnt = 0;
    for (int j = threadIdx.x; j < DD - 1; j += blockDim.x) {
        float yv = ya[j] + yb[j];
        float zv = xr[1 + j] + w * yv;
        sy += yv * yv; sz += zv * zv;
        zreg[cnt++] = zv;
    }
    sy = block_reduce_sum(sy, sm);
    sz = block_reduce_sum(sz, sm);
    float y0t = sqrtf(sy + 1.f);
    float z0 = xr[0] + w * y0t;
    float q = z0 * z0 - sz;
    float rden = rsqrtf(fmaxf(q, 1e-8f));
    cnt = 0;
    for (int j = threadIdx.x; j < DD - 1; j += blockDim.x)
        out[(size_t)row * DD + 1 + j] = zreg[cnt++] * rden;
    if (threadIdx.x == 0) out[(size_t)row * DD] = z0 * rden;
}

// ---------------- gelu (exact) + lift: bf16 in -> bf16 lifted out ----------------
__global__ __launch_bounds__(256) void k_gelu_lift(
        const u16* __restrict__ hfc, u16* __restrict__ hg) {
    __shared__ float sm[8];
    int row = blockIdx.x;
    const u16* hr = hfc + (size_t)row * 4096;
    u16* gr = hg + (size_t)row * 4096;
    float s2 = 0.f;
    for (int j = threadIdx.x; j < 4095; j += blockDim.x) {
        float v = bf2f(hr[j]);
        float gl = 0.5f * v * (1.f + erff(v * 0.70710678f));
        gr[1 + j] = f2bf(gl); s2 += gl * gl;
    }
    s2 = block_reduce_sum(s2, sm);
    if (threadIdx.x == 0) gr[0] = f2bf(sqrtf(s2 + 1.f));
}

// ---------------- launch ----------------
extern "C" void kernel_launch(void* const* d_in, const int* in_sizes, int n_in,
                              void* d_out, int out_size, void* d_ws, size_t ws_size,
                              hipStream_t stream) {
    const float* x   = (const float*)d_in[0];
    const float* g1  = (const float*)d_in[1];
    const float* b1  = (const float*)d_in[2];
    const float* Wq  = (const float*)d_in[3];
    const float* bq  = (const float*)d_in[4];
    const float* Wk  = (const float*)d_in[5];
    const float* bk  = (const float*)d_in[6];
    const float* Wv  = (const float*)d_in[7];
    const float* bv  = (const float*)d_in[8];
    const float* Wo  = (const float*)d_in[9];
    const float* bo  = (const float*)d_in[10];
    const float* g2  = (const float*)d_in[11];
    const float* b2  = (const float*)d_in[12];
    const float* Wfc = (const float*)d_in[13];
    const float* bfc = (const float*)d_in[14];
    const float* Wpj = (const float*)d_in[15];
    const float* bpj = (const float*)d_in[16];
    const float* w1  = (const float*)d_in[17];
    const float* w2  = (const float*)d_in[18];
    float* out = (float*)d_out;

    char* W = (char*)d_ws;
    // byte offsets; peak 117,571,584 B
    u16* lx_bf  = (u16*)(W + 0);            // 8 MB (ln1, later ln2)
    u16* WqkvT  = (u16*)(W + 8388608);      // [3072][1024]
    u16* WoT    = (u16*)(W + 14680064);     // [1024][1088]
    u16* WfcT   = (u16*)(W + 16908288);     // [4096][1024]
    u16* WpjT   = (u16*)(W + 25296896);     // [1024][4096]
    u16* qkv_bf = (u16*)(W + 33685504);     // 4096x3072 (dead after builders)
    u16* Qp     = (u16*)(W + 58851328);     // 64x1024x96
    u16* Kp     = (u16*)(W + 71434240);
    u16* Vt     = (u16*)(W + 84017152);     // 64x80x1024
    u16* cat_bf = (u16*)(W + 94502912);     // 4096x1088
    float* ax0  = (float*)(W + 33685504);   // overlay qkv (dead)
    float* ax1  = (float*)(W + 50462720);   // overlay qkv/Qp-head (dead)
    float* x1   = (float*)(W + 67239936);   // overlay Qp-tail/Kp (dead)
    u16* hfc_bf = (u16*)(W + 84017152);     // 32MB, overlay Vt/cat (dead)
    u16* hg_bf  = (u16*)(W + 33685504);     // 32MB, overlay ax0/ax1 (dead)
    float* h2a  = (float*)(W + 84017152);   // overlay hfc (dead after gelu)
    float* h2b  = (float*)(W + 100794368);

    dim3 blk(256);

    // weight conversion + transpose
    k_convT<<<dim3(32, 32), blk, 0, stream>>>(Wq, WqkvT,                 1024, 1024, 1024, 1024);
    k_convT<<<dim3(32, 32), blk, 0, stream>>>(Wk, WqkvT + 1024 * 1024,   1024, 1024, 1024, 1024);
    k_convT<<<dim3(32, 32), blk, 0, stream>>>(Wv, WqkvT + 2048 * 1024,   1024, 1024, 1024, 1024);
    k_convT<<<dim3(34, 32), blk, 0, stream>>>(Wo, WoT,                   1040, 1023, 1088, 1024);
    k_convT<<<dim3(32, 128), blk, 0, stream>>>(Wfc, WfcT,                1024, 4095, 1024, 4096);
    k_convT<<<dim3(128, 32), blk, 0, stream>>>(Wpj, WpjT,                4096, 1023, 4096, 1024);

    // 1) lx = lorentz_layernorm(x) -> bf16
    k_layernorm_lift_bf<<<ROWS, blk, 0, stream>>>(x, g1, b1, lx_bf);

    // 2) fused QKV GEMM + head layouts
    k_gemm_mfma<u16><<<dim3(24, 32, 1), blk, 0, stream>>>(
        lx_bf, WqkvT, nullptr, 0, qkv_bf, qkv_bf, 3072, 1024, 1024, 1024);
    k_build_qk<<<ROWS * HH / 4, blk, 0, stream>>>(qkv_bf, 0,    bq, Qp, -1.f);
    k_build_qk<<<ROWS * HH / 4, blk, 0, stream>>>(qkv_bf, 1024, bk, Kp, 1.f);
    k_build_vt<<<ROWS * HH / 4, blk, 0, stream>>>(qkv_bf, 2048, bv, Vt);

    // 3) MFMA flash attention v2 -> cat_bf (stride 1088)
    k_zero_pad<<<768, blk, 0, stream>>>(cat_bf);
    k_attn_mfma<<<dim3(8, 64), blk, 0, stream>>>(Qp, Kp, Vt, cat_bf);

    // 4) ax = cat @ Wo + bo, split-K (576+512) in one launch
    k_gemm_mfma<float><<<dim3(8, 32, 2), blk, 0, stream>>>(
        cat_bf, WoT, bo, 1023, ax0, ax1, 1024, 1088, 576, 1088);

    // 5) x1 = lresnet(x, lift(ax0+ax1), w1)
    k_lresnet<<<ROWS, blk, 0, stream>>>(x, ax0, ax1, w1, x1);

    // 6) ln2 -> bf16 (reuse lx_bf)
    k_layernorm_lift_bf<<<ROWS, blk, 0, stream>>>(x1, g2, b2, lx_bf);

    // 7) hfc = ln2 @ Wfc + bfc (bf16 out)
    k_gemm_mfma<u16><<<dim3(32, 32, 1), blk, 0, stream>>>(
        lx_bf, WfcT, bfc, 4095, hfc_bf, hfc_bf, 4096, 1024, 1024, 1024);

    // 8) hg = lift(gelu(hfc)) bf16
    k_gelu_lift<<<ROWS, blk, 0, stream>>>(hfc_bf, hg_bf);

    // 9) h2 = hg @ Wpj + bpj, split-K (2048+2048) in one launch
    k_gemm_mfma<float><<<dim3(8, 32, 2), blk, 0, stream>>>(
        hg_bf, WpjT, bpj, 1023, h2a, h2b, 1024, 4096, 2048, 4096);

    // 10) out = lresnet(x1, lift(h2a+h2b), w2)
    k_lresnet<<<ROWS, blk, 0, stream>>>(x1, h2a, h2b, w2, out);
}

// Round 6
// 462.133 us; speedup vs baseline: 9.8726x; 1.0590x over previous
//
#include <hip/hip_runtime.h>
#include <math.h>

#define BB 4
#define NN 1024
#define DD 1024
#define HH 16
#define ROWS (BB*NN)   // 4096

typedef __attribute__((ext_vector_type(8))) short bf16x8;
typedef __attribute__((ext_vector_type(4))) float f32x4;
typedef unsigned short u16;

__device__ __forceinline__ u16 f2bf(float f) {
    union { float f; unsigned u; } v; v.f = f;
    unsigned r = v.u + 0x7fff + ((v.u >> 16) & 1);
    return (u16)(r >> 16);
}
__device__ __forceinline__ float bf2f(u16 u) {
    union { unsigned u; float f; } v; v.u = ((unsigned)u) << 16; return v.f;
}

// async global->LDS, 16B per lane. LDS dest = wave-uniform base (+lane*16 implicit).
__device__ __forceinline__ void async16(const void* g, void* l) {
    __builtin_amdgcn_global_load_lds(
        (__attribute__((address_space(1))) void*)(uintptr_t)g,
        (__attribute__((address_space(3))) void*)(uintptr_t)l,
        16, 0, 0);
}

// ---------------- block reduce ----------------
__device__ __forceinline__ float block_reduce_sum(float v, float* sm) {
    #pragma unroll
    for (int o = 32; o > 0; o >>= 1) v += __shfl_down(v, o);
    int lane = threadIdx.x & 63, wid = threadIdx.x >> 6;
    if (lane == 0) sm[wid] = v;
    __syncthreads();
    if (wid == 0) {
        v = (lane < (int)(blockDim.x >> 6)) ? sm[lane] : 0.f;
        #pragma unroll
        for (int o = 2; o > 0; o >>= 1) v += __shfl_down(v, o);
        if (lane == 0) sm[0] = v;
    }
    __syncthreads();
    float r = sm[0];
    __syncthreads();
    return r;
}

// ---------------- fused weight transpose + bf16 convert (all 6 weights, 1 launch) ----------------
__global__ __launch_bounds__(256) void k_convT_all(
        const float* __restrict__ Wq_, const float* __restrict__ Wk_,
        const float* __restrict__ Wv_, const float* __restrict__ Wo_,
        const float* __restrict__ Wfc_, const float* __restrict__ Wpj_,
        u16* __restrict__ WqkvT, u16* __restrict__ WoT,
        u16* __restrict__ WfcT, u16* __restrict__ WpjT) {
    __shared__ float t[32][33];
    int bid = blockIdx.x;
    const float* W; u16* out; int K, N, Kpad, Npad, gx;
    if (bid < 1024)      { W = Wq_;  out = WqkvT;              K = 1024; N = 1024; Kpad = 1024; Npad = 1024; gx = 32; }
    else if (bid < 2048) { W = Wk_;  out = WqkvT + 1048576;    K = 1024; N = 1024; Kpad = 1024; Npad = 1024; gx = 32; bid -= 1024; }
    else if (bid < 3072) { W = Wv_;  out = WqkvT + 2097152;    K = 1024; N = 1024; Kpad = 1024; Npad = 1024; gx = 32; bid -= 2048; }
    else if (bid < 4160) { W = Wo_;  out = WoT;                K = 1040; N = 1023; Kpad = 1088; Npad = 1024; gx = 34; bid -= 3072; }
    else if (bid < 8256) { W = Wfc_; out = WfcT;               K = 1024; N = 4095; Kpad = 1024; Npad = 4096; gx = 32; bid -= 4160; }
    else                 { W = Wpj_; out = WpjT;               K = 4096; N = 1023; Kpad = 4096; Npad = 1024; gx = 128; bid -= 8256; }
    int k0 = (bid % gx) * 32, n0 = (bid / gx) * 32;
    int tx = threadIdx.x & 31, ty = threadIdx.x >> 5;
    #pragma unroll
    for (int i = 0; i < 32; i += 8) {
        int k = k0 + ty + i, n = n0 + tx;
        t[ty + i][tx] = (k < K && n < N) ? W[(size_t)k * N + n] : 0.f;
    }
    __syncthreads();
    #pragma unroll
    for (int i = 0; i < 32; i += 8) {
        int n = n0 + ty + i, k = k0 + tx;
        if (n < Npad && k < Kpad) out[(size_t)n * Kpad + k] = f2bf(t[tx][ty + i]);
    }
}

// ---------------- layernorm + lift -> bf16 ----------------
__global__ __launch_bounds__(256) void k_layernorm_lift_bf(
        const float* __restrict__ x, const float* __restrict__ g,
        const float* __restrict__ be, u16* __restrict__ out) {
    __shared__ float sm[8];
    int row = blockIdx.x;
    const float* xr = x + (size_t)row * DD;
    u16* orow = out + (size_t)row * DD;
    float s = 0.f, ss = 0.f;
    for (int j = threadIdx.x; j < DD - 1; j += blockDim.x) {
        float v = xr[1 + j]; s += v; ss += v * v;
    }
    s = block_reduce_sum(s, sm);
    ss = block_reduce_sum(ss, sm);
    float mu = s / (float)(DD - 1);
    float var = ss / (float)(DD - 1) - mu * mu;
    float rstd = rsqrtf(var + 1e-5f);
    float s2 = 0.f;
    for (int j = threadIdx.x; j < DD - 1; j += blockDim.x) {
        float v = (xr[1 + j] - mu) * rstd * g[j] + be[j];
        orow[1 + j] = f2bf(v); s2 += v * v;
    }
    s2 = block_reduce_sum(s2, sm);
    if (threadIdx.x == 0) orow[0] = f2bf(sqrtf(s2 + 1.f));
}

// ---------------- bf16 MFMA GEMM (m97 + XOR swizzle + in-launch split-K) ----------------
__device__ __forceinline__ void cstore(float* p, float v) { *p = v; }
__device__ __forceinline__ void cstore(u16* p, float v) { *p = f2bf(v); }

template <typename OT>
__global__ __launch_bounds__(256) void k_gemm_mfma(
        const u16* __restrict__ A, const u16* __restrict__ BT,
        const float* __restrict__ bias, int nbias,
        OT* __restrict__ C0, OT* __restrict__ C1,
        int ldc, int ldab, int ksplit, int K) {
    __shared__ __align__(16) u16 As[128 * 64];
    __shared__ __align__(16) u16 Bs[128 * 64];
    int z = blockIdx.z;
    int kbeg = z ? ksplit : 0;
    int kend = z ? K : ksplit;
    OT* C = z ? C1 : C0;
    const float* bs = z ? nullptr : bias;

    int tid = threadIdx.x;
    int wave = tid >> 6, lane = tid & 63;
    int quad = lane >> 4, m16 = lane & 15;
    int n0 = blockIdx.x * 128, m0 = blockIdx.y * 128;
    int wm = (wave & 1) * 64, wn = (wave >> 1) * 64;

    f32x4 acc[4][4];
    #pragma unroll
    for (int t = 0; t < 4; ++t)
        #pragma unroll
        for (int u = 0; u < 4; ++u) acc[t][u] = (f32x4){0.f, 0.f, 0.f, 0.f};

    int r8 = lane >> 3;
    int cc = (lane & 7) ^ r8;
    int srow = wave * 32 + r8;
    const u16* ag = A  + (size_t)(m0 + srow) * ldab + cc * 8;
    const u16* bg = BT + (size_t)(n0 + srow) * ldab + cc * 8;
    u16* asl = &As[(wave * 32) * 64];
    u16* bsl = &Bs[(wave * 32) * 64];

    for (int k0 = kbeg; k0 < kend; k0 += 64) {
        __syncthreads();
        #pragma unroll
        for (int j = 0; j < 4; ++j) {
            async16(ag + (size_t)(j * 8) * ldab + k0, asl + (j * 8) * 64);
            async16(bg + (size_t)(j * 8) * ldab + k0, bsl + (j * 8) * 64);
        }
        __syncthreads();
        #pragma unroll
        for (int kk = 0; kk < 2; ++kk) {
            bf16x8 af[4], bfr[4];
            #pragma unroll
            for (int t = 0; t < 4; ++t) {
                int slot = (kk * 4 + quad) ^ (m16 & 7);
                af[t] = *(const bf16x8*)&As[(wm + t * 16 + m16) * 64 + slot * 8];
            }
            #pragma unroll
            for (int u = 0; u < 4; ++u) {
                int slot = (kk * 4 + quad) ^ (m16 & 7);
                bfr[u] = *(const bf16x8*)&Bs[(wn + u * 16 + m16) * 64 + slot * 8];
            }
            #pragma unroll
            for (int t = 0; t < 4; ++t)
                #pragma unroll
                for (int u = 0; u < 4; ++u)
                    acc[t][u] = __builtin_amdgcn_mfma_f32_16x16x32_bf16(af[t], bfr[u], acc[t][u], 0, 0, 0);
        }
    }
    #pragma unroll
    for (int u = 0; u < 4; ++u) {
        int col = n0 + wn + u * 16 + m16;
        float bv = (bs != nullptr && col < nbias) ? bs[col] : 0.f;
        #pragma unroll
        for (int t = 0; t < 4; ++t) {
            #pragma unroll
            for (int r = 0; r < 4; ++r) {
                int row = m0 + wm + t * 16 + quad * 4 + r;
                cstore(C + (size_t)row * ldc + col, acc[t][u][r] + bv);
            }
        }
    }
}

// ---------------- fused head builder (Q, K, V in one launch via blockIdx.y) ----------------
// Q: (bh, n, 96), time negated. K: (bh, n, 104). V: tiled (bh, kt, d, 72), tile stride 6144.
__global__ __launch_bounds__(256) void k_build_heads(
        const u16* __restrict__ qkv,
        const float* __restrict__ bq, const float* __restrict__ bk,
        const float* __restrict__ bv,
        u16* __restrict__ Qp, u16* __restrict__ Kp, u16* __restrict__ V2) {
    int wid = threadIdx.x >> 6, lane = threadIdx.x & 63;
    int idx = blockIdx.x * 4 + wid;
    int h = idx & 15, bn = idx >> 4;
    int b = bn >> 10, n = bn & 1023;
    int sec = blockIdx.y;
    const float* bias = (sec == 0) ? bq : (sec == 1) ? bk : bv;
    float v = bf2f(qkv[(size_t)bn * 3072 + sec * 1024 + h * 64 + lane]) + bias[h * 64 + lane];
    float ss = v * v;
    #pragma unroll
    for (int o = 32; o > 0; o >>= 1) ss += __shfl_xor(ss, o);
    float tcomp = sqrtf(ss + 1.f);
    size_t bhn = (size_t)(b * 16 + h) * 1024 + n;
    if (sec == 0) {
        u16* drow = Qp + bhn * 96;
        drow[1 + lane] = f2bf(v);
        if (lane == 0) drow[0] = f2bf(-tcomp);
        if (lane < 31) drow[65 + lane] = 0;
    } else if (sec == 1) {
        u16* drow = Kp + bhn * 104;
        drow[1 + lane] = f2bf(v);
        if (lane == 0) drow[0] = f2bf(tcomp);
        if (lane < 39) drow[65 + lane] = 0;
    } else {
        u16* base = V2 + ((size_t)(b * 16 + h) * 16 + (n >> 6)) * 6144 + (n & 63);
        base[(1 + lane) * 72] = f2bf(v);
        if (lane == 0) base[0] = f2bf(tcomp);
        if (lane >= 49) base[(16 + lane) * 72] = 0;   // d = 65..79
    }
}

__global__ __launch_bounds__(256) void k_zero_pad(u16* __restrict__ cat) {
    int i = blockIdx.x * 256 + threadIdx.x;
    int r = i / 48, c = i - r * 48;
    cat[(size_t)r * 1088 + 1040 + c] = 0;
}

// ---------------- MFMA flash attention v3: double-buffered async K/V staging ----------------
// 128 queries/block, fixed softmax max (scores <= 0), denominator cancels.
// K tile: flat 64x104 (13312 B); V tile: flat 6144 u16 (12288 B, rows d*72+r valid d<80,r<64).
#define AKS 104
#define AVS 72
#define APS 88
#define KTILE_U16 (64 * AKS)   // 6656
#define VTILE_U16 6144
#define EXPC 0.36067376f       // 0.25 * log2(e)
__global__ __launch_bounds__(256) void k_attn_mfma(
        const u16* __restrict__ Qp, const u16* __restrict__ Kp,
        const u16* __restrict__ V2, u16* __restrict__ cat) {
    __shared__ __align__(16) u16 Klds[2][KTILE_U16];
    __shared__ __align__(16) u16 Vlds[2][VTILE_U16];
    __shared__ __align__(16) u16 Plds[4][16 * APS];
    int tid = threadIdx.x;
    int wave = tid >> 6, lane = tid & 63;
    int quad = lane >> 4, m = lane & 15;
    int bh = blockIdx.y, qt = blockIdx.x;

    const u16* kg = Kp + (size_t)bh * 16 * KTILE_U16;
    const u16* vg = V2 + (size_t)bh * 16 * VTILE_U16;

    // Q fragments for 2 query groups of 64
    bf16x8 aq[2][3];
    #pragma unroll
    for (int g = 0; g < 2; ++g) {
        const u16* qptr = Qp + ((size_t)bh * 1024 + qt * 128 + g * 64 + wave * 16 + m) * 96;
        aq[g][0] = *(const bf16x8*)(qptr + quad * 8);
        aq[g][1] = *(const bf16x8*)(qptr + 32 + quad * 8);
        aq[g][2] = *(const bf16x8*)(qptr + 64 + quad * 8);
    }

    f32x4 O[2][5];
    #pragma unroll
    for (int g = 0; g < 2; ++g)
        #pragma unroll
        for (int i = 0; i < 5; ++i) O[g][i] = (f32x4){0.f, 0.f, 0.f, 0.f};

    // flat async stage of tile kt into buffer s: 13 K-insts + 12 V-insts of 1 KB/wave
    auto stage = [&](int kt, int s) {
        const u16* kt_p = kg + kt * KTILE_U16 + lane * 8;
        const u16* vt_p = vg + kt * VTILE_U16 + lane * 8;
        for (int i = wave; i < 25; i += 4) {
            if (i < 13) async16(kt_p + i * 512, &Klds[s][i * 512]);
            else        async16(vt_p + (i - 13) * 512, &Vlds[s][(i - 13) * 512]);
        }
    };

    stage(0, 0);
    for (int kt = 0; kt < 16; ++kt) {
        int cur = kt & 1;
        __syncthreads();                       // drains staging of tile kt (vmcnt) + prior LDS reads
        if (kt < 15) stage(kt + 1, cur ^ 1);   // prefetch flies during this iter's MFMA
        u16* pw = &Plds[wave][0];
        #pragma unroll
        for (int g = 0; g < 2; ++g) {
            #pragma unroll
            for (int nt = 0; nt < 4; ++nt) {
                f32x4 acc = (f32x4){0.f, 0.f, 0.f, 0.f};
                const u16* kr = &Klds[cur][(nt * 16 + m) * AKS + quad * 8];
                acc = __builtin_amdgcn_mfma_f32_16x16x32_bf16(aq[g][0], *(const bf16x8*)(kr),      acc, 0, 0, 0);
                acc = __builtin_amdgcn_mfma_f32_16x16x32_bf16(aq[g][1], *(const bf16x8*)(kr + 32), acc, 0, 0, 0);
                acc = __builtin_amdgcn_mfma_f32_16x16x32_bf16(aq[g][2], *(const bf16x8*)(kr + 64), acc, 0, 0, 0);
                #pragma unroll
                for (int r = 0; r < 4; ++r) {
                    float p = __builtin_amdgcn_exp2f(fmaf(acc[r], EXPC, EXPC));
                    union { float f; unsigned u; } pv; pv.f = p;
                    pw[(quad * 4 + r) * APS + nt * 16 + m] = (u16)((pv.u + 0x8000u) >> 16);
                }
            }
            #pragma unroll
            for (int kc = 0; kc < 2; ++kc) {
                bf16x8 ap = *(const bf16x8*)&Plds[wave][m * APS + kc * 32 + quad * 8];
                #pragma unroll
                for (int vt = 0; vt < 5; ++vt) {
                    bf16x8 bv = *(const bf16x8*)&Vlds[cur][(vt * 16 + m) * AVS + kc * 32 + quad * 8];
                    O[g][vt] = __builtin_amdgcn_mfma_f32_16x16x32_bf16(ap, bv, O[g][vt], 0, 0, 0);
                }
            }
        }
    }
    // epilogue: Lorentz normalize rows, write cat (stride 1088)
    int b = bh >> 4, h = bh & 15;
    #pragma unroll
    for (int g = 0; g < 2; ++g) {
        #pragma unroll
        for (int r = 0; r < 4; ++r) {
            float part = 0.f;
            #pragma unroll
            for (int vt = 0; vt < 5; ++vt) {
                int c = vt * 16 + m;
                float o = O[g][vt][r];
                part += (c == 0) ? o * o : -o * o;
            }
            part += __shfl_xor(part, 1);
            part += __shfl_xor(part, 2);
            part += __shfl_xor(part, 4);
            part += __shfl_xor(part, 8);
            float rden = rsqrtf(fmaxf(part, 1e-8f));
            int n = qt * 128 + g * 64 + wave * 16 + quad * 4 + r;
            u16* crow = cat + (size_t)(b * 1024 + n) * 1088 + h * 65;
            #pragma unroll
            for (int vt = 0; vt < 5; ++vt) {
                int c = vt * 16 + m;
                if (c < 65) crow[c] = f2bf(O[g][vt][r] * rden);
            }
        }
    }
}

// ---------------- fused lift(y0+y1) + lresnet (fp32) ----------------
__global__ __launch_bounds__(256) void k_lresnet(
        const float* __restrict__ x, const float* __restrict__ y0,
        const float* __restrict__ y1, const float* __restrict__ wscale,
        float* __restrict__ out) {
    __shared__ float sm[8];
    int row = blockIdx.x;
    const float* xr = x + (size_t)row * DD;
    const float* ya = y0 + (size_t)row * 1024;
    const float* yb = y1 + (size_t)row * 1024;
    float w = *wscale;
    float zreg[4];
    float sy = 0.f, sz = 0.f;
    int cnt = 0;
    for (int j = threadIdx.x; j < DD - 1; j += blockDim.x) {
        float yv = ya[j] + yb[j];
        float zv = xr[1 + j] + w * yv;
        sy += yv * yv; sz += zv * zv;
        zreg[cnt++] = zv;
    }
    sy = block_reduce_sum(sy, sm);
    sz = block_reduce_sum(sz, sm);
    float y0t = sqrtf(sy + 1.f);
    float z0 = xr[0] + w * y0t;
    float q = z0 * z0 - sz;
    float rden = rsqrtf(fmaxf(q, 1e-8f));
    cnt = 0;
    for (int j = threadIdx.x; j < DD - 1; j += blockDim.x)
        out[(size_t)row * DD + 1 + j] = zreg[cnt++] * rden;
    if (threadIdx.x == 0) out[(size_t)row * DD] = z0 * rden;
}

// ---------------- gelu (exact) + lift: bf16 in -> bf16 lifted out ----------------
__global__ __launch_bounds__(256) void k_gelu_lift(
        const u16* __restrict__ hfc, u16* __restrict__ hg) {
    __shared__ float sm[8];
    int row = blockIdx.x;
    const u16* hr = hfc + (size_t)row * 4096;
    u16* gr = hg + (size_t)row * 4096;
    float s2 = 0.f;
    for (int j = threadIdx.x; j < 4095; j += blockDim.x) {
        float v = bf2f(hr[j]);
        float gl = 0.5f * v * (1.f + erff(v * 0.70710678f));
        gr[1 + j] = f2bf(gl); s2 += gl * gl;
    }
    s2 = block_reduce_sum(s2, sm);
    if (threadIdx.x == 0) gr[0] = f2bf(sqrtf(s2 + 1.f));
}

// ---------------- launch ----------------
extern "C" void kernel_launch(void* const* d_in, const int* in_sizes, int n_in,
                              void* d_out, int out_size, void* d_ws, size_t ws_size,
                              hipStream_t stream) {
    const float* x   = (const float*)d_in[0];
    const float* g1  = (const float*)d_in[1];
    const float* b1  = (const float*)d_in[2];
    const float* Wq  = (const float*)d_in[3];
    const float* bq  = (const float*)d_in[4];
    const float* Wk  = (const float*)d_in[5];
    const float* bk  = (const float*)d_in[6];
    const float* Wv  = (const float*)d_in[7];
    const float* bv  = (const float*)d_in[8];
    const float* Wo  = (const float*)d_in[9];
    const float* bo  = (const float*)d_in[10];
    const float* g2  = (const float*)d_in[11];
    const float* b2  = (const float*)d_in[12];
    const float* Wfc = (const float*)d_in[13];
    const float* bfc = (const float*)d_in[14];
    const float* Wpj = (const float*)d_in[15];
    const float* bpj = (const float*)d_in[16];
    const float* w1  = (const float*)d_in[17];
    const float* w2  = (const float*)d_in[18];
    float* out = (float*)d_out;

    char* W = (char*)d_ws;
    // byte offsets; peak 117,571,584 B
    u16* lx_bf  = (u16*)(W + 0);            // 8 MB (ln1, later ln2)
    u16* WqkvT  = (u16*)(W + 8388608);      // [3072][1024]        -> 14,680,064
    u16* WoT    = (u16*)(W + 14680064);     // [1024][1088]        -> 16,908,288
    u16* WfcT   = (u16*)(W + 16908288);     // [4096][1024]        -> 25,296,896
    u16* WpjT   = (u16*)(W + 25296896);     // [1024][4096]        -> 33,685,504
    u16* qkv_bf = (u16*)(W + 33685504);     // 4096x3072           -> 58,851,328 (dead after builders)
    u16* Qp     = (u16*)(W + 58851328);     // 64x1024x96          -> 71,434,240
    u16* Kp     = (u16*)(W + 71434240);     // 64x1024x104         -> 85,065,728
    u16* V2     = (u16*)(W + 85065728);     // 64x16x6144          -> 97,648,640
    u16* cat_bf = (u16*)(W + 97648640);     // 4096x1088           -> 106,561,536
    float* ax0  = (float*)(W + 33685504);   // overlay qkv (dead)
    float* ax1  = (float*)(W + 50462720);   // overlay qkv/Qp-head (dead)
    float* x1   = (float*)(W + 67239936);   // overlay Qp-tail/Kp (dead)  -> 84,017,152
    u16* hfc_bf = (u16*)(W + 84017152);     // 32MB, overlay Kp-tail/V2/cat (dead) -> 117,571,584
    u16* hg_bf  = (u16*)(W + 33685504);     // 32MB, overlay ax0/ax1 (dead) -> 67,239,936
    float* h2a  = (float*)(W + 84017152);   // overlay hfc (dead after gelu)
    float* h2b  = (float*)(W + 100794368);

    dim3 blk(256);

    // weight conversion + transpose (one launch, 12352 blocks)
    k_convT_all<<<12352, blk, 0, stream>>>(Wq, Wk, Wv, Wo, Wfc, Wpj,
                                           WqkvT, WoT, WfcT, WpjT);

    // 1) lx = lorentz_layernorm(x) -> bf16
    k_layernorm_lift_bf<<<ROWS, blk, 0, stream>>>(x, g1, b1, lx_bf);

    // 2) fused QKV GEMM + head layouts (one builder launch)
    k_gemm_mfma<u16><<<dim3(24, 32, 1), blk, 0, stream>>>(
        lx_bf, WqkvT, nullptr, 0, qkv_bf, qkv_bf, 3072, 1024, 1024, 1024);
    k_build_heads<<<dim3(ROWS * HH / 4, 3), blk, 0, stream>>>(
        qkv_bf, bq, bk, bv, Qp, Kp, V2);

    // 3) MFMA flash attention v3 -> cat_bf (stride 1088)
    k_zero_pad<<<768, blk, 0, stream>>>(cat_bf);
    k_attn_mfma<<<dim3(8, 64), blk, 0, stream>>>(Qp, Kp, V2, cat_bf);

    // 4) ax = cat @ Wo + bo, split-K (576+512)
    k_gemm_mfma<float><<<dim3(8, 32, 2), blk, 0, stream>>>(
        cat_bf, WoT, bo, 1023, ax0, ax1, 1024, 1088, 576, 1088);

    // 5) x1 = lresnet(x, lift(ax0+ax1), w1)
    k_lresnet<<<ROWS, blk, 0, stream>>>(x, ax0, ax1, w1, x1);

    // 6) ln2 -> bf16 (reuse lx_bf)
    k_layernorm_lift_bf<<<ROWS, blk, 0, stream>>>(x1, g2, b2, lx_bf);

    // 7) hfc = ln2 @ Wfc + bfc (bf16 out)
    k_gemm_mfma<u16><<<dim3(32, 32, 1), blk, 0, stream>>>(
        lx_bf, WfcT, bfc, 4095, hfc_bf, hfc_bf, 4096, 1024, 1024, 1024);

    // 8) hg = lift(gelu(hfc)) bf16
    k_gelu_lift<<<ROWS, blk, 0, stream>>>(hfc_bf, hg_bf);

    // 9) h2 = hg @ Wpj + bpj, split-K (2048+2048)
    k_gemm_mfma<float><<<dim3(8, 32, 2), blk, 0, stream>>>(
        hg_bf, WpjT, bpj, 1023, h2a, h2b, 1024, 4096, 2048, 4096);

    // 10) out = lresnet(x1, lift(h2a+h2b), w2)
    k_lresnet<<<ROWS, blk, 0, stream>>>(x1, h2a, h2b, w2, out);
}

// Round 7
// 446.629 us; speedup vs baseline: 10.2153x; 1.0347x over previous
//
#include <hip/hip_runtime.h>
#include <math.h>

#define BB 4
#define NN 1024
#define DD 1024
#define HH 16
#define ROWS (BB*NN)   // 4096

typedef __attribute__((ext_vector_type(8))) short bf16x8;
typedef __attribute__((ext_vector_type(4))) float f32x4;
typedef unsigned short u16;

__device__ __forceinline__ u16 f2bf(float f) {
    union { float f; unsigned u; } v; v.f = f;
    unsigned r = v.u + 0x7fff + ((v.u >> 16) & 1);
    return (u16)(r >> 16);
}
__device__ __forceinline__ float bf2f(u16 u) {
    union { unsigned u; float f; } v; v.u = ((unsigned)u) << 16; return v.f;
}

// async global->LDS, 16B per lane. LDS dest = wave-uniform base (+lane*16 implicit).
__device__ __forceinline__ void async16(const void* g, void* l) {
    __builtin_amdgcn_global_load_lds(
        (__attribute__((address_space(1))) void*)(uintptr_t)g,
        (__attribute__((address_space(3))) void*)(uintptr_t)l,
        16, 0, 0);
}

// ---------------- block reduce ----------------
__device__ __forceinline__ float block_reduce_sum(float v, float* sm) {
    #pragma unroll
    for (int o = 32; o > 0; o >>= 1) v += __shfl_down(v, o);
    int lane = threadIdx.x & 63, wid = threadIdx.x >> 6;
    if (lane == 0) sm[wid] = v;
    __syncthreads();
    if (wid == 0) {
        v = (lane < (int)(blockDim.x >> 6)) ? sm[lane] : 0.f;
        #pragma unroll
        for (int o = 2; o > 0; o >>= 1) v += __shfl_down(v, o);
        if (lane == 0) sm[0] = v;
    }
    __syncthreads();
    float r = sm[0];
    __syncthreads();
    return r;
}

// ---------------- fused: weight transpose+convert (6 weights) AND layernorm1 ----------------
// bid < 12352: convT path; else ln1 path (row = bid - 12352).
__global__ __launch_bounds__(256) void k_pre(
        const float* __restrict__ Wq_, const float* __restrict__ Wk_,
        const float* __restrict__ Wv_, const float* __restrict__ Wo_,
        const float* __restrict__ Wfc_, const float* __restrict__ Wpj_,
        u16* __restrict__ WqkvT, u16* __restrict__ WoT,
        u16* __restrict__ WfcT, u16* __restrict__ WpjT,
        const float* __restrict__ x, const float* __restrict__ g1,
        const float* __restrict__ be1, u16* __restrict__ lnout) {
    __shared__ float t[32][33];
    int bid = blockIdx.x;
    if (bid < 12352) {
        const float* W; u16* out; int K, N, Kpad, Npad, gx;
        if (bid < 1024)      { W = Wq_;  out = WqkvT;            K = 1024; N = 1024; Kpad = 1024; Npad = 1024; gx = 32; }
        else if (bid < 2048) { W = Wk_;  out = WqkvT + 1048576;  K = 1024; N = 1024; Kpad = 1024; Npad = 1024; gx = 32; bid -= 1024; }
        else if (bid < 3072) { W = Wv_;  out = WqkvT + 2097152;  K = 1024; N = 1024; Kpad = 1024; Npad = 1024; gx = 32; bid -= 2048; }
        else if (bid < 4160) { W = Wo_;  out = WoT;              K = 1040; N = 1023; Kpad = 1088; Npad = 1024; gx = 34; bid -= 3072; }
        else if (bid < 8256) { W = Wfc_; out = WfcT;             K = 1024; N = 4095; Kpad = 1024; Npad = 4096; gx = 32; bid -= 4160; }
        else                 { W = Wpj_; out = WpjT;             K = 4096; N = 1023; Kpad = 4096; Npad = 1024; gx = 128; bid -= 8256; }
        int k0 = (bid % gx) * 32, n0 = (bid / gx) * 32;
        int tx = threadIdx.x & 31, ty = threadIdx.x >> 5;
        #pragma unroll
        for (int i = 0; i < 32; i += 8) {
            int k = k0 + ty + i, n = n0 + tx;
            t[ty + i][tx] = (k < K && n < N) ? W[(size_t)k * N + n] : 0.f;
        }
        __syncthreads();
        #pragma unroll
        for (int i = 0; i < 32; i += 8) {
            int n = n0 + ty + i, k = k0 + tx;
            if (n < Npad && k < Kpad) out[(size_t)n * Kpad + k] = f2bf(t[tx][ty + i]);
        }
    } else {
        float* sm = &t[0][0];
        int row = bid - 12352;
        const float* xr = x + (size_t)row * DD;
        u16* orow = lnout + (size_t)row * DD;
        float s = 0.f, ss = 0.f;
        for (int j = threadIdx.x; j < DD - 1; j += blockDim.x) {
            float v = xr[1 + j]; s += v; ss += v * v;
        }
        s = block_reduce_sum(s, sm);
        ss = block_reduce_sum(ss, sm);
        float mu = s / (float)(DD - 1);
        float var = ss / (float)(DD - 1) - mu * mu;
        float rstd = rsqrtf(var + 1e-5f);
        float s2 = 0.f;
        for (int j = threadIdx.x; j < DD - 1; j += blockDim.x) {
            float v = (xr[1 + j] - mu) * rstd * g1[j] + be1[j];
            orow[1 + j] = f2bf(v); s2 += v * v;
        }
        s2 = block_reduce_sum(s2, sm);
        if (threadIdx.x == 0) orow[0] = f2bf(sqrtf(s2 + 1.f));
    }
}

// ---------------- layernorm + lift -> bf16 (standalone, unused slot kept for clarity) ----------------

// ---------------- bf16 MFMA GEMM (m97 + XOR swizzle + split-K + GROUP_M rasterization) ----------------
__device__ __forceinline__ void cstore(float* p, float v) { *p = v; }
__device__ __forceinline__ void cstore(u16* p, float v) { *p = f2bf(v); }

template <typename OT>
__global__ __launch_bounds__(256) void k_gemm_mfma(
        const u16* __restrict__ A, const u16* __restrict__ BT,
        const float* __restrict__ bias, int nbias,
        OT* __restrict__ C0, OT* __restrict__ C1,
        int ldc, int ldab, int ksplit, int K) {
    __shared__ __align__(16) u16 As[128 * 64];
    __shared__ __align__(16) u16 Bs[128 * 64];
    int z = blockIdx.z;
    int kbeg = z ? ksplit : 0;
    int kend = z ? K : ksplit;
    OT* C = z ? C1 : C0;
    const float* bs = z ? nullptr : bias;

    // GROUP_M=8 rasterization: consecutive ids cover 8-M x tiles_n rectangles.
    int tiles_n = gridDim.x;
    int lin = blockIdx.y * tiles_n + blockIdx.x;
    int width = 8 * tiles_n;
    int group = lin / width;
    int rem = lin - group * width;
    int mm = group * 8 + (rem & 7);
    int nn = rem >> 3;
    int n0 = nn * 128, m0 = mm * 128;

    int tid = threadIdx.x;
    int wave = tid >> 6, lane = tid & 63;
    int quad = lane >> 4, m16 = lane & 15;
    int wm = (wave & 1) * 64, wn = (wave >> 1) * 64;

    f32x4 acc[4][4];
    #pragma unroll
    for (int t = 0; t < 4; ++t)
        #pragma unroll
        for (int u = 0; u < 4; ++u) acc[t][u] = (f32x4){0.f, 0.f, 0.f, 0.f};

    int r8 = lane >> 3;
    int cc = (lane & 7) ^ r8;
    int srow = wave * 32 + r8;
    const u16* ag = A  + (size_t)(m0 + srow) * ldab + cc * 8;
    const u16* bg = BT + (size_t)(n0 + srow) * ldab + cc * 8;
    u16* asl = &As[(wave * 32) * 64];
    u16* bsl = &Bs[(wave * 32) * 64];

    for (int k0 = kbeg; k0 < kend; k0 += 64) {
        __syncthreads();
        #pragma unroll
        for (int j = 0; j < 4; ++j) {
            async16(ag + (size_t)(j * 8) * ldab + k0, asl + (j * 8) * 64);
            async16(bg + (size_t)(j * 8) * ldab + k0, bsl + (j * 8) * 64);
        }
        __syncthreads();
        #pragma unroll
        for (int kk = 0; kk < 2; ++kk) {
            bf16x8 af[4], bfr[4];
            #pragma unroll
            for (int t = 0; t < 4; ++t) {
                int slot = (kk * 4 + quad) ^ (m16 & 7);
                af[t] = *(const bf16x8*)&As[(wm + t * 16 + m16) * 64 + slot * 8];
            }
            #pragma unroll
            for (int u = 0; u < 4; ++u) {
                int slot = (kk * 4 + quad) ^ (m16 & 7);
                bfr[u] = *(const bf16x8*)&Bs[(wn + u * 16 + m16) * 64 + slot * 8];
            }
            #pragma unroll
            for (int t = 0; t < 4; ++t)
                #pragma unroll
                for (int u = 0; u < 4; ++u)
                    acc[t][u] = __builtin_amdgcn_mfma_f32_16x16x32_bf16(af[t], bfr[u], acc[t][u], 0, 0, 0);
        }
    }
    #pragma unroll
    for (int u = 0; u < 4; ++u) {
        int col = n0 + wn + u * 16 + m16;
        float bv = (bs != nullptr && col < nbias) ? bs[col] : 0.f;
        #pragma unroll
        for (int t = 0; t < 4; ++t) {
            #pragma unroll
            for (int r = 0; r < 4; ++r) {
                int row = m0 + wm + t * 16 + quad * 4 + r;
                cstore(C + (size_t)row * ldc + col, acc[t][u][r] + bv);
            }
        }
    }
}

// ---------------- fused head builder (Q, K, V via blockIdx.y) ----------------
// Q: (bh, n, 96), time negated. K: (bh, n, 104). V: tiled (bh, kt, d, 72), tile stride 6144.
__global__ __launch_bounds__(256) void k_build_heads(
        const u16* __restrict__ qkv,
        const float* __restrict__ bq, const float* __restrict__ bk,
        const float* __restrict__ bv,
        u16* __restrict__ Qp, u16* __restrict__ Kp, u16* __restrict__ V2) {
    int wid = threadIdx.x >> 6, lane = threadIdx.x & 63;
    int idx = blockIdx.x * 4 + wid;
    int h = idx & 15, bn = idx >> 4;
    int b = bn >> 10, n = bn & 1023;
    int sec = blockIdx.y;
    const float* bias = (sec == 0) ? bq : (sec == 1) ? bk : bv;
    float v = bf2f(qkv[(size_t)bn * 3072 + sec * 1024 + h * 64 + lane]) + bias[h * 64 + lane];
    float ss = v * v;
    #pragma unroll
    for (int o = 32; o > 0; o >>= 1) ss += __shfl_xor(ss, o);
    float tcomp = sqrtf(ss + 1.f);
    size_t bhn = (size_t)(b * 16 + h) * 1024 + n;
    if (sec == 0) {
        u16* drow = Qp + bhn * 96;
        drow[1 + lane] = f2bf(v);
        if (lane == 0) drow[0] = f2bf(-tcomp);
        if (lane < 31) drow[65 + lane] = 0;
    } else if (sec == 1) {
        u16* drow = Kp + bhn * 104;
        drow[1 + lane] = f2bf(v);
        if (lane == 0) drow[0] = f2bf(tcomp);
        if (lane < 39) drow[65 + lane] = 0;
    } else {
        u16* base = V2 + ((size_t)(b * 16 + h) * 16 + (n >> 6)) * 6144 + (n & 63);
        base[(1 + lane) * 72] = f2bf(v);
        if (lane == 0) base[0] = f2bf(tcomp);
        if (lane >= 49) base[(16 + lane) * 72] = 0;   // d = 65..79
    }
}

// ---------------- MFMA flash attention v3 + pad zeroing in epilogue ----------------
#define AKS 104
#define AVS 72
#define APS 88
#define KTILE_U16 (64 * AKS)   // 6656
#define VTILE_U16 6144
#define EXPC 0.36067376f       // 0.25 * log2(e)
__global__ __launch_bounds__(256) void k_attn_mfma(
        const u16* __restrict__ Qp, const u16* __restrict__ Kp,
        const u16* __restrict__ V2, u16* __restrict__ cat) {
    __shared__ __align__(16) u16 Klds[2][KTILE_U16];
    __shared__ __align__(16) u16 Vlds[2][VTILE_U16];
    __shared__ __align__(16) u16 Plds[4][16 * APS];
    int tid = threadIdx.x;
    int wave = tid >> 6, lane = tid & 63;
    int quad = lane >> 4, m = lane & 15;
    int bh = blockIdx.y, qt = blockIdx.x;

    const u16* kg = Kp + (size_t)bh * 16 * KTILE_U16;
    const u16* vg = V2 + (size_t)bh * 16 * VTILE_U16;

    bf16x8 aq[2][3];
    #pragma unroll
    for (int g = 0; g < 2; ++g) {
        const u16* qptr = Qp + ((size_t)bh * 1024 + qt * 128 + g * 64 + wave * 16 + m) * 96;
        aq[g][0] = *(const bf16x8*)(qptr + quad * 8);
        aq[g][1] = *(const bf16x8*)(qptr + 32 + quad * 8);
        aq[g][2] = *(const bf16x8*)(qptr + 64 + quad * 8);
    }

    f32x4 O[2][5];
    #pragma unroll
    for (int g = 0; g < 2; ++g)
        #pragma unroll
        for (int i = 0; i < 5; ++i) O[g][i] = (f32x4){0.f, 0.f, 0.f, 0.f};

    auto stage = [&](int kt, int s) {
        const u16* kt_p = kg + kt * KTILE_U16 + lane * 8;
        const u16* vt_p = vg + kt * VTILE_U16 + lane * 8;
        for (int i = wave; i < 25; i += 4) {
            if (i < 13) async16(kt_p + i * 512, &Klds[s][i * 512]);
            else        async16(vt_p + (i - 13) * 512, &Vlds[s][(i - 13) * 512]);
        }
    };

    stage(0, 0);
    for (int kt = 0; kt < 16; ++kt) {
        int cur = kt & 1;
        __syncthreads();
        if (kt < 15) stage(kt + 1, cur ^ 1);
        u16* pw = &Plds[wave][0];
        #pragma unroll
        for (int g = 0; g < 2; ++g) {
            #pragma unroll
            for (int nt = 0; nt < 4; ++nt) {
                f32x4 acc = (f32x4){0.f, 0.f, 0.f, 0.f};
                const u16* kr = &Klds[cur][(nt * 16 + m) * AKS + quad * 8];
                acc = __builtin_amdgcn_mfma_f32_16x16x32_bf16(aq[g][0], *(const bf16x8*)(kr),      acc, 0, 0, 0);
                acc = __builtin_amdgcn_mfma_f32_16x16x32_bf16(aq[g][1], *(const bf16x8*)(kr + 32), acc, 0, 0, 0);
                acc = __builtin_amdgcn_mfma_f32_16x16x32_bf16(aq[g][2], *(const bf16x8*)(kr + 64), acc, 0, 0, 0);
                #pragma unroll
                for (int r = 0; r < 4; ++r) {
                    float p = __builtin_amdgcn_exp2f(fmaf(acc[r], EXPC, EXPC));
                    union { float f; unsigned u; } pv; pv.f = p;
                    pw[(quad * 4 + r) * APS + nt * 16 + m] = (u16)((pv.u + 0x8000u) >> 16);
                }
            }
            #pragma unroll
            for (int kc = 0; kc < 2; ++kc) {
                bf16x8 ap = *(const bf16x8*)&Plds[wave][m * APS + kc * 32 + quad * 8];
                #pragma unroll
                for (int vt = 0; vt < 5; ++vt) {
                    bf16x8 bv = *(const bf16x8*)&Vlds[cur][(vt * 16 + m) * AVS + kc * 32 + quad * 8];
                    O[g][vt] = __builtin_amdgcn_mfma_f32_16x16x32_bf16(ap, bv, O[g][vt], 0, 0, 0);
                }
            }
        }
    }
    int b = bh >> 4, h = bh & 15;
    #pragma unroll
    for (int g = 0; g < 2; ++g) {
        #pragma unroll
        for (int r = 0; r < 4; ++r) {
            float part = 0.f;
            #pragma unroll
            for (int vt = 0; vt < 5; ++vt) {
                int c = vt * 16 + m;
                float o = O[g][vt][r];
                part += (c == 0) ? o * o : -o * o;
            }
            part += __shfl_xor(part, 1);
            part += __shfl_xor(part, 2);
            part += __shfl_xor(part, 4);
            part += __shfl_xor(part, 8);
            float rden = rsqrtf(fmaxf(part, 1e-8f));
            int n = qt * 128 + g * 64 + wave * 16 + quad * 4 + r;
            u16* crow = cat + (size_t)(b * 1024 + n) * 1088 + h * 65;
            #pragma unroll
            for (int vt = 0; vt < 5; ++vt) {
                int c = vt * 16 + m;
                if (c < 65) crow[c] = f2bf(O[g][vt][r] * rden);
            }
        }
    }
    // zero pad cols 1040..1087 for this block's 128 rows (one h-slot per (b,qt))
    if (h == 15) {
        for (int i = tid; i < 128 * 48; i += 256) {
            int rr = i / 48, c = i - rr * 48;
            int n = qt * 128 + rr;
            cat[(size_t)(b * 1024 + n) * 1088 + 1040 + c] = 0;
        }
    }
}

// ---------------- fused lift(y0+y1) + lresnet + layernorm2 (row-local) ----------------
// writes x1 (fp32, needed by final lresnet) and ln2 output (bf16, feeds Wfc GEMM)
__global__ __launch_bounds__(256) void k_lresnet_ln(
        const float* __restrict__ x, const float* __restrict__ y0,
        const float* __restrict__ y1, const float* __restrict__ wscale,
        const float* __restrict__ g2, const float* __restrict__ be2,
        float* __restrict__ x1, u16* __restrict__ lnout) {
    __shared__ float sm[8];
    int row = blockIdx.x;
    const float* xr = x + (size_t)row * DD;
    const float* ya = y0 + (size_t)row * 1024;
    const float* yb = y1 + (size_t)row * 1024;
    float w = *wscale;
    float zreg[4];
    float sy = 0.f, sz = 0.f, szs = 0.f;
    int cnt = 0;
    for (int j = threadIdx.x; j < DD - 1; j += blockDim.x) {
        float yv = ya[j] + yb[j];
        float zv = xr[1 + j] + w * yv;
        sy += yv * yv; sz += zv * zv; szs += zv;
        zreg[cnt++] = zv;
    }
    sy = block_reduce_sum(sy, sm);
    sz = block_reduce_sum(sz, sm);
    szs = block_reduce_sum(szs, sm);
    float y0t = sqrtf(sy + 1.f);
    float z0 = xr[0] + w * y0t;
    float q = z0 * z0 - sz;
    float rden = rsqrtf(fmaxf(q, 1e-8f));
    // layernorm over x1 space = rden * z
    float mu = rden * szs / (float)(DD - 1);
    float ex2 = rden * rden * sz / (float)(DD - 1);
    float var = ex2 - mu * mu;
    float rstd = rsqrtf(var + 1e-5f);
    float s2 = 0.f;
    cnt = 0;
    float* x1r = x1 + (size_t)row * DD;
    u16* lr = lnout + (size_t)row * DD;
    for (int j = threadIdx.x; j < DD - 1; j += blockDim.x) {
        float xv = zreg[cnt++] * rden;
        x1r[1 + j] = xv;
        float v = (xv - mu) * rstd * g2[j] + be2[j];
        lr[1 + j] = f2bf(v); s2 += v * v;
    }
    s2 = block_reduce_sum(s2, sm);
    if (threadIdx.x == 0) {
        x1r[0] = z0 * rden;
        lr[0] = f2bf(sqrtf(s2 + 1.f));
    }
}

// ---------------- final lresnet (fp32 out) ----------------
__global__ __launch_bounds__(256) void k_lresnet(
        const float* __restrict__ x, const float* __restrict__ y0,
        const float* __restrict__ y1, const float* __restrict__ wscale,
        float* __restrict__ out) {
    __shared__ float sm[8];
    int row = blockIdx.x;
    const float* xr = x + (size_t)row * DD;
    const float* ya = y0 + (size_t)row * 1024;
    const float* yb = y1 + (size_t)row * 1024;
    float w = *wscale;
    float zreg[4];
    float sy = 0.f, sz = 0.f;
    int cnt = 0;
    for (int j = threadIdx.x; j < DD - 1; j += blockDim.x) {
        float yv = ya[j] + yb[j];
        float zv = xr[1 + j] + w * yv;
        sy += yv * yv; sz += zv * zv;
        zreg[cnt++] = zv;
    }
    sy = block_reduce_sum(sy, sm);
    sz = block_reduce_sum(sz, sm);
    float y0t = sqrtf(sy + 1.f);
    float z0 = xr[0] + w * y0t;
    float q = z0 * z0 - sz;
    float rden = rsqrtf(fmaxf(q, 1e-8f));
    cnt = 0;
    for (int j = threadIdx.x; j < DD - 1; j += blockDim.x)
        out[(size_t)row * DD + 1 + j] = zreg[cnt++] * rden;
    if (threadIdx.x == 0) out[(size_t)row * DD] = z0 * rden;
}

// ---------------- gelu (exact) + lift: bf16 in -> bf16 lifted out ----------------
__global__ __launch_bounds__(256) void k_gelu_lift(
        const u16* __restrict__ hfc, u16* __restrict__ hg) {
    __shared__ float sm[8];
    int row = blockIdx.x;
    const u16* hr = hfc + (size_t)row * 4096;
    u16* gr = hg + (size_t)row * 4096;
    float s2 = 0.f;
    for (int j = threadIdx.x; j < 4095; j += blockDim.x) {
        float v = bf2f(hr[j]);
        float gl = 0.5f * v * (1.f + erff(v * 0.70710678f));
        gr[1 + j] = f2bf(gl); s2 += gl * gl;
    }
    s2 = block_reduce_sum(s2, sm);
    if (threadIdx.x == 0) gr[0] = f2bf(sqrtf(s2 + 1.f));
}

// ---------------- launch ----------------
extern "C" void kernel_launch(void* const* d_in, const int* in_sizes, int n_in,
                              void* d_out, int out_size, void* d_ws, size_t ws_size,
                              hipStream_t stream) {
    const float* x   = (const float*)d_in[0];
    const float* g1  = (const float*)d_in[1];
    const float* b1  = (const float*)d_in[2];
    const float* Wq  = (const float*)d_in[3];
    const float* bq  = (const float*)d_in[4];
    const float* Wk  = (const float*)d_in[5];
    const float* bk  = (const float*)d_in[6];
    const float* Wv  = (const float*)d_in[7];
    const float* bv  = (const float*)d_in[8];
    const float* Wo  = (const float*)d_in[9];
    const float* bo  = (const float*)d_in[10];
    const float* g2  = (const float*)d_in[11];
    const float* b2  = (const float*)d_in[12];
    const float* Wfc = (const float*)d_in[13];
    const float* bfc = (const float*)d_in[14];
    const float* Wpj = (const float*)d_in[15];
    const float* bpj = (const float*)d_in[16];
    const float* w1  = (const float*)d_in[17];
    const float* w2  = (const float*)d_in[18];
    float* out = (float*)d_out;

    char* W = (char*)d_ws;
    // byte offsets; peak 117,571,584 B
    u16* lx_bf  = (u16*)(W + 0);            // 8 MB (ln1, later ln2)
    u16* WqkvT  = (u16*)(W + 8388608);      // [3072][1024]
    u16* WoT    = (u16*)(W + 14680064);     // [1024][1088]
    u16* WfcT   = (u16*)(W + 16908288);     // [4096][1024]
    u16* WpjT   = (u16*)(W + 25296896);     // [1024][4096]
    u16* qkv_bf = (u16*)(W + 33685504);     // 4096x3072 (dead after builders)
    u16* Qp     = (u16*)(W + 58851328);     // 64x1024x96
    u16* Kp     = (u16*)(W + 71434240);     // 64x1024x104
    u16* V2     = (u16*)(W + 85065728);     // 64x16x6144
    u16* cat_bf = (u16*)(W + 97648640);     // 4096x1088
    float* ax0  = (float*)(W + 33685504);   // overlay qkv (dead)
    float* ax1  = (float*)(W + 50462720);   // overlay qkv/Qp-head (dead)
    float* x1   = (float*)(W + 67239936);   // overlay Qp-tail/Kp (dead)
    u16* hfc_bf = (u16*)(W + 84017152);     // 32MB, overlay Kp-tail/V2/cat (dead)
    u16* hg_bf  = (u16*)(W + 33685504);     // 32MB, overlay ax0/ax1 (dead)
    float* h2a  = (float*)(W + 84017152);   // overlay hfc (dead after gelu)
    float* h2b  = (float*)(W + 100794368);

    dim3 blk(256);

    // 1) weight conversion + layernorm1 (fused, 16448 blocks)
    k_pre<<<16448, blk, 0, stream>>>(Wq, Wk, Wv, Wo, Wfc, Wpj,
                                     WqkvT, WoT, WfcT, WpjT,
                                     x, g1, b1, lx_bf);

    // 2) fused QKV GEMM + head layouts
    k_gemm_mfma<u16><<<dim3(24, 32, 1), blk, 0, stream>>>(
        lx_bf, WqkvT, nullptr, 0, qkv_bf, qkv_bf, 3072, 1024, 1024, 1024);
    k_build_heads<<<dim3(ROWS * HH / 4, 3), blk, 0, stream>>>(
        qkv_bf, bq, bk, bv, Qp, Kp, V2);

    // 3) MFMA flash attention (pad zeroing fused in epilogue)
    k_attn_mfma<<<dim3(8, 64), blk, 0, stream>>>(Qp, Kp, V2, cat_bf);

    // 4) ax = cat @ Wo + bo, split-K (576+512)
    k_gemm_mfma<float><<<dim3(8, 32, 2), blk, 0, stream>>>(
        cat_bf, WoT, bo, 1023, ax0, ax1, 1024, 1088, 576, 1088);

    // 5) x1 = lresnet(x, lift(ax0+ax1), w1); ln2 -> lx_bf (fused)
    k_lresnet_ln<<<ROWS, blk, 0, stream>>>(x, ax0, ax1, w1, g2, b2, x1, lx_bf);

    // 6) hfc = ln2 @ Wfc + bfc (bf16 out)
    k_gemm_mfma<u16><<<dim3(32, 32, 1), blk, 0, stream>>>(
        lx_bf, WfcT, bfc, 4095, hfc_bf, hfc_bf, 4096, 1024, 1024, 1024);

    // 7) hg = lift(gelu(hfc)) bf16
    k_gelu_lift<<<ROWS, blk, 0, stream>>>(hfc_bf, hg_bf);

    // 8) h2 = hg @ Wpj + bpj, split-K (2048+2048)
    k_gemm_mfma<float><<<dim3(8, 32, 2), blk, 0, stream>>>(
        hg_bf, WpjT, bpj, 1023, h2a, h2b, 1024, 4096, 2048, 4096);

    // 9) out = lresnet(x1, lift(h2a+h2b), w2)
    k_lresnet<<<ROWS, blk, 0, stream>>>(x1, h2a, h2b, w2, out);
}

// Round 8
// 441.895 us; speedup vs baseline: 10.3247x; 1.0107x over previous
//
#include <hip/hip_runtime.h>
#include <math.h>

#define BB 4
#define NN 1024
#define DD 1024
#define HH 16
#define ROWS (BB*NN)   // 4096

typedef __attribute__((ext_vector_type(8))) short bf16x8;
typedef __attribute__((ext_vector_type(4))) float f32x4;
typedef unsigned short u16;

__device__ __forceinline__ u16 f2bf(float f) {
    union { float f; unsigned u; } v; v.f = f;
    unsigned r = v.u + 0x7fff + ((v.u >> 16) & 1);
    return (u16)(r >> 16);
}
__device__ __forceinline__ float bf2f(u16 u) {
    union { unsigned u; float f; } v; v.u = ((unsigned)u) << 16; return v.f;
}

// async global->LDS, 16B per lane. LDS dest = wave-uniform base (+lane*16 implicit).
__device__ __forceinline__ void async16(const void* g, void* l) {
    __builtin_amdgcn_global_load_lds(
        (__attribute__((address_space(1))) void*)(uintptr_t)g,
        (__attribute__((address_space(3))) void*)(uintptr_t)l,
        16, 0, 0);
}

// ---------------- block reduce ----------------
__device__ __forceinline__ float block_reduce_sum(float v, float* sm) {
    #pragma unroll
    for (int o = 32; o > 0; o >>= 1) v += __shfl_down(v, o);
    int lane = threadIdx.x & 63, wid = threadIdx.x >> 6;
    if (lane == 0) sm[wid] = v;
    __syncthreads();
    if (wid == 0) {
        v = (lane < (int)(blockDim.x >> 6)) ? sm[lane] : 0.f;
        #pragma unroll
        for (int o = 2; o > 0; o >>= 1) v += __shfl_down(v, o);
        if (lane == 0) sm[0] = v;
    }
    __syncthreads();
    float r = sm[0];
    __syncthreads();
    return r;
}

// ---------------- fused: weight transpose+convert (6 weights) AND layernorm1 ----------------
__global__ __launch_bounds__(256) void k_pre(
        const float* __restrict__ Wq_, const float* __restrict__ Wk_,
        const float* __restrict__ Wv_, const float* __restrict__ Wo_,
        const float* __restrict__ Wfc_, const float* __restrict__ Wpj_,
        u16* __restrict__ WqkvT, u16* __restrict__ WoT,
        u16* __restrict__ WfcT, u16* __restrict__ WpjT,
        const float* __restrict__ x, const float* __restrict__ g1,
        const float* __restrict__ be1, u16* __restrict__ lnout) {
    __shared__ float t[32][33];
    int bid = blockIdx.x;
    if (bid < 12352) {
        const float* W; u16* out; int K, N, Kpad, Npad, gx;
        if (bid < 1024)      { W = Wq_;  out = WqkvT;            K = 1024; N = 1024; Kpad = 1024; Npad = 1024; gx = 32; }
        else if (bid < 2048) { W = Wk_;  out = WqkvT + 1048576;  K = 1024; N = 1024; Kpad = 1024; Npad = 1024; gx = 32; bid -= 1024; }
        else if (bid < 3072) { W = Wv_;  out = WqkvT + 2097152;  K = 1024; N = 1024; Kpad = 1024; Npad = 1024; gx = 32; bid -= 2048; }
        else if (bid < 4160) { W = Wo_;  out = WoT;              K = 1040; N = 1023; Kpad = 1088; Npad = 1024; gx = 34; bid -= 3072; }
        else if (bid < 8256) { W = Wfc_; out = WfcT;             K = 1024; N = 4095; Kpad = 1024; Npad = 4096; gx = 32; bid -= 4160; }
        else                 { W = Wpj_; out = WpjT;             K = 4096; N = 1023; Kpad = 4096; Npad = 1024; gx = 128; bid -= 8256; }
        int k0 = (bid % gx) * 32, n0 = (bid / gx) * 32;
        int tx = threadIdx.x & 31, ty = threadIdx.x >> 5;
        #pragma unroll
        for (int i = 0; i < 32; i += 8) {
            int k = k0 + ty + i, n = n0 + tx;
            t[ty + i][tx] = (k < K && n < N) ? W[(size_t)k * N + n] : 0.f;
        }
        __syncthreads();
        #pragma unroll
        for (int i = 0; i < 32; i += 8) {
            int n = n0 + ty + i, k = k0 + tx;
            if (n < Npad && k < Kpad) out[(size_t)n * Kpad + k] = f2bf(t[tx][ty + i]);
        }
    } else {
        float* sm = &t[0][0];
        int row = bid - 12352;
        const float* xr = x + (size_t)row * DD;
        u16* orow = lnout + (size_t)row * DD;
        float s = 0.f, ss = 0.f;
        for (int j = threadIdx.x; j < DD - 1; j += blockDim.x) {
            float v = xr[1 + j]; s += v; ss += v * v;
        }
        s = block_reduce_sum(s, sm);
        ss = block_reduce_sum(ss, sm);
        float mu = s / (float)(DD - 1);
        float var = ss / (float)(DD - 1) - mu * mu;
        float rstd = rsqrtf(var + 1e-5f);
        float s2 = 0.f;
        for (int j = threadIdx.x; j < DD - 1; j += blockDim.x) {
            float v = (xr[1 + j] - mu) * rstd * g1[j] + be1[j];
            orow[1 + j] = f2bf(v); s2 += v * v;
        }
        s2 = block_reduce_sum(s2, sm);
        if (threadIdx.x == 0) orow[0] = f2bf(sqrtf(s2 + 1.f));
    }
}

// ---------------- bf16 MFMA GEMM: single-barrier double-buffered K-loop ----------------
// stage(it+1) issued right after the barrier flies during the whole MFMA phase.
__device__ __forceinline__ void cstore(float* p, float v) { *p = v; }
__device__ __forceinline__ void cstore(u16* p, float v) { *p = f2bf(v); }

template <typename OT>
__global__ __launch_bounds__(256) void k_gemm_mfma(
        const u16* __restrict__ A, const u16* __restrict__ BT,
        const float* __restrict__ bias, int nbias,
        OT* __restrict__ C0, OT* __restrict__ C1,
        int ldc, int ldab, int ksplit, int K) {
    __shared__ __align__(16) u16 As[2][128 * 64];
    __shared__ __align__(16) u16 Bs[2][128 * 64];
    int z = blockIdx.z;
    int kbeg = z ? ksplit : 0;
    int kend = z ? K : ksplit;
    OT* C = z ? C1 : C0;
    const float* bs = z ? nullptr : bias;

    int tid = threadIdx.x;
    int wave = tid >> 6, lane = tid & 63;
    int quad = lane >> 4, m16 = lane & 15;
    int n0 = blockIdx.x * 128, m0 = blockIdx.y * 128;
    int wm = (wave & 1) * 64, wn = (wave >> 1) * 64;

    f32x4 acc[4][4];
    #pragma unroll
    for (int t = 0; t < 4; ++t)
        #pragma unroll
        for (int u = 0; u < 4; ++u) acc[t][u] = (f32x4){0.f, 0.f, 0.f, 0.f};

    int r8 = lane >> 3;
    int cc = (lane & 7) ^ r8;               // XOR chunk swizzle (bank-conflict-free, measured 0)
    int srow = wave * 32 + r8;
    const u16* ag = A  + (size_t)(m0 + srow) * ldab + cc * 8;
    const u16* bg = BT + (size_t)(n0 + srow) * ldab + cc * 8;

    auto stage = [&](int k0, int s) {
        #pragma unroll
        for (int j = 0; j < 4; ++j) {
            async16(ag + (size_t)(j * 8) * ldab + k0, &As[s][(wave * 32 + j * 8) * 64]);
            async16(bg + (size_t)(j * 8) * ldab + k0, &Bs[s][(wave * 32 + j * 8) * 64]);
        }
    };

    int niter = (kend - kbeg) >> 6;
    stage(kbeg, 0);
    for (int it = 0; it < niter; ++it) {
        int cur = it & 1;
        __syncthreads();                    // drains stage(it) + prior iter's LDS reads
        if (it + 1 < niter) stage(kbeg + (it + 1) * 64, cur ^ 1);
        #pragma unroll
        for (int kk = 0; kk < 2; ++kk) {
            bf16x8 af[4], bfr[4];
            #pragma unroll
            for (int t = 0; t < 4; ++t) {
                int slot = (kk * 4 + quad) ^ (m16 & 7);
                af[t] = *(const bf16x8*)&As[cur][(wm + t * 16 + m16) * 64 + slot * 8];
            }
            #pragma unroll
            for (int u = 0; u < 4; ++u) {
                int slot = (kk * 4 + quad) ^ (m16 & 7);
                bfr[u] = *(const bf16x8*)&Bs[cur][(wn + u * 16 + m16) * 64 + slot * 8];
            }
            #pragma unroll
            for (int t = 0; t < 4; ++t)
                #pragma unroll
                for (int u = 0; u < 4; ++u)
                    acc[t][u] = __builtin_amdgcn_mfma_f32_16x16x32_bf16(af[t], bfr[u], acc[t][u], 0, 0, 0);
        }
    }
    #pragma unroll
    for (int u = 0; u < 4; ++u) {
        int col = n0 + wn + u * 16 + m16;
        float bv = (bs != nullptr && col < nbias) ? bs[col] : 0.f;
        #pragma unroll
        for (int t = 0; t < 4; ++t) {
            #pragma unroll
            for (int r = 0; r < 4; ++r) {
                int row = m0 + wm + t * 16 + quad * 4 + r;
                cstore(C + (size_t)row * ldc + col, acc[t][u][r] + bv);
            }
        }
    }
}

// ---------------- fused head builder (Q, K, V via blockIdx.y) ----------------
__global__ __launch_bounds__(256) void k_build_heads(
        const u16* __restrict__ qkv,
        const float* __restrict__ bq, const float* __restrict__ bk,
        const float* __restrict__ bv,
        u16* __restrict__ Qp, u16* __restrict__ Kp, u16* __restrict__ V2) {
    int wid = threadIdx.x >> 6, lane = threadIdx.x & 63;
    int idx = blockIdx.x * 4 + wid;
    int h = idx & 15, bn = idx >> 4;
    int b = bn >> 10, n = bn & 1023;
    int sec = blockIdx.y;
    const float* bias = (sec == 0) ? bq : (sec == 1) ? bk : bv;
    float v = bf2f(qkv[(size_t)bn * 3072 + sec * 1024 + h * 64 + lane]) + bias[h * 64 + lane];
    float ss = v * v;
    #pragma unroll
    for (int o = 32; o > 0; o >>= 1) ss += __shfl_xor(ss, o);
    float tcomp = sqrtf(ss + 1.f);
    size_t bhn = (size_t)(b * 16 + h) * 1024 + n;
    if (sec == 0) {
        u16* drow = Qp + bhn * 96;
        drow[1 + lane] = f2bf(v);
        if (lane == 0) drow[0] = f2bf(-tcomp);
        if (lane < 31) drow[65 + lane] = 0;
    } else if (sec == 1) {
        u16* drow = Kp + bhn * 104;
        drow[1 + lane] = f2bf(v);
        if (lane == 0) drow[0] = f2bf(tcomp);
        if (lane < 39) drow[65 + lane] = 0;
    } else {
        u16* base = V2 + ((size_t)(b * 16 + h) * 16 + (n >> 6)) * 6144 + (n & 63);
        base[(1 + lane) * 72] = f2bf(v);
        if (lane == 0) base[0] = f2bf(tcomp);
        if (lane >= 49) base[(16 + lane) * 72] = 0;   // d = 65..79
    }
}

// ---------------- MFMA flash attention v3 + pad zeroing in epilogue ----------------
#define AKS 104
#define AVS 72
#define APS 88
#define KTILE_U16 (64 * AKS)   // 6656
#define VTILE_U16 6144
#define EXPC 0.36067376f       // 0.25 * log2(e)
__global__ __launch_bounds__(256) void k_attn_mfma(
        const u16* __restrict__ Qp, const u16* __restrict__ Kp,
        const u16* __restrict__ V2, u16* __restrict__ cat) {
    __shared__ __align__(16) u16 Klds[2][KTILE_U16];
    __shared__ __align__(16) u16 Vlds[2][VTILE_U16];
    __shared__ __align__(16) u16 Plds[4][16 * APS];
    int tid = threadIdx.x;
    int wave = tid >> 6, lane = tid & 63;
    int quad = lane >> 4, m = lane & 15;
    int bh = blockIdx.y, qt = blockIdx.x;

    const u16* kg = Kp + (size_t)bh * 16 * KTILE_U16;
    const u16* vg = V2 + (size_t)bh * 16 * VTILE_U16;

    bf16x8 aq[2][3];
    #pragma unroll
    for (int g = 0; g < 2; ++g) {
        const u16* qptr = Qp + ((size_t)bh * 1024 + qt * 128 + g * 64 + wave * 16 + m) * 96;
        aq[g][0] = *(const bf16x8*)(qptr + quad * 8);
        aq[g][1] = *(const bf16x8*)(qptr + 32 + quad * 8);
        aq[g][2] = *(const bf16x8*)(qptr + 64 + quad * 8);
    }

    f32x4 O[2][5];
    #pragma unroll
    for (int g = 0; g < 2; ++g)
        #pragma unroll
        for (int i = 0; i < 5; ++i) O[g][i] = (f32x4){0.f, 0.f, 0.f, 0.f};

    auto stage = [&](int kt, int s) {
        const u16* kt_p = kg + kt * KTILE_U16 + lane * 8;
        const u16* vt_p = vg + kt * VTILE_U16 + lane * 8;
        for (int i = wave; i < 25; i += 4) {
            if (i < 13) async16(kt_p + i * 512, &Klds[s][i * 512]);
            else        async16(vt_p + (i - 13) * 512, &Vlds[s][(i - 13) * 512]);
        }
    };

    stage(0, 0);
    for (int kt = 0; kt < 16; ++kt) {
        int cur = kt & 1;
        __syncthreads();
        if (kt < 15) stage(kt + 1, cur ^ 1);
        u16* pw = &Plds[wave][0];
        #pragma unroll
        for (int g = 0; g < 2; ++g) {
            #pragma unroll
            for (int nt = 0; nt < 4; ++nt) {
                f32x4 acc = (f32x4){0.f, 0.f, 0.f, 0.f};
                const u16* kr = &Klds[cur][(nt * 16 + m) * AKS + quad * 8];
                acc = __builtin_amdgcn_mfma_f32_16x16x32_bf16(aq[g][0], *(const bf16x8*)(kr),      acc, 0, 0, 0);
                acc = __builtin_amdgcn_mfma_f32_16x16x32_bf16(aq[g][1], *(const bf16x8*)(kr + 32), acc, 0, 0, 0);
                acc = __builtin_amdgcn_mfma_f32_16x16x32_bf16(aq[g][2], *(const bf16x8*)(kr + 64), acc, 0, 0, 0);
                #pragma unroll
                for (int r = 0; r < 4; ++r) {
                    float p = __builtin_amdgcn_exp2f(fmaf(acc[r], EXPC, EXPC));
                    union { float f; unsigned u; } pv; pv.f = p;
                    pw[(quad * 4 + r) * APS + nt * 16 + m] = (u16)((pv.u + 0x8000u) >> 16);
                }
            }
            #pragma unroll
            for (int kc = 0; kc < 2; ++kc) {
                bf16x8 ap = *(const bf16x8*)&Plds[wave][m * APS + kc * 32 + quad * 8];
                #pragma unroll
                for (int vt = 0; vt < 5; ++vt) {
                    bf16x8 bv = *(const bf16x8*)&Vlds[cur][(vt * 16 + m) * AVS + kc * 32 + quad * 8];
                    O[g][vt] = __builtin_amdgcn_mfma_f32_16x16x32_bf16(ap, bv, O[g][vt], 0, 0, 0);
                }
            }
        }
    }
    int b = bh >> 4, h = bh & 15;
    #pragma unroll
    for (int g = 0; g < 2; ++g) {
        #pragma unroll
        for (int r = 0; r < 4; ++r) {
            float part = 0.f;
            #pragma unroll
            for (int vt = 0; vt < 5; ++vt) {
                int c = vt * 16 + m;
                float o = O[g][vt][r];
                part += (c == 0) ? o * o : -o * o;
            }
            part += __shfl_xor(part, 1);
            part += __shfl_xor(part, 2);
            part += __shfl_xor(part, 4);
            part += __shfl_xor(part, 8);
            float rden = rsqrtf(fmaxf(part, 1e-8f));
            int n = qt * 128 + g * 64 + wave * 16 + quad * 4 + r;
            u16* crow = cat + (size_t)(b * 1024 + n) * 1088 + h * 65;
            #pragma unroll
            for (int vt = 0; vt < 5; ++vt) {
                int c = vt * 16 + m;
                if (c < 65) crow[c] = f2bf(O[g][vt][r] * rden);
            }
        }
    }
    if (h == 15) {
        for (int i = tid; i < 128 * 48; i += 256) {
            int rr = i / 48, c = i - rr * 48;
            int n = qt * 128 + rr;
            cat[(size_t)(b * 1024 + n) * 1088 + 1040 + c] = 0;
        }
    }
}

// ---------------- fused lift(y0+y1) + lresnet + layernorm2 (row-local) ----------------
__global__ __launch_bounds__(256) void k_lresnet_ln(
        const float* __restrict__ x, const float* __restrict__ y0,
        const float* __restrict__ y1, const float* __restrict__ wscale,
        const float* __restrict__ g2, const float* __restrict__ be2,
        float* __restrict__ x1, u16* __restrict__ lnout) {
    __shared__ float sm[8];
    int row = blockIdx.x;
    const float* xr = x + (size_t)row * DD;
    const float* ya = y0 + (size_t)row * 1024;
    const float* yb = y1 + (size_t)row * 1024;
    float w = *wscale;
    float zreg[4];
    float sy = 0.f, sz = 0.f, szs = 0.f;
    int cnt = 0;
    for (int j = threadIdx.x; j < DD - 1; j += blockDim.x) {
        float yv = ya[j] + yb[j];
        float zv = xr[1 + j] + w * yv;
        sy += yv * yv; sz += zv * zv; szs += zv;
        zreg[cnt++] = zv;
    }
    sy = block_reduce_sum(sy, sm);
    sz = block_reduce_sum(sz, sm);
    szs = block_reduce_sum(szs, sm);
    float y0t = sqrtf(sy + 1.f);
    float z0 = xr[0] + w * y0t;
    float q = z0 * z0 - sz;
    float rden = rsqrtf(fmaxf(q, 1e-8f));
    float mu = rden * szs / (float)(DD - 1);
    float ex2 = rden * rden * sz / (float)(DD - 1);
    float var = ex2 - mu * mu;
    float rstd = rsqrtf(var + 1e-5f);
    float s2 = 0.f;
    cnt = 0;
    float* x1r = x1 + (size_t)row * DD;
    u16* lr = lnout + (size_t)row * DD;
    for (int j = threadIdx.x; j < DD - 1; j += blockDim.x) {
        float xv = zreg[cnt++] * rden;
        x1r[1 + j] = xv;
        float v = (xv - mu) * rstd * g2[j] + be2[j];
        lr[1 + j] = f2bf(v); s2 += v * v;
    }
    s2 = block_reduce_sum(s2, sm);
    if (threadIdx.x == 0) {
        x1r[0] = z0 * rden;
        lr[0] = f2bf(sqrtf(s2 + 1.f));
    }
}

// ---------------- final lresnet (fp32 out) ----------------
__global__ __launch_bounds__(256) void k_lresnet(
        const float* __restrict__ x, const float* __restrict__ y0,
        const float* __restrict__ y1, const float* __restrict__ wscale,
        float* __restrict__ out) {
    __shared__ float sm[8];
    int row = blockIdx.x;
    const float* xr = x + (size_t)row * DD;
    const float* ya = y0 + (size_t)row * 1024;
    const float* yb = y1 + (size_t)row * 1024;
    float w = *wscale;
    float zreg[4];
    float sy = 0.f, sz = 0.f;
    int cnt = 0;
    for (int j = threadIdx.x; j < DD - 1; j += blockDim.x) {
        float yv = ya[j] + yb[j];
        float zv = xr[1 + j] + w * yv;
        sy += yv * yv; sz += zv * zv;
        zreg[cnt++] = zv;
    }
    sy = block_reduce_sum(sy, sm);
    sz = block_reduce_sum(sz, sm);
    float y0t = sqrtf(sy + 1.f);
    float z0 = xr[0] + w * y0t;
    float q = z0 * z0 - sz;
    float rden = rsqrtf(fmaxf(q, 1e-8f));
    cnt = 0;
    for (int j = threadIdx.x; j < DD - 1; j += blockDim.x)
        out[(size_t)row * DD + 1 + j] = zreg[cnt++] * rden;
    if (threadIdx.x == 0) out[(size_t)row * DD] = z0 * rden;
}

// ---------------- gelu (exact) + lift: bf16 in -> bf16 lifted out ----------------
__global__ __launch_bounds__(256) void k_gelu_lift(
        const u16* __restrict__ hfc, u16* __restrict__ hg) {
    __shared__ float sm[8];
    int row = blockIdx.x;
    const u16* hr = hfc + (size_t)row * 4096;
    u16* gr = hg + (size_t)row * 4096;
    float s2 = 0.f;
    for (int j = threadIdx.x; j < 4095; j += blockDim.x) {
        float v = bf2f(hr[j]);
        float gl = 0.5f * v * (1.f + erff(v * 0.70710678f));
        gr[1 + j] = f2bf(gl); s2 += gl * gl;
    }
    s2 = block_reduce_sum(s2, sm);
    if (threadIdx.x == 0) gr[0] = f2bf(sqrtf(s2 + 1.f));
}

// ---------------- launch ----------------
extern "C" void kernel_launch(void* const* d_in, const int* in_sizes, int n_in,
                              void* d_out, int out_size, void* d_ws, size_t ws_size,
                              hipStream_t stream) {
    const float* x   = (const float*)d_in[0];
    const float* g1  = (const float*)d_in[1];
    const float* b1  = (const float*)d_in[2];
    const float* Wq  = (const float*)d_in[3];
    const float* bq  = (const float*)d_in[4];
    const float* Wk  = (const float*)d_in[5];
    const float* bk  = (const float*)d_in[6];
    const float* Wv  = (const float*)d_in[7];
    const float* bv  = (const float*)d_in[8];
    const float* Wo  = (const float*)d_in[9];
    const float* bo  = (const float*)d_in[10];
    const float* g2  = (const float*)d_in[11];
    const float* b2  = (const float*)d_in[12];
    const float* Wfc = (const float*)d_in[13];
    const float* bfc = (const float*)d_in[14];
    const float* Wpj = (const float*)d_in[15];
    const float* bpj = (const float*)d_in[16];
    const float* w1  = (const float*)d_in[17];
    const float* w2  = (const float*)d_in[18];
    float* out = (float*)d_out;

    char* W = (char*)d_ws;
    // byte offsets; peak 117,571,584 B
    u16* lx_bf  = (u16*)(W + 0);            // 8 MB (ln1, later ln2)
    u16* WqkvT  = (u16*)(W + 8388608);      // [3072][1024]
    u16* WoT    = (u16*)(W + 14680064);     // [1024][1088]
    u16* WfcT   = (u16*)(W + 16908288);     // [4096][1024]
    u16* WpjT   = (u16*)(W + 25296896);     // [1024][4096]
    u16* qkv_bf = (u16*)(W + 33685504);     // 4096x3072 (dead after builders)
    u16* Qp     = (u16*)(W + 58851328);     // 64x1024x96
    u16* Kp     = (u16*)(W + 71434240);     // 64x1024x104
    u16* V2     = (u16*)(W + 85065728);     // 64x16x6144
    u16* cat_bf = (u16*)(W + 97648640);     // 4096x1088
    float* ax0  = (float*)(W + 33685504);   // overlay qkv (dead)
    float* ax1  = (float*)(W + 50462720);   // overlay qkv/Qp-head (dead)
    float* x1   = (float*)(W + 67239936);   // overlay Qp-tail/Kp (dead)
    u16* hfc_bf = (u16*)(W + 84017152);     // 32MB, overlay Kp-tail/V2/cat (dead)
    u16* hg_bf  = (u16*)(W + 33685504);     // 32MB, overlay ax0/ax1 (dead)
    float* h2a  = (float*)(W + 84017152);   // overlay hfc (dead after gelu)
    float* h2b  = (float*)(W + 100794368);

    dim3 blk(256);

    // 1) weight conversion + layernorm1 (fused)
    k_pre<<<16448, blk, 0, stream>>>(Wq, Wk, Wv, Wo, Wfc, Wpj,
                                     WqkvT, WoT, WfcT, WpjT,
                                     x, g1, b1, lx_bf);

    // 2) fused QKV GEMM + head layouts
    k_gemm_mfma<u16><<<dim3(24, 32, 1), blk, 0, stream>>>(
        lx_bf, WqkvT, nullptr, 0, qkv_bf, qkv_bf, 3072, 1024, 1024, 1024);
    k_build_heads<<<dim3(ROWS * HH / 4, 3), blk, 0, stream>>>(
        qkv_bf, bq, bk, bv, Qp, Kp, V2);

    // 3) MFMA flash attention (pad zeroing fused in epilogue)
    k_attn_mfma<<<dim3(8, 64), blk, 0, stream>>>(Qp, Kp, V2, cat_bf);

    // 4) ax = cat @ Wo + bo, split-K (576+512)
    k_gemm_mfma<float><<<dim3(8, 32, 2), blk, 0, stream>>>(
        cat_bf, WoT, bo, 1023, ax0, ax1, 1024, 1088, 576, 1088);

    // 5) x1 = lresnet(x, lift(ax0+ax1), w1); ln2 -> lx_bf (fused)
    k_lresnet_ln<<<ROWS, blk, 0, stream>>>(x, ax0, ax1, w1, g2, b2, x1, lx_bf);

    // 6) hfc = ln2 @ Wfc + bfc (bf16 out)
    k_gemm_mfma<u16><<<dim3(32, 32, 1), blk, 0, stream>>>(
        lx_bf, WfcT, bfc, 4095, hfc_bf, hfc_bf, 4096, 1024, 1024, 1024);

    // 7) hg = lift(gelu(hfc)) bf16
    k_gelu_lift<<<ROWS, blk, 0, stream>>>(hfc_bf, hg_bf);

    // 8) h2 = hg @ Wpj + bpj, split-K (2048+2048)
    k_gemm_mfma<float><<<dim3(8, 32, 2), blk, 0, stream>>>(
        hg_bf, WpjT, bpj, 1023, h2a, h2b, 1024, 4096, 2048, 4096);

    // 9) out = lresnet(x1, lift(h2a+h2b), w2)
    k_lresnet<<<ROWS, blk, 0, stream>>>(x1, h2a, h2b, w2, out);
}

// Round 9
// 434.112 us; speedup vs baseline: 10.5099x; 1.0179x over previous
//
#include <hip/hip_runtime.h>
#include <math.h>

#define BB 4
#define NN 1024
#define DD 1024
#define HH 16
#define ROWS (BB*NN)   // 4096

typedef __attribute__((ext_vector_type(8))) short bf16x8;
typedef __attribute__((ext_vector_type(4))) float f32x4;
typedef unsigned short u16;

__device__ __forceinline__ u16 f2bf(float f) {
    union { float f; unsigned u; } v; v.f = f;
    unsigned r = v.u + 0x7fff + ((v.u >> 16) & 1);
    return (u16)(r >> 16);
}
__device__ __forceinline__ float bf2f(u16 u) {
    union { unsigned u; float f; } v; v.u = ((unsigned)u) << 16; return v.f;
}

// async global->LDS, 16B per lane. LDS dest = wave-uniform base (+lane*16 implicit).
__device__ __forceinline__ void async16(const void* g, void* l) {
    __builtin_amdgcn_global_load_lds(
        (__attribute__((address_space(1))) void*)(uintptr_t)g,
        (__attribute__((address_space(3))) void*)(uintptr_t)l,
        16, 0, 0);
}

// ---------------- block reduce ----------------
__device__ __forceinline__ float block_reduce_sum(float v, float* sm) {
    #pragma unroll
    for (int o = 32; o > 0; o >>= 1) v += __shfl_down(v, o);
    int lane = threadIdx.x & 63, wid = threadIdx.x >> 6;
    if (lane == 0) sm[wid] = v;
    __syncthreads();
    if (wid == 0) {
        v = (lane < (int)(blockDim.x >> 6)) ? sm[lane] : 0.f;
        #pragma unroll
        for (int o = 2; o > 0; o >>= 1) v += __shfl_down(v, o);
        if (lane == 0) sm[0] = v;
    }
    __syncthreads();
    float r = sm[0];
    __syncthreads();
    return r;
}

// ---------------- fused: weight transpose+convert (6 weights) AND layernorm1 ----------------
__global__ __launch_bounds__(256) void k_pre(
        const float* __restrict__ Wq_, const float* __restrict__ Wk_,
        const float* __restrict__ Wv_, const float* __restrict__ Wo_,
        const float* __restrict__ Wfc_, const float* __restrict__ Wpj_,
        u16* __restrict__ WqkvT, u16* __restrict__ WoT,
        u16* __restrict__ WfcT, u16* __restrict__ WpjT,
        const float* __restrict__ x, const float* __restrict__ g1,
        const float* __restrict__ be1, u16* __restrict__ lnout) {
    __shared__ float t[32][33];
    int bid = blockIdx.x;
    if (bid < 12352) {
        const float* W; u16* out; int K, N, Kpad, Npad, gx;
        if (bid < 1024)      { W = Wq_;  out = WqkvT;            K = 1024; N = 1024; Kpad = 1024; Npad = 1024; gx = 32; }
        else if (bid < 2048) { W = Wk_;  out = WqkvT + 1048576;  K = 1024; N = 1024; Kpad = 1024; Npad = 1024; gx = 32; bid -= 1024; }
        else if (bid < 3072) { W = Wv_;  out = WqkvT + 2097152;  K = 1024; N = 1024; Kpad = 1024; Npad = 1024; gx = 32; bid -= 2048; }
        else if (bid < 4160) { W = Wo_;  out = WoT;              K = 1040; N = 1023; Kpad = 1088; Npad = 1024; gx = 34; bid -= 3072; }
        else if (bid < 8256) { W = Wfc_; out = WfcT;             K = 1024; N = 4095; Kpad = 1024; Npad = 4096; gx = 32; bid -= 4160; }
        else                 { W = Wpj_; out = WpjT;             K = 4096; N = 1023; Kpad = 4096; Npad = 1024; gx = 128; bid -= 8256; }
        int k0 = (bid % gx) * 32, n0 = (bid / gx) * 32;
        int tx = threadIdx.x & 31, ty = threadIdx.x >> 5;
        #pragma unroll
        for (int i = 0; i < 32; i += 8) {
            int k = k0 + ty + i, n = n0 + tx;
            t[ty + i][tx] = (k < K && n < N) ? W[(size_t)k * N + n] : 0.f;
        }
        __syncthreads();
        #pragma unroll
        for (int i = 0; i < 32; i += 8) {
            int n = n0 + ty + i, k = k0 + tx;
            if (n < Npad && k < Kpad) out[(size_t)n * Kpad + k] = f2bf(t[tx][ty + i]);
        }
    } else {
        float* sm = &t[0][0];
        int row = bid - 12352;
        const float* xr = x + (size_t)row * DD;
        u16* orow = lnout + (size_t)row * DD;
        float s = 0.f, ss = 0.f;
        for (int j = threadIdx.x; j < DD - 1; j += blockDim.x) {
            float v = xr[1 + j]; s += v; ss += v * v;
        }
        s = block_reduce_sum(s, sm);
        ss = block_reduce_sum(ss, sm);
        float mu = s / (float)(DD - 1);
        float var = ss / (float)(DD - 1) - mu * mu;
        float rstd = rsqrtf(var + 1e-5f);
        float s2 = 0.f;
        for (int j = threadIdx.x; j < DD - 1; j += blockDim.x) {
            float v = (xr[1 + j] - mu) * rstd * g1[j] + be1[j];
            orow[1 + j] = f2bf(v); s2 += v * v;
        }
        s2 = block_reduce_sum(s2, sm);
        if (threadIdx.x == 0) orow[0] = f2bf(sqrtf(s2 + 1.f));
    }
}

// ---------------- bf16 MFMA GEMM: single-barrier double-buffered K-loop ----------------
__device__ __forceinline__ void cstore(float* p, float v) { *p = v; }
__device__ __forceinline__ void cstore(u16* p, float v) { *p = f2bf(v); }

template <typename OT>
__global__ __launch_bounds__(256) void k_gemm_mfma(
        const u16* __restrict__ A, const u16* __restrict__ BT,
        const float* __restrict__ bias, int nbias,
        OT* __restrict__ C0, OT* __restrict__ C1,
        int ldc, int ldab, int ksplit, int K) {
    __shared__ __align__(16) u16 As[2][128 * 64];
    __shared__ __align__(16) u16 Bs[2][128 * 64];
    int z = blockIdx.z;
    int kbeg = z ? ksplit : 0;
    int kend = z ? K : ksplit;
    OT* C = z ? C1 : C0;
    const float* bs = z ? nullptr : bias;

    int tid = threadIdx.x;
    int wave = tid >> 6, lane = tid & 63;
    int quad = lane >> 4, m16 = lane & 15;
    int n0 = blockIdx.x * 128, m0 = blockIdx.y * 128;
    int wm = (wave & 1) * 64, wn = (wave >> 1) * 64;

    f32x4 acc[4][4];
    #pragma unroll
    for (int t = 0; t < 4; ++t)
        #pragma unroll
        for (int u = 0; u < 4; ++u) acc[t][u] = (f32x4){0.f, 0.f, 0.f, 0.f};

    int r8 = lane >> 3;
    int cc = (lane & 7) ^ r8;               // XOR chunk swizzle (bank-conflict-free, measured 0)
    int srow = wave * 32 + r8;
    const u16* ag = A  + (size_t)(m0 + srow) * ldab + cc * 8;
    const u16* bg = BT + (size_t)(n0 + srow) * ldab + cc * 8;

    auto stage = [&](int k0, int s) {
        #pragma unroll
        for (int j = 0; j < 4; ++j) {
            async16(ag + (size_t)(j * 8) * ldab + k0, &As[s][(wave * 32 + j * 8) * 64]);
            async16(bg + (size_t)(j * 8) * ldab + k0, &Bs[s][(wave * 32 + j * 8) * 64]);
        }
    };

    int niter = (kend - kbeg) >> 6;
    stage(kbeg, 0);
    for (int it = 0; it < niter; ++it) {
        int cur = it & 1;
        __syncthreads();                    // drains stage(it) + prior iter's LDS reads
        if (it + 1 < niter) stage(kbeg + (it + 1) * 64, cur ^ 1);
        #pragma unroll
        for (int kk = 0; kk < 2; ++kk) {
            bf16x8 af[4], bfr[4];
            #pragma unroll
            for (int t = 0; t < 4; ++t) {
                int slot = (kk * 4 + quad) ^ (m16 & 7);
                af[t] = *(const bf16x8*)&As[cur][(wm + t * 16 + m16) * 64 + slot * 8];
            }
            #pragma unroll
            for (int u = 0; u < 4; ++u) {
                int slot = (kk * 4 + quad) ^ (m16 & 7);
                bfr[u] = *(const bf16x8*)&Bs[cur][(wn + u * 16 + m16) * 64 + slot * 8];
            }
            #pragma unroll
            for (int t = 0; t < 4; ++t)
                #pragma unroll
                for (int u = 0; u < 4; ++u)
                    acc[t][u] = __builtin_amdgcn_mfma_f32_16x16x32_bf16(af[t], bfr[u], acc[t][u], 0, 0, 0);
        }
    }
    #pragma unroll
    for (int u = 0; u < 4; ++u) {
        int col = n0 + wn + u * 16 + m16;
        float bv = (bs != nullptr && col < nbias) ? bs[col] : 0.f;
        #pragma unroll
        for (int t = 0; t < 4; ++t) {
            #pragma unroll
            for (int r = 0; r < 4; ++r) {
                int row = m0 + wm + t * 16 + quad * 4 + r;
                cstore(C + (size_t)row * ldc + col, acc[t][u][r] + bv);
            }
        }
    }
}

// ---------------- fused head builder (Q, K, V via blockIdx.y) ----------------
__global__ __launch_bounds__(256) void k_build_heads(
        const u16* __restrict__ qkv,
        const float* __restrict__ bq, const float* __restrict__ bk,
        const float* __restrict__ bv,
        u16* __restrict__ Qp, u16* __restrict__ Kp, u16* __restrict__ V2) {
    int wid = threadIdx.x >> 6, lane = threadIdx.x & 63;
    int idx = blockIdx.x * 4 + wid;
    int h = idx & 15, bn = idx >> 4;
    int b = bn >> 10, n = bn & 1023;
    int sec = blockIdx.y;
    const float* bias = (sec == 0) ? bq : (sec == 1) ? bk : bv;
    float v = bf2f(qkv[(size_t)bn * 3072 + sec * 1024 + h * 64 + lane]) + bias[h * 64 + lane];
    float ss = v * v;
    #pragma unroll
    for (int o = 32; o > 0; o >>= 1) ss += __shfl_xor(ss, o);
    float tcomp = sqrtf(ss + 1.f);
    size_t bhn = (size_t)(b * 16 + h) * 1024 + n;
    if (sec == 0) {
        u16* drow = Qp + bhn * 96;
        drow[1 + lane] = f2bf(v);
        if (lane == 0) drow[0] = f2bf(-tcomp);
        if (lane < 31) drow[65 + lane] = 0;
    } else if (sec == 1) {
        u16* drow = Kp + bhn * 104;
        drow[1 + lane] = f2bf(v);
        if (lane == 0) drow[0] = f2bf(tcomp);
        if (lane < 39) drow[65 + lane] = 0;
    } else {
        u16* base = V2 + ((size_t)(b * 16 + h) * 16 + (n >> 6)) * 6144 + (n & 63);
        base[(1 + lane) * 72] = f2bf(v);
        if (lane == 0) base[0] = f2bf(tcomp);
        if (lane >= 49) base[(16 + lane) * 72] = 0;   // d = 65..79
    }
}

// ---------------- MFMA flash attention v4 ----------------
// XCD-swizzled 1D grid: 8 blocks sharing one bh land on one XCD (L2 K/V reuse).
// S^T trick: A=K-frag, B=Q-frag -> C gives 4 consecutive keys/lane -> packed b64 P-writes.
#define AKS 104
#define AVS 72
#define APS 88
#define KTILE_U16 (64 * AKS)   // 6656
#define VTILE_U16 6144
#define EXPC 0.36067376f       // 0.25 * log2(e)
__global__ __launch_bounds__(256) void k_attn_mfma(
        const u16* __restrict__ Qp, const u16* __restrict__ Kp,
        const u16* __restrict__ V2, u16* __restrict__ cat) {
    __shared__ __align__(16) u16 Klds[2][KTILE_U16];
    __shared__ __align__(16) u16 Vlds[2][VTILE_U16];
    __shared__ __align__(16) u16 Plds[4][16 * APS];
    int tid = threadIdx.x;
    int wave = tid >> 6, lane = tid & 63;
    int quad = lane >> 4, m = lane & 15;
    // XCD swizzle: bid ≡ c (mod 8) share an XCD; give them the same bh.
    int bid = blockIdx.x;
    int bh = ((bid & 7) << 3) | (bid >> 6);
    int qt = (bid >> 3) & 7;

    const u16* kg = Kp + (size_t)bh * 16 * KTILE_U16;
    const u16* vg = V2 + (size_t)bh * 16 * VTILE_U16;

    bf16x8 aq[2][3];
    #pragma unroll
    for (int g = 0; g < 2; ++g) {
        const u16* qptr = Qp + ((size_t)bh * 1024 + qt * 128 + g * 64 + wave * 16 + m) * 96;
        aq[g][0] = *(const bf16x8*)(qptr + quad * 8);
        aq[g][1] = *(const bf16x8*)(qptr + 32 + quad * 8);
        aq[g][2] = *(const bf16x8*)(qptr + 64 + quad * 8);
    }

    f32x4 O[2][5];
    #pragma unroll
    for (int g = 0; g < 2; ++g)
        #pragma unroll
        for (int i = 0; i < 5; ++i) O[g][i] = (f32x4){0.f, 0.f, 0.f, 0.f};

    auto stage = [&](int kt, int s) {
        const u16* kt_p = kg + kt * KTILE_U16 + lane * 8;
        const u16* vt_p = vg + kt * VTILE_U16 + lane * 8;
        for (int i = wave; i < 25; i += 4) {
            if (i < 13) async16(kt_p + i * 512, &Klds[s][i * 512]);
            else        async16(vt_p + (i - 13) * 512, &Vlds[s][(i - 13) * 512]);
        }
    };

    stage(0, 0);
    for (int kt = 0; kt < 16; ++kt) {
        int cur = kt & 1;
        __syncthreads();
        if (kt < 15) stage(kt + 1, cur ^ 1);
        u16* pw = &Plds[wave][0];
        #pragma unroll
        for (int g = 0; g < 2; ++g) {
            #pragma unroll
            for (int nt = 0; nt < 4; ++nt) {
                // S^T tile: rows=keys nt*16+quad*4+r, cols=q (this wave's 16 q's)
                f32x4 acc = (f32x4){0.f, 0.f, 0.f, 0.f};
                const u16* kr = &Klds[cur][(nt * 16 + m) * AKS + quad * 8];
                acc = __builtin_amdgcn_mfma_f32_16x16x32_bf16(*(const bf16x8*)(kr),      aq[g][0], acc, 0, 0, 0);
                acc = __builtin_amdgcn_mfma_f32_16x16x32_bf16(*(const bf16x8*)(kr + 32), aq[g][1], acc, 0, 0, 0);
                acc = __builtin_amdgcn_mfma_f32_16x16x32_bf16(*(const bf16x8*)(kr + 64), aq[g][2], acc, 0, 0, 0);
                // p for 4 consecutive keys -> one packed 8B write at Plds[q=m][key]
                unsigned pk0, pk1;
                {
                    union { float f; unsigned u; } a0, a1, a2, a3;
                    a0.f = __builtin_amdgcn_exp2f(fmaf(acc[0], EXPC, EXPC));
                    a1.f = __builtin_amdgcn_exp2f(fmaf(acc[1], EXPC, EXPC));
                    a2.f = __builtin_amdgcn_exp2f(fmaf(acc[2], EXPC, EXPC));
                    a3.f = __builtin_amdgcn_exp2f(fmaf(acc[3], EXPC, EXPC));
                    pk0 = ((a0.u + 0x8000u) >> 16) | (((a1.u + 0x8000u) >> 16) << 16);
                    pk1 = ((a2.u + 0x8000u) >> 16) | (((a3.u + 0x8000u) >> 16) << 16);
                }
                uint2 pk; pk.x = pk0; pk.y = pk1;
                *(uint2*)&pw[m * APS + nt * 16 + quad * 4] = pk;
            }
            #pragma unroll
            for (int kc = 0; kc < 2; ++kc) {
                bf16x8 ap = *(const bf16x8*)&Plds[wave][m * APS + kc * 32 + quad * 8];
                #pragma unroll
                for (int vt = 0; vt < 5; ++vt) {
                    bf16x8 bv = *(const bf16x8*)&Vlds[cur][(vt * 16 + m) * AVS + kc * 32 + quad * 8];
                    O[g][vt] = __builtin_amdgcn_mfma_f32_16x16x32_bf16(ap, bv, O[g][vt], 0, 0, 0);
                }
            }
        }
    }
    int b = bh >> 4, h = bh & 15;
    #pragma unroll
    for (int g = 0; g < 2; ++g) {
        #pragma unroll
        for (int r = 0; r < 4; ++r) {
            float part = 0.f;
            #pragma unroll
            for (int vt = 0; vt < 5; ++vt) {
                int c = vt * 16 + m;
                float o = O[g][vt][r];
                part += (c == 0) ? o * o : -o * o;
            }
            part += __shfl_xor(part, 1);
            part += __shfl_xor(part, 2);
            part += __shfl_xor(part, 4);
            part += __shfl_xor(part, 8);
            float rden = rsqrtf(fmaxf(part, 1e-8f));
            int n = qt * 128 + g * 64 + wave * 16 + quad * 4 + r;
            u16* crow = cat + (size_t)(b * 1024 + n) * 1088 + h * 65;
            #pragma unroll
            for (int vt = 0; vt < 5; ++vt) {
                int c = vt * 16 + m;
                if (c < 65) crow[c] = f2bf(O[g][vt][r] * rden);
            }
        }
    }
    if (h == 15) {
        for (int i = tid; i < 128 * 48; i += 256) {
            int rr = i / 48, c = i - rr * 48;
            int n = qt * 128 + rr;
            cat[(size_t)(b * 1024 + n) * 1088 + 1040 + c] = 0;
        }
    }
}

// ---------------- fused lift(y0+y1) + lresnet + layernorm2 (row-local) ----------------
__global__ __launch_bounds__(256) void k_lresnet_ln(
        const float* __restrict__ x, const float* __restrict__ y0,
        const float* __restrict__ y1, const float* __restrict__ wscale,
        const float* __restrict__ g2, const float* __restrict__ be2,
        float* __restrict__ x1, u16* __restrict__ lnout) {
    __shared__ float sm[8];
    int row = blockIdx.x;
    const float* xr = x + (size_t)row * DD;
    const float* ya = y0 + (size_t)row * 1024;
    const float* yb = y1 + (size_t)row * 1024;
    float w = *wscale;
    float zreg[4];
    float sy = 0.f, sz = 0.f, szs = 0.f;
    int cnt = 0;
    for (int j = threadIdx.x; j < DD - 1; j += blockDim.x) {
        float yv = ya[j] + yb[j];
        float zv = xr[1 + j] + w * yv;
        sy += yv * yv; sz += zv * zv; szs += zv;
        zreg[cnt++] = zv;
    }
    sy = block_reduce_sum(sy, sm);
    sz = block_reduce_sum(sz, sm);
    szs = block_reduce_sum(szs, sm);
    float y0t = sqrtf(sy + 1.f);
    float z0 = xr[0] + w * y0t;
    float q = z0 * z0 - sz;
    float rden = rsqrtf(fmaxf(q, 1e-8f));
    float mu = rden * szs / (float)(DD - 1);
    float ex2 = rden * rden * sz / (float)(DD - 1);
    float var = ex2 - mu * mu;
    float rstd = rsqrtf(var + 1e-5f);
    float s2 = 0.f;
    cnt = 0;
    float* x1r = x1 + (size_t)row * DD;
    u16* lr = lnout + (size_t)row * DD;
    for (int j = threadIdx.x; j < DD - 1; j += blockDim.x) {
        float xv = zreg[cnt++] * rden;
        x1r[1 + j] = xv;
        float v = (xv - mu) * rstd * g2[j] + be2[j];
        lr[1 + j] = f2bf(v); s2 += v * v;
    }
    s2 = block_reduce_sum(s2, sm);
    if (threadIdx.x == 0) {
        x1r[0] = z0 * rden;
        lr[0] = f2bf(sqrtf(s2 + 1.f));
    }
}

// ---------------- final lresnet (fp32 out) ----------------
__global__ __launch_bounds__(256) void k_lresnet(
        const float* __restrict__ x, const float* __restrict__ y0,
        const float* __restrict__ y1, const float* __restrict__ wscale,
        float* __restrict__ out) {
    __shared__ float sm[8];
    int row = blockIdx.x;
    const float* xr = x + (size_t)row * DD;
    const float* ya = y0 + (size_t)row * 1024;
    const float* yb = y1 + (size_t)row * 1024;
    float w = *wscale;
    float zreg[4];
    float sy = 0.f, sz = 0.f;
    int cnt = 0;
    for (int j = threadIdx.x; j < DD - 1; j += blockDim.x) {
        float yv = ya[j] + yb[j];
        float zv = xr[1 + j] + w * yv;
        sy += yv * yv; sz += zv * zv;
        zreg[cnt++] = zv;
    }
    sy = block_reduce_sum(sy, sm);
    sz = block_reduce_sum(sz, sm);
    float y0t = sqrtf(sy + 1.f);
    float z0 = xr[0] + w * y0t;
    float q = z0 * z0 - sz;
    float rden = rsqrtf(fmaxf(q, 1e-8f));
    cnt = 0;
    for (int j = threadIdx.x; j < DD - 1; j += blockDim.x)
        out[(size_t)row * DD + 1 + j] = zreg[cnt++] * rden;
    if (threadIdx.x == 0) out[(size_t)row * DD] = z0 * rden;
}

// ---------------- gelu (exact) + lift: bf16 in -> bf16 lifted out ----------------
__global__ __launch_bounds__(256) void k_gelu_lift(
        const u16* __restrict__ hfc, u16* __restrict__ hg) {
    __shared__ float sm[8];
    int row = blockIdx.x;
    const u16* hr = hfc + (size_t)row * 4096;
    u16* gr = hg + (size_t)row * 4096;
    float s2 = 0.f;
    for (int j = threadIdx.x; j < 4095; j += blockDim.x) {
        float v = bf2f(hr[j]);
        float gl = 0.5f * v * (1.f + erff(v * 0.70710678f));
        gr[1 + j] = f2bf(gl); s2 += gl * gl;
    }
    s2 = block_reduce_sum(s2, sm);
    if (threadIdx.x == 0) gr[0] = f2bf(sqrtf(s2 + 1.f));
}

// ---------------- launch ----------------
extern "C" void kernel_launch(void* const* d_in, const int* in_sizes, int n_in,
                              void* d_out, int out_size, void* d_ws, size_t ws_size,
                              hipStream_t stream) {
    const float* x   = (const float*)d_in[0];
    const float* g1  = (const float*)d_in[1];
    const float* b1  = (const float*)d_in[2];
    const float* Wq  = (const float*)d_in[3];
    const float* bq  = (const float*)d_in[4];
    const float* Wk  = (const float*)d_in[5];
    const float* bk  = (const float*)d_in[6];
    const float* Wv  = (const float*)d_in[7];
    const float* bv  = (const float*)d_in[8];
    const float* Wo  = (const float*)d_in[9];
    const float* bo  = (const float*)d_in[10];
    const float* g2  = (const float*)d_in[11];
    const float* b2  = (const float*)d_in[12];
    const float* Wfc = (const float*)d_in[13];
    const float* bfc = (const float*)d_in[14];
    const float* Wpj = (const float*)d_in[15];
    const float* bpj = (const float*)d_in[16];
    const float* w1  = (const float*)d_in[17];
    const float* w2  = (const float*)d_in[18];
    float* out = (float*)d_out;

    char* W = (char*)d_ws;
    // byte offsets; peak 117,571,584 B
    u16* lx_bf  = (u16*)(W + 0);            // 8 MB (ln1, later ln2)
    u16* WqkvT  = (u16*)(W + 8388608);      // [3072][1024]
    u16* WoT    = (u16*)(W + 14680064);     // [1024][1088]
    u16* WfcT   = (u16*)(W + 16908288);     // [4096][1024]
    u16* WpjT   = (u16*)(W + 25296896);     // [1024][4096]
    u16* qkv_bf = (u16*)(W + 33685504);     // 4096x3072 (dead after builders)
    u16* Qp     = (u16*)(W + 58851328);     // 64x1024x96
    u16* Kp     = (u16*)(W + 71434240);     // 64x1024x104
    u16* V2     = (u16*)(W + 85065728);     // 64x16x6144
    u16* cat_bf = (u16*)(W + 97648640);     // 4096x1088
    float* ax0  = (float*)(W + 33685504);   // overlay qkv (dead)
    float* ax1  = (float*)(W + 50462720);   // overlay qkv/Qp-head (dead)
    float* x1   = (float*)(W + 67239936);   // overlay Qp-tail/Kp (dead)
    u16* hfc_bf = (u16*)(W + 84017152);     // 32MB, overlay Kp-tail/V2/cat (dead)
    u16* hg_bf  = (u16*)(W + 33685504);     // 32MB, overlay ax0/ax1 (dead)
    float* h2a  = (float*)(W + 84017152);   // overlay hfc (dead after gelu)
    float* h2b  = (float*)(W + 100794368);

    dim3 blk(256);

    // 1) weight conversion + layernorm1 (fused)
    k_pre<<<16448, blk, 0, stream>>>(Wq, Wk, Wv, Wo, Wfc, Wpj,
                                     WqkvT, WoT, WfcT, WpjT,
                                     x, g1, b1, lx_bf);

    // 2) fused QKV GEMM + head layouts
    k_gemm_mfma<u16><<<dim3(24, 32, 1), blk, 0, stream>>>(
        lx_bf, WqkvT, nullptr, 0, qkv_bf, qkv_bf, 3072, 1024, 1024, 1024);
    k_build_heads<<<dim3(ROWS * HH / 4, 3), blk, 0, stream>>>(
        qkv_bf, bq, bk, bv, Qp, Kp, V2);

    // 3) MFMA flash attention v4 (XCD-swizzled 1D grid)
    k_attn_mfma<<<512, blk, 0, stream>>>(Qp, Kp, V2, cat_bf);

    // 4) ax = cat @ Wo + bo, split-K (576+512)
    k_gemm_mfma<float><<<dim3(8, 32, 2), blk, 0, stream>>>(
        cat_bf, WoT, bo, 1023, ax0, ax1, 1024, 1088, 576, 1088);

    // 5) x1 = lresnet(x, lift(ax0+ax1), w1); ln2 -> lx_bf (fused)
    k_lresnet_ln<<<ROWS, blk, 0, stream>>>(x, ax0, ax1, w1, g2, b2, x1, lx_bf);

    // 6) hfc = ln2 @ Wfc + bfc (bf16 out)
    k_gemm_mfma<u16><<<dim3(32, 32, 1), blk, 0, stream>>>(
        lx_bf, WfcT, bfc, 4095, hfc_bf, hfc_bf, 4096, 1024, 1024, 1024);

    // 7) hg = lift(gelu(hfc)) bf16
    k_gelu_lift<<<ROWS, blk, 0, stream>>>(hfc_bf, hg_bf);

    // 8) h2 = hg @ Wpj + bpj, split-K (2048+2048)
    k_gemm_mfma<float><<<dim3(8, 32, 2), blk, 0, stream>>>(
        hg_bf, WpjT, bpj, 1023, h2a, h2b, 1024, 4096, 2048, 4096);

    // 9) out = lresnet(x1, lift(h2a+h2b), w2)
    k_lresnet<<<ROWS, blk, 0, stream>>>(x1, h2a, h2b, w2, out);
}